// Round 1
// baseline (345.588 us; speedup 1.0000x reference)
//
#include <hip/hip_runtime.h>
#include <hip/hip_bf16.h>
#include <cmath>

#define BS   4
#define NQ   1000
#define CDIM 256
#define NH   8
#define HD   32
#define NVAL 20000
#define FFND 512
#define PN   4
#define WBEV 100
#define HBEV 200
#define TK   64

typedef __bf16 v8bf __attribute__((ext_vector_type(8)));
typedef float  v4f  __attribute__((ext_vector_type(4)));

__device__ __forceinline__ void gload_lds16(const void* g, void* l) {
    __builtin_amdgcn_global_load_lds(
        (const __attribute__((address_space(1))) unsigned int*)g,
        (__attribute__((address_space(3))) unsigned int*)l, 16, 0, 0);
}

// ============ vgemm rider: value-proj, 64 rows x 256 cols per block =========
// value (fp32) is read exactly ONCE across all 1250 blocks (was 2x at 128x128).
// Needs 40960 B of smem.
__device__ __forceinline__ void vgemm64_block(
    int vb, const float* __restrict__ value, const __bf16* __restrict__ Wv,
    const float* __restrict__ bv, __bf16* __restrict__ vpj, char* smem)
{
    __bf16* As = (__bf16*)smem;             // [64][64]
    __bf16* Bs = (__bf16*)(smem + 8192);    // [256][64]
    int tid = threadIdx.x;
    int wave = tid >> 6, lane = tid & 63, quad = lane >> 4, n16 = lane & 15;
    int bm = vb * 64;
    int wm = (wave & 1) * 32, wn = (wave >> 1) * 128;
    v4f acc[2][8] = {};

    for (int k0 = 0; k0 < 256; k0 += 64) {
        float4 fa[2][2];
        #pragma unroll
        for (int i = 0; i < 2; i++) {
            int e = i * 256 + tid;
            int r = e >> 3, c = (e & 7) ^ (r & 7);
            const float* p = value + (long)(bm + r) * 256 + k0 + c * 8;
            fa[i][0] = *(const float4*)p;
            fa[i][1] = *(const float4*)(p + 4);
        }
        __syncthreads();
        #pragma unroll
        for (int i = 0; i < 2; i++) {
            int e = i * 256 + tid;
            v8bf v;
            v[0] = (__bf16)fa[i][0].x; v[1] = (__bf16)fa[i][0].y;
            v[2] = (__bf16)fa[i][0].z; v[3] = (__bf16)fa[i][0].w;
            v[4] = (__bf16)fa[i][1].x; v[5] = (__bf16)fa[i][1].y;
            v[6] = (__bf16)fa[i][1].z; v[7] = (__bf16)fa[i][1].w;
            *(v8bf*)(As + e * 8) = v;
        }
        #pragma unroll
        for (int i = 0; i < 8; i++) {
            int e = i * 256 + tid;
            int r = e >> 3, c = (e & 7) ^ (r & 7);
            gload_lds16(Wv + (long)r * 256 + k0 + c * 8, Bs + e * 8);
        }
        __syncthreads();
        #pragma unroll
        for (int s = 0; s < 2; s++) {
            v8bf af[2], bfr[8];
            #pragma unroll
            for (int mi = 0; mi < 2; mi++) {
                int row = wm + mi * 16 + n16;
                af[mi] = *(v8bf*)&As[row * 64 + (((quad + s * 4) ^ (row & 7))) * 8];
            }
            #pragma unroll
            for (int nj = 0; nj < 8; nj++) {
                int row = wn + nj * 16 + n16;
                bfr[nj] = *(v8bf*)&Bs[row * 64 + (((quad + s * 4) ^ (row & 7))) * 8];
            }
            #pragma unroll
            for (int mi = 0; mi < 2; mi++)
                #pragma unroll
                for (int nj = 0; nj < 8; nj++)
                    acc[mi][nj] = __builtin_amdgcn_mfma_f32_16x16x32_bf16(af[mi], bfr[nj], acc[mi][nj], 0, 0, 0);
        }
    }
    #pragma unroll
    for (int mi = 0; mi < 2; mi++) {
        #pragma unroll
        for (int r = 0; r < 4; r++) {
            int m = bm + wm + mi * 16 + quad * 4 + r;
            #pragma unroll
            for (int nj = 0; nj < 8; nj++) {
                int nn = wn + nj * 16 + n16;
                vpj[(long)m * 256 + nn] = (__bf16)(acc[mi][nj][r] + bv[nn]);
            }
        }
    }
}

// ============ prep_all: weight cast | prep | soaw pack ============
__global__ __launch_bounds__(256) void prep_all_kernel(
    const float* __restrict__ query, const float* __restrict__ qpos,
    const float* __restrict__ in_w, const float* __restrict__ mha_ow,
    const float* __restrict__ vp_w, const float* __restrict__ op_w,
    const float* __restrict__ ffn_w1, const float* __restrict__ ffn_w2,
    const float* __restrict__ so_w, const float* __restrict__ aw_w,
    const float* __restrict__ so_b, const float* __restrict__ aw_b,
    float* __restrict__ x, float* __restrict__ qpos_t,
    __bf16* __restrict__ x_bf, __bf16* __restrict__ xq_bf,
    __bf16* __restrict__ wb, __bf16* __restrict__ wsmall,
    float* __restrict__ bsmall)
{
    int blk = blockIdx.x, tid = threadIdx.x;
    if (blk < 640) {
        long e = ((long)blk * 256 + tid) * 4;
        const float* src; long off;
        if      (e < 196608) { src = in_w;   off = e; }
        else if (e < 262144) { src = mha_ow; off = e - 196608; }
        else if (e < 327680) { src = vp_w;   off = e - 262144; }
        else if (e < 393216) { src = op_w;   off = e - 327680; }
        else if (e < 524288) { src = ffn_w1; off = e - 393216; }
        else                 { src = ffn_w2; off = e - 524288; }
        float4 v = *(const float4*)(src + off);
        __bf16* d = wb + e;
        d[0] = (__bf16)v.x; d[1] = (__bf16)v.y; d[2] = (__bf16)v.z; d[3] = (__bf16)v.w;
    } else if (blk < 4640) {
        int qb = blk - 640;
        int q = qb / BS, b = qb % BS;
        float qv = query[(q * BS + b) * CDIM + tid];
        float pv = qpos [(q * BS + b) * CDIM + tid];
        int o = (b * NQ + q) * CDIM + tid;
        x[o] = qv; qpos_t[o] = pv;
        x_bf[o] = (__bf16)qv; xq_bf[o] = (__bf16)(qv + pv);
    } else if (blk < 4672) {
        long e = ((long)(blk - 4640) * 256 + tid) * 4;
        int row = (int)(e >> 8), col = (int)(e & 255);
        float4 v = {0.f, 0.f, 0.f, 0.f};
        if (row < 64)      v = *(const float4*)(so_w + row * 256 + col);
        else if (row < 96) v = *(const float4*)(aw_w + (row - 64) * 256 + col);
        __bf16* d = wsmall + e;
        d[0] = (__bf16)v.x; d[1] = (__bf16)v.y; d[2] = (__bf16)v.z; d[3] = (__bf16)v.w;
    } else {
        if (tid < 128) bsmall[tid] = tid < 64 ? so_b[tid] : (tid < 96 ? aw_b[tid - 64] : 0.f);
    }
}

// ============ fused q|k|v projection (756 blocks) + vgemm rider ============
__global__ __launch_bounds__(256) void qkvv_kernel(
    const __bf16* __restrict__ xq, const __bf16* __restrict__ xv,
    const __bf16* __restrict__ W, const float* __restrict__ bias,
    __bf16* __restrict__ qk, __bf16* __restrict__ vh,
    const float* __restrict__ value, const __bf16* __restrict__ Wv,
    const float* __restrict__ bv, __bf16* __restrict__ vpj, int voff)
{
    __shared__ __align__(16) char smem[40960];
    int tid = threadIdx.x;
    if ((int)blockIdx.x >= 756) {
        vgemm64_block(blockIdx.x - 756 + voff, value, Wv, bv, vpj, smem);
        return;
    }
    int blk = blockIdx.x;
    int bn = (blk % 12) * 64, bm = (blk / 12) * 64;
    __bf16* As = (__bf16*)smem;             // [64][64]
    __bf16* Bs = (__bf16*)(smem + 8192);    // [64][64]
    const __bf16* A = (bn < 512) ? xq : xv;
    int wave = tid >> 6, lane = tid & 63, quad = lane >> 4, n16 = lane & 15;
    int wm = (wave & 1) * 32, wn = (wave >> 1) * 32;
    v4f acc[2][2] = {};

    for (int k0 = 0; k0 < 256; k0 += 64) {
        __syncthreads();
        #pragma unroll
        for (int i = 0; i < 2; i++) {
            int e = i * 256 + tid;
            int r = e >> 3, c = (e & 7) ^ (r & 7);
            int row = bm + r; if (row > BS * NQ - 1) row = BS * NQ - 1;
            gload_lds16(A + (long)row * 256 + k0 + c * 8, As + e * 8);
        }
        #pragma unroll
        for (int i = 0; i < 2; i++) {
            int e = i * 256 + tid;
            int r = e >> 3, c = (e & 7) ^ (r & 7);
            gload_lds16(W + (long)(bn + r) * 256 + k0 + c * 8, Bs + e * 8);
        }
        __syncthreads();
        #pragma unroll
        for (int s = 0; s < 2; s++) {
            v8bf af[2], bfr[2];
            #pragma unroll
            for (int mi = 0; mi < 2; mi++) {
                int row = wm + mi * 16 + n16;
                af[mi] = *(v8bf*)&As[row * 64 + (((quad + s * 4) ^ (row & 7))) * 8];
            }
            #pragma unroll
            for (int nj = 0; nj < 2; nj++) {
                int row = wn + nj * 16 + n16;
                bfr[nj] = *(v8bf*)&Bs[row * 64 + (((quad + s * 4) ^ (row & 7))) * 8];
            }
            #pragma unroll
            for (int mi = 0; mi < 2; mi++)
                #pragma unroll
                for (int nj = 0; nj < 2; nj++)
                    acc[mi][nj] = __builtin_amdgcn_mfma_f32_16x16x32_bf16(af[mi], bfr[nj], acc[mi][nj], 0, 0, 0);
        }
    }

    #pragma unroll
    for (int mi = 0; mi < 2; mi++) {
        #pragma unroll
        for (int r = 0; r < 4; r++) {
            int m = bm + wm + mi * 16 + quad * 4 + r;
            if (m >= BS * NQ) continue;
            #pragma unroll
            for (int nj = 0; nj < 2; nj++) {
                int nn = bn + wn + nj * 16 + n16;
                float v = acc[mi][nj][r] + bias[nn];
                if (nn < 512) qk[(long)m * 512 + nn] = (__bf16)v;
                else          vh[(long)m * 256 + (nn - 512)] = (__bf16)v;
            }
        }
    }
}

// ============ flash attention, TK=64 (512 blocks) + vgemm rider ============
__global__ __launch_bounds__(256) void fattnv_kernel(
    const __bf16* __restrict__ qk, const __bf16* __restrict__ vh,
    __bf16* __restrict__ aout,
    const float* __restrict__ value, const __bf16* __restrict__ Wv,
    const float* __restrict__ bv, __bf16* __restrict__ vpj, int voff)
{
    __shared__ __align__(16) char smem[40960];
    int tid = threadIdx.x;
    if ((int)blockIdx.x >= 512) {
        vgemm64_block(blockIdx.x - 512 + voff, value, Wv, bv, vpj, smem);
        return;
    }
    int fb = blockIdx.x;
    int qt = fb & 15, h = (fb >> 4) & 7, b = fb >> 7;
    __bf16* Ks = (__bf16*)smem;             // [2][64][40]  = 10240 B
    __bf16* Vt = (__bf16*)(smem + 10240);   // [2][32][72]  =  9216 B
    __bf16* Pl = (__bf16*)(smem + 19456);   // [4][16][72]  =  9216 B
    int wave = tid >> 6, lane = tid & 63, quad = lane >> 4, n = lane & 15;
    int q0 = qt * 64 + wave * 16;
    const float scale = 0.17677669529663687f;
    const float M0 = 8.0f;

    int qrow = q0 + n; if (qrow > NQ - 1) qrow = NQ - 1;
    v8bf aq = *(const v8bf*)(qk + (long)(b * NQ + qrow) * 512 + h * HD + quad * 8);

    v4f o0 = {}, o1 = {};
    float lp[4] = {0.f, 0.f, 0.f, 0.f};

    int sv = tid >> 7;          // 0: stage K, 1: stage V
    int t2 = tid & 127;
    int key = t2 & 63;
    int d16 = (t2 >> 6) * 16;

    v8bf stg0, stg1;
    auto loadtile = [&](int k0) {
        int krow = k0 + key; if (krow > NQ - 1) krow = NQ - 1;
        const __bf16* p = sv ? (vh + (long)(b * NQ + krow) * CDIM + h * HD + d16)
                             : (qk + (long)(b * NQ + krow) * 512 + 256 + h * HD + d16);
        stg0 = *(const v8bf*)p;
        stg1 = *(const v8bf*)(p + 8);
    };

    loadtile(0);
    int pb = 0;
    for (int k0 = 0; k0 < NQ; k0 += TK) {
        if (sv == 0) {
            *(v8bf*)&Ks[(pb * 64 + key) * 40 + d16]     = stg0;
            *(v8bf*)&Ks[(pb * 64 + key) * 40 + d16 + 8] = stg1;
        } else {
            // V transposed; col swizzle ^16 on odd 8-row groups (write+read paired)
            #pragma unroll
            for (int j = 0; j < 8; j++) {
                Vt[(pb * 32 + d16 + j) * 72 + key]            = stg0[j];
                Vt[(pb * 32 + d16 + 8 + j) * 72 + (key ^ 16)] = stg1[j];
            }
        }
        if (k0 + TK < NQ) loadtile(k0 + TK);
        __syncthreads();

        v8bf bk0 = *(v8bf*)&Ks[(pb * 64 +      n) * 40 + quad * 8];
        v8bf bk1 = *(v8bf*)&Ks[(pb * 64 + 16 + n) * 40 + quad * 8];
        v8bf bk2 = *(v8bf*)&Ks[(pb * 64 + 32 + n) * 40 + quad * 8];
        v8bf bk3 = *(v8bf*)&Ks[(pb * 64 + 48 + n) * 40 + quad * 8];
        v4f z = {};
        v4f S0 = __builtin_amdgcn_mfma_f32_16x16x32_bf16(aq, bk0, z, 0, 0, 0);
        v4f S1 = __builtin_amdgcn_mfma_f32_16x16x32_bf16(aq, bk1, z, 0, 0, 0);
        v4f S2 = __builtin_amdgcn_mfma_f32_16x16x32_bf16(aq, bk2, z, 0, 0, 0);
        v4f S3 = __builtin_amdgcn_mfma_f32_16x16x32_bf16(aq, bk3, z, 0, 0, 0);

        bool last = (k0 + TK > NQ);
        float p0[4], p1[4], p2[4], p3[4];
        #pragma unroll
        for (int r = 0; r < 4; r++) {
            p0[r] = __expf(fmaf(S0[r], scale, -M0));
            p1[r] = __expf(fmaf(S1[r], scale, -M0));
            p2[r] = __expf(fmaf(S2[r], scale, -M0));
            p3[r] = __expf(fmaf(S3[r], scale, -M0));
            if (last) {
                if (k0 + 32 + n >= NQ) p2[r] = 0.f;
                if (k0 + 48 + n >= NQ) p3[r] = 0.f;
            }
            lp[r] += p0[r] + p1[r] + p2[r] + p3[r];
        }
        #pragma unroll
        for (int r = 0; r < 4; r++) {
            __bf16* pp = &Pl[(wave * 16 + quad * 4 + r) * 72];
            pp[n]      = (__bf16)p0[r];
            pp[16 + n] = (__bf16)p1[r];
            pp[32 + n] = (__bf16)p2[r];
            pp[48 + n] = (__bf16)p3[r];
        }
        asm volatile("s_waitcnt lgkmcnt(0)" ::: "memory");
        v8bf ap0 = *(v8bf*)&Pl[(wave * 16 + n) * 72 + quad * 8];
        v8bf ap1 = *(v8bf*)&Pl[(wave * 16 + n) * 72 + 32 + quad * 8];
        int swz = ((n >> 3) & 1) << 4;
        int c0 = (quad * 8) ^ swz;
        int c1 = (32 + quad * 8) ^ swz;
        v8bf bv00 = *(v8bf*)&Vt[(pb * 32 +      n) * 72 + c0];
        v8bf bv01 = *(v8bf*)&Vt[(pb * 32 +      n) * 72 + c1];
        v8bf bv10 = *(v8bf*)&Vt[(pb * 32 + 16 + n) * 72 + c0];
        v8bf bv11 = *(v8bf*)&Vt[(pb * 32 + 16 + n) * 72 + c1];
        o0 = __builtin_amdgcn_mfma_f32_16x16x32_bf16(ap0, bv00, o0, 0, 0, 0);
        o0 = __builtin_amdgcn_mfma_f32_16x16x32_bf16(ap1, bv01, o0, 0, 0, 0);
        o1 = __builtin_amdgcn_mfma_f32_16x16x32_bf16(ap0, bv10, o1, 0, 0, 0);
        o1 = __builtin_amdgcn_mfma_f32_16x16x32_bf16(ap1, bv11, o1, 0, 0, 0);
        pb ^= 1;
    }

    #pragma unroll
    for (int r = 0; r < 4; r++) {
        float l = lp[r];
        #pragma unroll
        for (int off = 1; off < 16; off <<= 1) l += __shfl_xor(l, off, 16);
        int q = q0 + quad * 4 + r;
        if (q < NQ) {
            float invl = 1.0f / l;
            __bf16* op = aout + ((long)(b * NQ + q) * CDIM + h * HD);
            op[n]      = (__bf16)(o0[r] * invl);
            op[16 + n] = (__bf16)(o1[r] * invl);
        }
    }
}

// ==== mha out-proj + res + LN1 + (LN1out+qpos -> soaw projection), rider ====
__global__ __launch_bounds__(256) void gln1s_kernel(
    const __bf16* __restrict__ A, const __bf16* __restrict__ W,
    const float* __restrict__ bias, const float* __restrict__ res,
    const float* __restrict__ g, const float* __restrict__ beta,
    const float* __restrict__ qpos_t,
    const __bf16* __restrict__ Wsm, const float* __restrict__ bsm,
    float* __restrict__ outf, float* __restrict__ soawO,
    const float* __restrict__ value, const __bf16* __restrict__ Wv,
    const float* __restrict__ bv, __bf16* __restrict__ vpj, int voff)
{
    __shared__ __align__(16) char smem[43776];
    int tid = threadIdx.x;
    if ((int)blockIdx.x >= 250) {
        vgemm64_block(blockIdx.x - 250 + voff, value, Wv, bv, vpj, smem);
        return;
    }
    __bf16* As  = (__bf16*)smem;             // [16][64]
    __bf16* Bs  = (__bf16*)(smem + 2048);    // [256][64]
    __bf16* Axq = (__bf16*)(smem + 34816);   // [16][264]
    float* redS = (float*)(smem + 43264);    // [64]
    float* redQ = redS + 64;                 // [64]
    int bm = blockIdx.x * 16;
    int wave = tid >> 6, lane = tid & 63, quad = lane >> 4, n16 = lane & 15;
    int wn = wave * 64;
    v4f acc[4] = {};

    for (int k0 = 0; k0 < 256; k0 += 64) {
        __syncthreads();
        if (tid < 128) {
            int e = tid;
            int r = e >> 3, c = (e & 7) ^ (r & 7);
            gload_lds16(A + (long)(bm + r) * 256 + k0 + c * 8, As + e * 8);
        }
        #pragma unroll
        for (int i = 0; i < 8; i++) {
            int e = i * 256 + tid;
            int r = e >> 3, c = (e & 7) ^ (r & 7);
            gload_lds16(W + (long)r * 256 + k0 + c * 8, Bs + e * 8);
        }
        __syncthreads();
        #pragma unroll
        for (int s = 0; s < 2; s++) {
            v8bf af = *(v8bf*)&As[n16 * 64 + (((quad + s * 4) ^ (n16 & 7))) * 8];
            #pragma unroll
            for (int nj = 0; nj < 4; nj++) {
                int row = wn + nj * 16 + n16;
                v8bf bfr = *(v8bf*)&Bs[row * 64 + (((quad + s * 4) ^ (row & 7))) * 8];
                acc[nj] = __builtin_amdgcn_mfma_f32_16x16x32_bf16(af, bfr, acc[nj], 0, 0, 0);
            }
        }
    }

    float y[4][4], s1[4] = {}, s2[4] = {};
    #pragma unroll
    for (int r = 0; r < 4; r++) {
        int m = bm + quad * 4 + r;
        #pragma unroll
        for (int nj = 0; nj < 4; nj++) {
            int nn = wn + nj * 16 + n16;
            float v = acc[nj][r] + bias[nn] + res[(long)m * 256 + nn];
            y[r][nj] = v;
            s1[r] += v; s2[r] += v * v;
        }
    }
    #pragma unroll
    for (int r = 0; r < 4; r++) {
        #pragma unroll
        for (int off = 1; off < 16; off <<= 1) {
            s1[r] += __shfl_xor(s1[r], off, 16);
            s2[r] += __shfl_xor(s2[r], off, 16);
        }
    }
    if (n16 == 0) {
        #pragma unroll
        for (int r = 0; r < 4; r++) {
            redS[wave * 16 + quad * 4 + r] = s1[r];
            redQ[wave * 16 + quad * 4 + r] = s2[r];
        }
    }
    __syncthreads();
    #pragma unroll
    for (int r = 0; r < 4; r++) {
        int mr = quad * 4 + r;
        float ts = redS[mr] + redS[16 + mr] + redS[32 + mr] + redS[48 + mr];
        float tq = redQ[mr] + redQ[16 + mr] + redQ[32 + mr] + redQ[48 + mr];
        float mean = ts * (1.0f / 256.0f);
        float var = tq * (1.0f / 256.0f) - mean * mean;
        float rinv = rsqrtf(var + 1e-5f);
        int m = bm + mr;
        #pragma unroll
        for (int nj = 0; nj < 4; nj++) {
            int nn = wn + nj * 16 + n16;
            float o = (y[r][nj] - mean) * rinv * g[nn] + beta[nn];
            outf[(long)m * 256 + nn] = o;
            Axq[mr * 264 + nn] = (__bf16)(o + qpos_t[(long)m * 256 + nn]);
        }
    }
    __syncthreads();
    // soaw projection: 16 x 96, K=256, waves 0..2 handle 32 cols each
    if (wave < 3) {
        v4f sacc[2] = {};
        #pragma unroll
        for (int k0 = 0; k0 < 256; k0 += 32) {
            v8bf af = *(v8bf*)&Axq[n16 * 264 + k0 + quad * 8];
            #pragma unroll
            for (int t = 0; t < 2; t++) {
                int col = wave * 32 + t * 16 + n16;
                v8bf bw = *(const v8bf*)(Wsm + (long)col * 256 + k0 + quad * 8);
                sacc[t] = __builtin_amdgcn_mfma_f32_16x16x32_bf16(af, bw, sacc[t], 0, 0, 0);
            }
        }
        #pragma unroll
        for (int t = 0; t < 2; t++)
            #pragma unroll
            for (int r = 0; r < 4; r++) {
                int mm = bm + quad * 4 + r;
                int col = wave * 32 + t * 16 + n16;
                soawO[(long)mm * 96 + col] = sacc[t][r] + bsm[col];
            }
    }
}

// ====== fused msdeform sampling + op-proj + residual + LN2 (250 blocks) =====
__global__ __launch_bounds__(256) void msdsop_kernel(
    const __bf16* __restrict__ vproj, const float* __restrict__ soaw,
    const float* __restrict__ refp,
    const __bf16* __restrict__ W, const float* __restrict__ bias,
    const float* __restrict__ res, const float* __restrict__ g,
    const float* __restrict__ beta,
    float* __restrict__ outf, __bf16* __restrict__ outb)
{
    __shared__ __align__(16) char smem[41472];
    __bf16* As4 = (__bf16*)smem;             // [4][16][64] swizzled A-tile
    __bf16* Bs  = (__bf16*)(smem + 8192);    // [256][64]
    float* redS = (float*)(smem + 40960);    // [64]
    float* redQ = redS + 64;                 // [64]
    int tid = threadIdx.x;
    int bm = blockIdx.x * 16;
    int h = tid >> 5, d = tid & 31;

    // ---- Phase A: msdeform sampling for rows bm..bm+15 -> LDS A-tile ----
    #pragma unroll 4
    for (int r = 0; r < 16; r++) {
        int m = bm + r;
        int bb = m / NQ;
        float rx = refp[m * 2 + 0];
        float ry = refp[m * 2 + 1];
        const float* rowp = soaw + (long)m * 96;
        const float* offp = rowp + h * 8;
        const float* awp  = rowp + 64 + h * 4;
        float a0 = awp[0], a1 = awp[1], a2 = awp[2], a3 = awp[3];
        float mx = fmaxf(fmaxf(a0, a1), fmaxf(a2, a3));
        float e0 = __expf(a0 - mx), e1 = __expf(a1 - mx);
        float e2 = __expf(a2 - mx), e3 = __expf(a3 - mx);
        float invs = 1.0f / (e0 + e1 + e2 + e3);
        float acc = 0.f;
        #pragma unroll
        for (int p = 0; p < PN; p++) {
            float ew = (p == 0 ? e0 : p == 1 ? e1 : p == 2 ? e2 : e3) * invs;
            float xim = rx * (float)WBEV + offp[p * 2 + 0] - 0.5f;
            float yim = ry * (float)HBEV + offp[p * 2 + 1] - 0.5f;
            float x0f = floorf(xim), y0f = floorf(yim);
            float lx = xim - x0f, ly = yim - y0f;
            int x0 = (int)x0f, y0 = (int)y0f;
            float gsum = 0.f;
            #pragma unroll
            for (int dy = 0; dy < 2; dy++) {
                #pragma unroll
                for (int dx = 0; dx < 2; dx++) {
                    int xi = x0 + dx, yi = y0 + dy;
                    float w = (dx ? lx : 1.f - lx) * (dy ? ly : 1.f - ly);
                    bool ok = (xi >= 0 && xi < WBEV && yi >= 0 && yi < HBEV);
                    int xc = min(max(xi, 0), WBEV - 1);
                    int yc = min(max(yi, 0), HBEV - 1);
                    int idx = yc * WBEV + xc;
                    float gv = (float)vproj[((long)(idx * BS + bb)) * CDIM + h * HD + d];
                    gsum += (ok ? w : 0.f) * gv;
                }
            }
            acc += ew * gsum;
        }
        int cg = (tid >> 3) & 7, jj = tid & 7, kc = tid >> 6;
        As4[kc * 1024 + r * 64 + ((cg ^ (r & 7)) << 3) + jj] = (__bf16)acc;
    }
    __syncthreads();

    // ---- Phase B: op-proj GEMM (K=256) + residual + LN2 ----
    int wave = tid >> 6, lane = tid & 63, quad = lane >> 4, n16 = lane & 15;
    int wn = wave * 64;
    v4f acc2[4] = {};
    for (int k0 = 0; k0 < 256; k0 += 64) {
        __syncthreads();
        #pragma unroll
        for (int i = 0; i < 8; i++) {
            int e = i * 256 + tid;
            int r = e >> 3, c = (e & 7) ^ (r & 7);
            gload_lds16(W + (long)r * 256 + k0 + c * 8, Bs + e * 8);
        }
        __syncthreads();
        int kc = k0 >> 6;
        #pragma unroll
        for (int s = 0; s < 2; s++) {
            v8bf af = *(v8bf*)&As4[kc * 1024 + n16 * 64 + (((quad + s * 4) ^ (n16 & 7))) * 8];
            #pragma unroll
            for (int nj = 0; nj < 4; nj++) {
                int row = wn + nj * 16 + n16;
                v8bf bfr = *(v8bf*)&Bs[row * 64 + (((quad + s * 4) ^ (row & 7))) * 8];
                acc2[nj] = __builtin_amdgcn_mfma_f32_16x16x32_bf16(af, bfr, acc2[nj], 0, 0, 0);
            }
        }
    }

    float y[4][4], s1[4] = {}, s2[4] = {};
    #pragma unroll
    for (int r = 0; r < 4; r++) {
        int m = bm + quad * 4 + r;
        #pragma unroll
        for (int nj = 0; nj < 4; nj++) {
            int nn = wn + nj * 16 + n16;
            float v = acc2[nj][r] + bias[nn] + res[(long)m * 256 + nn];
            y[r][nj] = v;
            s1[r] += v; s2[r] += v * v;
        }
    }
    #pragma unroll
    for (int r = 0; r < 4; r++) {
        #pragma unroll
        for (int off = 1; off < 16; off <<= 1) {
            s1[r] += __shfl_xor(s1[r], off, 16);
            s2[r] += __shfl_xor(s2[r], off, 16);
        }
    }
    if (n16 == 0) {
        #pragma unroll
        for (int r = 0; r < 4; r++) {
            redS[wave * 16 + quad * 4 + r] = s1[r];
            redQ[wave * 16 + quad * 4 + r] = s2[r];
        }
    }
    __syncthreads();
    #pragma unroll
    for (int r = 0; r < 4; r++) {
        int mr = quad * 4 + r;
        float ts = redS[mr] + redS[16 + mr] + redS[32 + mr] + redS[48 + mr];
        float tq = redQ[mr] + redQ[16 + mr] + redQ[32 + mr] + redQ[48 + mr];
        float mean = ts * (1.0f / 256.0f);
        float var = tq * (1.0f / 256.0f) - mean * mean;
        float rinv = rsqrtf(var + 1e-5f);
        int m = bm + mr;
        #pragma unroll
        for (int nj = 0; nj < 4; nj++) {
            int nn = wn + nj * 16 + n16;
            float o = (y[r][nj] - mean) * rinv * g[nn] + beta[nn];
            outf[(long)m * 256 + nn] = o;
            outb[(long)m * 256 + nn] = (__bf16)o;
        }
    }
}

// ============ plain MFMA bf16 GEMM (FFN1), BK=64 ============
template<int TBM, int TBN>
__global__ __launch_bounds__(256) void mgemm_kernel(
    const __bf16* __restrict__ A, const __bf16* __restrict__ W,
    const float* __restrict__ bias, __bf16* __restrict__ Yb,
    int M, int N, int K, int relu, int nx)
{
    constexpr int SZ = TBM * 128 + TBN * 128;
    __shared__ __align__(16) char smem[SZ];
    constexpr int WMF = TBM / 32;
    constexpr int WNF = TBN / 32;
    __bf16* As = (__bf16*)smem;                 // [TBM][64]
    __bf16* Bs = (__bf16*)(smem + TBM * 128);   // [TBN][64]
    int bm = (blockIdx.x / nx) * TBM, bn = (blockIdx.x % nx) * TBN;
    int tid = threadIdx.x;
    int wave = tid >> 6, lane = tid & 63, quad = lane >> 4, n16 = lane & 15;
    int wm = (wave & 1) * (TBM / 2), wn = (wave >> 1) * (TBN / 2);
    v4f acc[WMF][WNF] = {};

    for (int k0 = 0; k0 < K; k0 += 64) {
        __syncthreads();
        #pragma unroll
        for (int i = 0; i < TBM * 8 / 256; i++) {
            int e = i * 256 + tid;
            int r = e >> 3, c = (e & 7) ^ (r & 7);
            int row = bm + r; if (row > M - 1) row = M - 1;
            gload_lds16(A + (long)row * K + k0 + c * 8, As + e * 8);
        }
        #pragma unroll
        for (int i = 0; i < TBN * 8 / 256; i++) {
            int e = i * 256 + tid;
            int r = e >> 3, c = (e & 7) ^ (r & 7);
            gload_lds16(W + (long)(bn + r) * K + k0 + c * 8, Bs + e * 8);
        }
        __syncthreads();
        #pragma unroll
        for (int s = 0; s < 2; s++) {
            v8bf af[WMF], bfr[WNF];
            #pragma unroll
            for (int mi = 0; mi < WMF; mi++) {
                int row = wm + mi * 16 + n16;
                af[mi] = *(v8bf*)&As[row * 64 + (((quad + s * 4) ^ (row & 7))) * 8];
            }
            #pragma unroll
            for (int nj = 0; nj < WNF; nj++) {
                int row = wn + nj * 16 + n16;
                bfr[nj] = *(v8bf*)&Bs[row * 64 + (((quad + s * 4) ^ (row & 7))) * 8];
            }
            #pragma unroll
            for (int mi = 0; mi < WMF; mi++)
                #pragma unroll
                for (int nj = 0; nj < WNF; nj++)
                    acc[mi][nj] = __builtin_amdgcn_mfma_f32_16x16x32_bf16(af[mi], bfr[nj], acc[mi][nj], 0, 0, 0);
        }
    }

    #pragma unroll
    for (int mi = 0; mi < WMF; mi++) {
        #pragma unroll
        for (int r = 0; r < 4; r++) {
            int m = bm + wm + mi * 16 + quad * 4 + r;
            if (m >= M) continue;
            #pragma unroll
            for (int nj = 0; nj < WNF; nj++) {
                int nn = bn + wn + nj * 16 + n16;
                if (nn >= N) continue;
                float v = acc[mi][nj][r] + bias[nn];
                if (relu) v = fmaxf(v, 0.f);
                Yb[(long)m * N + nn] = (__bf16)v;
            }
        }
    }
}

// ============ FFN2 (K=512) + residual + LN3 + transpose-out ============
__global__ __launch_bounds__(256) void gln3_kernel(
    const __bf16* __restrict__ A, const __bf16* __restrict__ W,
    const float* __restrict__ bias, const float* __restrict__ res,
    const float* __restrict__ g, const float* __restrict__ beta,
    float* __restrict__ outf)
{
    __shared__ __align__(16) char smem[35328];
    __bf16* As = (__bf16*)smem;             // [16][64]
    __bf16* Bs = (__bf16*)(smem + 2048);    // [256][64]
    float* redS = (float*)(smem + 34816);
    float* redQ = redS + 64;
    int tid = threadIdx.x;
    int bm = blockIdx.x * 16;
    int wave = tid >> 6, lane = tid & 63, quad = lane >> 4, n16 = lane & 15;
    int wn = wave * 64;
    v4f acc[4] = {};

    for (int k0 = 0; k0 < 512; k0 += 64) {
        __syncthreads();
        if (tid < 128) {
            int e = tid;
            int r = e >> 3, c = (e & 7) ^ (r & 7);
            gload_lds16(A + (long)(bm + r) * 512 + k0 + c * 8, As + e * 8);
        }
        #pragma unroll
        for (int i = 0; i < 8; i++) {
            int e = i * 256 + tid;
            int r = e >> 3, c = (e & 7) ^ (r & 7);
            gload_lds16(W + (long)r * 512 + k0 + c * 8, Bs + e * 8);
        }
        __syncthreads();
        #pragma unroll
        for (int s = 0; s < 2; s++) {
            v8bf af = *(v8bf*)&As[n16 * 64 + (((quad + s * 4) ^ (n16 & 7))) * 8];
            #pragma unroll
            for (int nj = 0; nj < 4; nj++) {
                int row = wn + nj * 16 + n16;
                v8bf bfr = *(v8bf*)&Bs[row * 64 + (((quad + s * 4) ^ (row & 7))) * 8];
                acc[nj] = __builtin_amdgcn_mfma_f32_16x16x32_bf16(af, bfr, acc[nj], 0, 0, 0);
            }
        }
    }

    float y[4][4], s1[4] = {}, s2[4] = {};
    #pragma unroll
    for (int r = 0; r < 4; r++) {
        int m = bm + quad * 4 + r;
        #pragma unroll
        for (int nj = 0; nj < 4; nj++) {
            int nn = wn + nj * 16 + n16;
            float v = acc[nj][r] + bias[nn] + res[(long)m * 256 + nn];
            y[r][nj] = v;
            s1[r] += v; s2[r] += v * v;
        }
    }
    #pragma unroll
    for (int r = 0; r < 4; r++) {
        #pragma unroll
        for (int off = 1; off < 16; off <<= 1) {
            s1[r] += __shfl_xor(s1[r], off, 16);
            s2[r] += __shfl_xor(s2[r], off, 16);
        }
    }
    if (n16 == 0) {
        #pragma unroll
        for (int r = 0; r < 4; r++) {
            redS[wave * 16 + quad * 4 + r] = s1[r];
            redQ[wave * 16 + quad * 4 + r] = s2[r];
        }
    }
    __syncthreads();
    #pragma unroll
    for (int r = 0; r < 4; r++) {
        int mr = quad * 4 + r;
        float ts = redS[mr] + redS[16 + mr] + redS[32 + mr] + redS[48 + mr];
        float tq = redQ[mr] + redQ[16 + mr] + redQ[32 + mr] + redQ[48 + mr];
        float mean = ts * (1.0f / 256.0f);
        float var = tq * (1.0f / 256.0f) - mean * mean;
        float rinv = rsqrtf(var + 1e-5f);
        int m = bm + mr;
        int b = m / NQ, q = m - b * NQ;
        #pragma unroll
        for (int nj = 0; nj < 4; nj++) {
            int nn = wn + nj * 16 + n16;
            float o = (y[r][nj] - mean) * rinv * g[nn] + beta[nn];
            outf[(long)(q * BS + b) * 256 + nn] = o;
        }
    }
}

extern "C" void kernel_launch(void* const* d_in, const int* in_sizes, int n_in,
                              void* d_out, int out_size, void* d_ws, size_t ws_size,
                              hipStream_t stream) {
    const float* query = (const float*)d_in[0];
    const float* value = (const float*)d_in[1];
    const float* qpos  = (const float*)d_in[2];
    const float* refp  = (const float*)d_in[3];
    const float* in_w  = (const float*)d_in[6];
    const float* in_b  = (const float*)d_in[7];
    const float* mha_ow = (const float*)d_in[8];
    const float* mha_ob = (const float*)d_in[9];
    const float* so_w  = (const float*)d_in[10];
    const float* so_b  = (const float*)d_in[11];
    const float* aw_w  = (const float*)d_in[12];
    const float* aw_b  = (const float*)d_in[13];
    const float* vp_w  = (const float*)d_in[14];
    const float* vp_b  = (const float*)d_in[15];
    const float* op_w  = (const float*)d_in[16];
    const float* op_b  = (const float*)d_in[17];
    const float* ffn_w1 = (const float*)d_in[18];
    const float* ffn_b1 = (const float*)d_in[19];
    const float* ffn_w2 = (const float*)d_in[20];
    const float* ffn_b2 = (const float*)d_in[21];
    const float* ln1_g = (const float*)d_in[22];
    const float* ln1_b = (const float*)d_in[23];
    const float* ln2_g = (const float*)d_in[24];
    const float* ln2_b = (const float*)d_in[25];
    const float* ln3_g = (const float*)d_in[26];
    const float* ln3_b = (const float*)d_in[27];
    float* out = (float*)d_out;

    const long NTOK = (long)BS * NQ * CDIM;   // 1,024,000

    float* x      = (float*)d_ws;
    float* qpos_t = x + NTOK;
    float* x1     = qpos_t + NTOK;
    float* x2     = x1 + NTOK;
    float* soaw   = x2 + NTOK;                       // 4000*96
    float* bsmall = soaw + (long)BS * NQ * 96;       // 128
    __bf16* x_bf   = (__bf16*)(bsmall + 128);
    __bf16* xq_bf  = x_bf + NTOK;
    __bf16* qk_bf  = xq_bf + NTOK;                   // 2*NTOK (q|k, stride 512)
    __bf16* vh_bf  = qk_bf + 2 * NTOK;
    __bf16* aA_bf  = vh_bf + NTOK;
    __bf16* x2_bf  = aA_bf + NTOK;
    __bf16* h1_bf  = x2_bf + NTOK;                   // 2*NTOK
    __bf16* vpj_bf = h1_bf + 2 * NTOK;               // 20,480,000
    __bf16* wb     = vpj_bf + (long)BS * NVAL * CDIM;
    __bf16* inw_b  = wb;
    __bf16* mow_b  = wb + 196608;
    __bf16* vpw_b  = wb + 262144;
    __bf16* opw_b  = wb + 327680;
    __bf16* fw1_b  = wb + 393216;
    __bf16* fw2_b  = wb + 524288;
    __bf16* wsmall = wb + 655360;                    // 128x256

    dim3 blk(256);

    prep_all_kernel<<<4673, blk, 0, stream>>>(
        query, qpos, in_w, mha_ow, vp_w, op_w, ffn_w1, ffn_w2,
        so_w, aw_w, so_b, aw_b,
        x, qpos_t, x_bf, xq_bf, wb, wsmall, bsmall);

    // q|k|v in-proj (756) + vgemm chunk 0 (417)
    qkvv_kernel<<<1173, blk, 0, stream>>>(xq_bf, x_bf, inw_b, in_b, qk_bf, vh_bf,
                                          value, vpw_b, vp_b, vpj_bf, 0);

    // flash attention TK=64 (512) + vgemm chunk 1 (417)
    fattnv_kernel<<<929, blk, 0, stream>>>(qk_bf, vh_bf, aA_bf,
                                           value, vpw_b, vp_b, vpj_bf, 417);

    // mha out-proj + res(x) + LN1 + fused soaw projection (250) + chunk 2 (416)
    gln1s_kernel<<<666, blk, 0, stream>>>(
        aA_bf, mow_b, mha_ob, x, ln1_g, ln1_b, qpos_t, wsmall, bsmall,
        x1, soaw, value, vpw_b, vp_b, vpj_bf, 834);

    // fused msdeform sampling + op-proj + res(x1) + LN2 -> x2 fp32 + bf16
    msdsop_kernel<<<250, blk, 0, stream>>>(
        vpj_bf, soaw, refp, opw_b, op_b, x1, ln2_g, ln2_b, x2, x2_bf);

    // FFN1 (relu)
    mgemm_kernel<64, 64><<<504, blk, 0, stream>>>(
        x2_bf, fw1_b, ffn_b1, h1_bf, BS * NQ, 512, 256, 1, 8);

    // FFN2 + residual(x2) + LN3 + transpose -> out
    gln3_kernel<<<250, blk, 0, stream>>>(
        h1_bf, fw2_b, ffn_b2, x2, ln3_g, ln3_b, out);
}

// Round 2
// 274.938 us; speedup vs baseline: 1.2570x; 1.2570x over previous
//
#include <hip/hip_runtime.h>
#include <hip/hip_bf16.h>
#include <cmath>

#define BS   4
#define NQ   1000
#define CDIM 256
#define NH   8
#define HD   32
#define NVAL 20000
#define FFND 512
#define PN   4
#define WBEV 100
#define HBEV 200
#define TK   64

typedef __bf16 v8bf __attribute__((ext_vector_type(8)));
typedef float  v4f  __attribute__((ext_vector_type(4)));

__device__ __forceinline__ void gload_lds16(const void* g, void* l) {
    __builtin_amdgcn_global_load_lds(
        (const __attribute__((address_space(1))) unsigned int*)g,
        (__attribute__((address_space(3))) unsigned int*)l, 16, 0, 0);
}

// ============ vgemm rider: value-proj, 64 rows x 256 cols per block =========
// value (fp32) is read exactly ONCE across all 1250 blocks.
// Needs 40960 B of smem.
__device__ __forceinline__ void vgemm64_block(
    int vb, const float* __restrict__ value, const __bf16* __restrict__ Wv,
    const float* __restrict__ bv, __bf16* __restrict__ vpj, char* smem)
{
    __bf16* As = (__bf16*)smem;             // [64][64]
    __bf16* Bs = (__bf16*)(smem + 8192);    // [256][64]
    int tid = threadIdx.x;
    int wave = tid >> 6, lane = tid & 63, quad = lane >> 4, n16 = lane & 15;
    int bm = vb * 64;
    int wm = (wave & 1) * 32, wn = (wave >> 1) * 128;
    v4f acc[2][8] = {};

    for (int k0 = 0; k0 < 256; k0 += 64) {
        float4 fa[2][2];
        #pragma unroll
        for (int i = 0; i < 2; i++) {
            int e = i * 256 + tid;
            int r = e >> 3, c = (e & 7) ^ (r & 7);
            const float* p = value + (long)(bm + r) * 256 + k0 + c * 8;
            fa[i][0] = *(const float4*)p;
            fa[i][1] = *(const float4*)(p + 4);
        }
        __syncthreads();
        #pragma unroll
        for (int i = 0; i < 2; i++) {
            int e = i * 256 + tid;
            v8bf v;
            v[0] = (__bf16)fa[i][0].x; v[1] = (__bf16)fa[i][0].y;
            v[2] = (__bf16)fa[i][0].z; v[3] = (__bf16)fa[i][0].w;
            v[4] = (__bf16)fa[i][1].x; v[5] = (__bf16)fa[i][1].y;
            v[6] = (__bf16)fa[i][1].z; v[7] = (__bf16)fa[i][1].w;
            *(v8bf*)(As + e * 8) = v;
        }
        #pragma unroll
        for (int i = 0; i < 8; i++) {
            int e = i * 256 + tid;
            int r = e >> 3, c = (e & 7) ^ (r & 7);
            gload_lds16(Wv + (long)r * 256 + k0 + c * 8, Bs + e * 8);
        }
        __syncthreads();
        #pragma unroll
        for (int s = 0; s < 2; s++) {
            v8bf af[2], bfr[8];
            #pragma unroll
            for (int mi = 0; mi < 2; mi++) {
                int row = wm + mi * 16 + n16;
                af[mi] = *(v8bf*)&As[row * 64 + (((quad + s * 4) ^ (row & 7))) * 8];
            }
            #pragma unroll
            for (int nj = 0; nj < 8; nj++) {
                int row = wn + nj * 16 + n16;
                bfr[nj] = *(v8bf*)&Bs[row * 64 + (((quad + s * 4) ^ (row & 7))) * 8];
            }
            #pragma unroll
            for (int mi = 0; mi < 2; mi++)
                #pragma unroll
                for (int nj = 0; nj < 8; nj++)
                    acc[mi][nj] = __builtin_amdgcn_mfma_f32_16x16x32_bf16(af[mi], bfr[nj], acc[mi][nj], 0, 0, 0);
        }
    }
    #pragma unroll
    for (int mi = 0; mi < 2; mi++) {
        #pragma unroll
        for (int r = 0; r < 4; r++) {
            int m = bm + wm + mi * 16 + quad * 4 + r;
            #pragma unroll
            for (int nj = 0; nj < 8; nj++) {
                int nn = wn + nj * 16 + n16;
                vpj[(long)m * 256 + nn] = (__bf16)(acc[mi][nj][r] + bv[nn]);
            }
        }
    }
}

// ============ prep_all: weight cast | prep | soaw pack ============
__global__ __launch_bounds__(256) void prep_all_kernel(
    const float* __restrict__ query, const float* __restrict__ qpos,
    const float* __restrict__ in_w, const float* __restrict__ mha_ow,
    const float* __restrict__ vp_w, const float* __restrict__ op_w,
    const float* __restrict__ ffn_w1, const float* __restrict__ ffn_w2,
    const float* __restrict__ so_w, const float* __restrict__ aw_w,
    const float* __restrict__ so_b, const float* __restrict__ aw_b,
    float* __restrict__ x, float* __restrict__ qpos_t,
    __bf16* __restrict__ x_bf, __bf16* __restrict__ xq_bf,
    __bf16* __restrict__ wb, __bf16* __restrict__ wsmall,
    float* __restrict__ bsmall)
{
    int blk = blockIdx.x, tid = threadIdx.x;
    if (blk < 640) {
        long e = ((long)blk * 256 + tid) * 4;
        const float* src; long off;
        if      (e < 196608) { src = in_w;   off = e; }
        else if (e < 262144) { src = mha_ow; off = e - 196608; }
        else if (e < 327680) { src = vp_w;   off = e - 262144; }
        else if (e < 393216) { src = op_w;   off = e - 327680; }
        else if (e < 524288) { src = ffn_w1; off = e - 393216; }
        else                 { src = ffn_w2; off = e - 524288; }
        float4 v = *(const float4*)(src + off);
        __bf16* d = wb + e;
        d[0] = (__bf16)v.x; d[1] = (__bf16)v.y; d[2] = (__bf16)v.z; d[3] = (__bf16)v.w;
    } else if (blk < 4640) {
        int qb = blk - 640;
        int q = qb / BS, b = qb % BS;
        float qv = query[(q * BS + b) * CDIM + tid];
        float pv = qpos [(q * BS + b) * CDIM + tid];
        int o = (b * NQ + q) * CDIM + tid;
        x[o] = qv; qpos_t[o] = pv;
        x_bf[o] = (__bf16)qv; xq_bf[o] = (__bf16)(qv + pv);
    } else if (blk < 4672) {
        long e = ((long)(blk - 4640) * 256 + tid) * 4;
        int row = (int)(e >> 8), col = (int)(e & 255);
        float4 v = {0.f, 0.f, 0.f, 0.f};
        if (row < 64)      v = *(const float4*)(so_w + row * 256 + col);
        else if (row < 96) v = *(const float4*)(aw_w + (row - 64) * 256 + col);
        __bf16* d = wsmall + e;
        d[0] = (__bf16)v.x; d[1] = (__bf16)v.y; d[2] = (__bf16)v.z; d[3] = (__bf16)v.w;
    } else {
        if (tid < 128) bsmall[tid] = tid < 64 ? so_b[tid] : (tid < 96 ? aw_b[tid - 64] : 0.f);
    }
}

// ============ fused q|k|v projection (756 blocks) + vgemm rider ============
__global__ __launch_bounds__(256) void qkvv_kernel(
    const __bf16* __restrict__ xq, const __bf16* __restrict__ xv,
    const __bf16* __restrict__ W, const float* __restrict__ bias,
    __bf16* __restrict__ qk, __bf16* __restrict__ vh,
    const float* __restrict__ value, const __bf16* __restrict__ Wv,
    const float* __restrict__ bv, __bf16* __restrict__ vpj, int voff)
{
    __shared__ __align__(16) char smem[40960];
    int tid = threadIdx.x;
    if ((int)blockIdx.x >= 756) {
        vgemm64_block(blockIdx.x - 756 + voff, value, Wv, bv, vpj, smem);
        return;
    }
    int blk = blockIdx.x;
    int bn = (blk % 12) * 64, bm = (blk / 12) * 64;
    __bf16* As = (__bf16*)smem;             // [64][64]
    __bf16* Bs = (__bf16*)(smem + 8192);    // [64][64]
    const __bf16* A = (bn < 512) ? xq : xv;
    int wave = tid >> 6, lane = tid & 63, quad = lane >> 4, n16 = lane & 15;
    int wm = (wave & 1) * 32, wn = (wave >> 1) * 32;
    v4f acc[2][2] = {};

    for (int k0 = 0; k0 < 256; k0 += 64) {
        __syncthreads();
        #pragma unroll
        for (int i = 0; i < 2; i++) {
            int e = i * 256 + tid;
            int r = e >> 3, c = (e & 7) ^ (r & 7);
            int row = bm + r; if (row > BS * NQ - 1) row = BS * NQ - 1;
            gload_lds16(A + (long)row * 256 + k0 + c * 8, As + e * 8);
        }
        #pragma unroll
        for (int i = 0; i < 2; i++) {
            int e = i * 256 + tid;
            int r = e >> 3, c = (e & 7) ^ (r & 7);
            gload_lds16(W + (long)(bn + r) * 256 + k0 + c * 8, Bs + e * 8);
        }
        __syncthreads();
        #pragma unroll
        for (int s = 0; s < 2; s++) {
            v8bf af[2], bfr[2];
            #pragma unroll
            for (int mi = 0; mi < 2; mi++) {
                int row = wm + mi * 16 + n16;
                af[mi] = *(v8bf*)&As[row * 64 + (((quad + s * 4) ^ (row & 7))) * 8];
            }
            #pragma unroll
            for (int nj = 0; nj < 2; nj++) {
                int row = wn + nj * 16 + n16;
                bfr[nj] = *(v8bf*)&Bs[row * 64 + (((quad + s * 4) ^ (row & 7))) * 8];
            }
            #pragma unroll
            for (int mi = 0; mi < 2; mi++)
                #pragma unroll
                for (int nj = 0; nj < 2; nj++)
                    acc[mi][nj] = __builtin_amdgcn_mfma_f32_16x16x32_bf16(af[mi], bfr[nj], acc[mi][nj], 0, 0, 0);
        }
    }

    #pragma unroll
    for (int mi = 0; mi < 2; mi++) {
        #pragma unroll
        for (int r = 0; r < 4; r++) {
            int m = bm + wm + mi * 16 + quad * 4 + r;
            if (m >= BS * NQ) continue;
            #pragma unroll
            for (int nj = 0; nj < 2; nj++) {
                int nn = bn + wn + nj * 16 + n16;
                float v = acc[mi][nj][r] + bias[nn];
                if (nn < 512) qk[(long)m * 512 + nn] = (__bf16)v;
                else          vh[(long)m * 256 + (nn - 512)] = (__bf16)v;
            }
        }
    }
}

// ============ flash attention, TK=64 (512 blocks) + vgemm rider ============
__global__ __launch_bounds__(256) void fattnv_kernel(
    const __bf16* __restrict__ qk, const __bf16* __restrict__ vh,
    __bf16* __restrict__ aout,
    const float* __restrict__ value, const __bf16* __restrict__ Wv,
    const float* __restrict__ bv, __bf16* __restrict__ vpj, int voff)
{
    __shared__ __align__(16) char smem[40960];
    int tid = threadIdx.x;
    if ((int)blockIdx.x >= 512) {
        vgemm64_block(blockIdx.x - 512 + voff, value, Wv, bv, vpj, smem);
        return;
    }
    int fb = blockIdx.x;
    int qt = fb & 15, h = (fb >> 4) & 7, b = fb >> 7;
    __bf16* Ks = (__bf16*)smem;             // [2][64][40]  = 10240 B
    __bf16* Vt = (__bf16*)(smem + 10240);   // [2][32][72]  =  9216 B
    __bf16* Pl = (__bf16*)(smem + 19456);   // [4][16][72]  =  9216 B
    int wave = tid >> 6, lane = tid & 63, quad = lane >> 4, n = lane & 15;
    int q0 = qt * 64 + wave * 16;
    const float scale = 0.17677669529663687f;
    const float M0 = 8.0f;

    int qrow = q0 + n; if (qrow > NQ - 1) qrow = NQ - 1;
    v8bf aq = *(const v8bf*)(qk + (long)(b * NQ + qrow) * 512 + h * HD + quad * 8);

    v4f o0 = {}, o1 = {};
    float lp[4] = {0.f, 0.f, 0.f, 0.f};

    int sv = tid >> 7;          // 0: stage K, 1: stage V
    int t2 = tid & 127;
    int key = t2 & 63;
    int d16 = (t2 >> 6) * 16;

    v8bf stg0, stg1;
    auto loadtile = [&](int k0) {
        int krow = k0 + key; if (krow > NQ - 1) krow = NQ - 1;
        const __bf16* p = sv ? (vh + (long)(b * NQ + krow) * CDIM + h * HD + d16)
                             : (qk + (long)(b * NQ + krow) * 512 + 256 + h * HD + d16);
        stg0 = *(const v8bf*)p;
        stg1 = *(const v8bf*)(p + 8);
    };

    loadtile(0);
    int pb = 0;
    for (int k0 = 0; k0 < NQ; k0 += TK) {
        if (sv == 0) {
            *(v8bf*)&Ks[(pb * 64 + key) * 40 + d16]     = stg0;
            *(v8bf*)&Ks[(pb * 64 + key) * 40 + d16 + 8] = stg1;
        } else {
            #pragma unroll
            for (int j = 0; j < 8; j++) {
                Vt[(pb * 32 + d16 + j) * 72 + key]            = stg0[j];
                Vt[(pb * 32 + d16 + 8 + j) * 72 + (key ^ 16)] = stg1[j];
            }
        }
        if (k0 + TK < NQ) loadtile(k0 + TK);
        __syncthreads();

        v8bf bk0 = *(v8bf*)&Ks[(pb * 64 +      n) * 40 + quad * 8];
        v8bf bk1 = *(v8bf*)&Ks[(pb * 64 + 16 + n) * 40 + quad * 8];
        v8bf bk2 = *(v8bf*)&Ks[(pb * 64 + 32 + n) * 40 + quad * 8];
        v8bf bk3 = *(v8bf*)&Ks[(pb * 64 + 48 + n) * 40 + quad * 8];
        v4f z = {};
        v4f S0 = __builtin_amdgcn_mfma_f32_16x16x32_bf16(aq, bk0, z, 0, 0, 0);
        v4f S1 = __builtin_amdgcn_mfma_f32_16x16x32_bf16(aq, bk1, z, 0, 0, 0);
        v4f S2 = __builtin_amdgcn_mfma_f32_16x16x32_bf16(aq, bk2, z, 0, 0, 0);
        v4f S3 = __builtin_amdgcn_mfma_f32_16x16x32_bf16(aq, bk3, z, 0, 0, 0);

        bool last = (k0 + TK > NQ);
        float p0[4], p1[4], p2[4], p3[4];
        #pragma unroll
        for (int r = 0; r < 4; r++) {
            p0[r] = __expf(fmaf(S0[r], scale, -M0));
            p1[r] = __expf(fmaf(S1[r], scale, -M0));
            p2[r] = __expf(fmaf(S2[r], scale, -M0));
            p3[r] = __expf(fmaf(S3[r], scale, -M0));
            if (last) {
                if (k0 + 32 + n >= NQ) p2[r] = 0.f;
                if (k0 + 48 + n >= NQ) p3[r] = 0.f;
            }
            lp[r] += p0[r] + p1[r] + p2[r] + p3[r];
        }
        #pragma unroll
        for (int r = 0; r < 4; r++) {
            __bf16* pp = &Pl[(wave * 16 + quad * 4 + r) * 72];
            pp[n]      = (__bf16)p0[r];
            pp[16 + n] = (__bf16)p1[r];
            pp[32 + n] = (__bf16)p2[r];
            pp[48 + n] = (__bf16)p3[r];
        }
        asm volatile("s_waitcnt lgkmcnt(0)" ::: "memory");
        v8bf ap0 = *(v8bf*)&Pl[(wave * 16 + n) * 72 + quad * 8];
        v8bf ap1 = *(v8bf*)&Pl[(wave * 16 + n) * 72 + 32 + quad * 8];
        int swz = ((n >> 3) & 1) << 4;
        int c0 = (quad * 8) ^ swz;
        int c1 = (32 + quad * 8) ^ swz;
        v8bf bv00 = *(v8bf*)&Vt[(pb * 32 +      n) * 72 + c0];
        v8bf bv01 = *(v8bf*)&Vt[(pb * 32 +      n) * 72 + c1];
        v8bf bv10 = *(v8bf*)&Vt[(pb * 32 + 16 + n) * 72 + c0];
        v8bf bv11 = *(v8bf*)&Vt[(pb * 32 + 16 + n) * 72 + c1];
        o0 = __builtin_amdgcn_mfma_f32_16x16x32_bf16(ap0, bv00, o0, 0, 0, 0);
        o0 = __builtin_amdgcn_mfma_f32_16x16x32_bf16(ap1, bv01, o0, 0, 0, 0);
        o1 = __builtin_amdgcn_mfma_f32_16x16x32_bf16(ap0, bv10, o1, 0, 0, 0);
        o1 = __builtin_amdgcn_mfma_f32_16x16x32_bf16(ap1, bv11, o1, 0, 0, 0);
        pb ^= 1;
    }

    #pragma unroll
    for (int r = 0; r < 4; r++) {
        float l = lp[r];
        #pragma unroll
        for (int off = 1; off < 16; off <<= 1) l += __shfl_xor(l, off, 16);
        int q = q0 + quad * 4 + r;
        if (q < NQ) {
            float invl = 1.0f / l;
            __bf16* op = aout + ((long)(b * NQ + q) * CDIM + h * HD);
            op[n]      = (__bf16)(o0[r] * invl);
            op[16 + n] = (__bf16)(o1[r] * invl);
        }
    }
}

// ==== mha out-proj + res + LN1 + (LN1out+qpos -> soaw projection), rider ====
__global__ __launch_bounds__(256) void gln1s_kernel(
    const __bf16* __restrict__ A, const __bf16* __restrict__ W,
    const float* __restrict__ bias, const float* __restrict__ res,
    const float* __restrict__ g, const float* __restrict__ beta,
    const float* __restrict__ qpos_t,
    const __bf16* __restrict__ Wsm, const float* __restrict__ bsm,
    float* __restrict__ outf, float* __restrict__ soawO,
    const float* __restrict__ value, const __bf16* __restrict__ Wv,
    const float* __restrict__ bv, __bf16* __restrict__ vpj, int voff)
{
    __shared__ __align__(16) char smem[43776];
    int tid = threadIdx.x;
    if ((int)blockIdx.x >= 250) {
        vgemm64_block(blockIdx.x - 250 + voff, value, Wv, bv, vpj, smem);
        return;
    }
    __bf16* As  = (__bf16*)smem;             // [16][64]
    __bf16* Bs  = (__bf16*)(smem + 2048);    // [256][64]
    __bf16* Axq = (__bf16*)(smem + 34816);   // [16][264]
    float* redS = (float*)(smem + 43264);    // [64]
    float* redQ = redS + 64;                 // [64]
    int bm = blockIdx.x * 16;
    int wave = tid >> 6, lane = tid & 63, quad = lane >> 4, n16 = lane & 15;
    int wn = wave * 64;
    v4f acc[4] = {};

    for (int k0 = 0; k0 < 256; k0 += 64) {
        __syncthreads();
        if (tid < 128) {
            int e = tid;
            int r = e >> 3, c = (e & 7) ^ (r & 7);
            gload_lds16(A + (long)(bm + r) * 256 + k0 + c * 8, As + e * 8);
        }
        #pragma unroll
        for (int i = 0; i < 8; i++) {
            int e = i * 256 + tid;
            int r = e >> 3, c = (e & 7) ^ (r & 7);
            gload_lds16(W + (long)r * 256 + k0 + c * 8, Bs + e * 8);
        }
        __syncthreads();
        #pragma unroll
        for (int s = 0; s < 2; s++) {
            v8bf af = *(v8bf*)&As[n16 * 64 + (((quad + s * 4) ^ (n16 & 7))) * 8];
            #pragma unroll
            for (int nj = 0; nj < 4; nj++) {
                int row = wn + nj * 16 + n16;
                v8bf bfr = *(v8bf*)&Bs[row * 64 + (((quad + s * 4) ^ (row & 7))) * 8];
                acc[nj] = __builtin_amdgcn_mfma_f32_16x16x32_bf16(af, bfr, acc[nj], 0, 0, 0);
            }
        }
    }

    float y[4][4], s1[4] = {}, s2[4] = {};
    #pragma unroll
    for (int r = 0; r < 4; r++) {
        int m = bm + quad * 4 + r;
        #pragma unroll
        for (int nj = 0; nj < 4; nj++) {
            int nn = wn + nj * 16 + n16;
            float v = acc[nj][r] + bias[nn] + res[(long)m * 256 + nn];
            y[r][nj] = v;
            s1[r] += v; s2[r] += v * v;
        }
    }
    #pragma unroll
    for (int r = 0; r < 4; r++) {
        #pragma unroll
        for (int off = 1; off < 16; off <<= 1) {
            s1[r] += __shfl_xor(s1[r], off, 16);
            s2[r] += __shfl_xor(s2[r], off, 16);
        }
    }
    if (n16 == 0) {
        #pragma unroll
        for (int r = 0; r < 4; r++) {
            redS[wave * 16 + quad * 4 + r] = s1[r];
            redQ[wave * 16 + quad * 4 + r] = s2[r];
        }
    }
    __syncthreads();
    #pragma unroll
    for (int r = 0; r < 4; r++) {
        int mr = quad * 4 + r;
        float ts = redS[mr] + redS[16 + mr] + redS[32 + mr] + redS[48 + mr];
        float tq = redQ[mr] + redQ[16 + mr] + redQ[32 + mr] + redQ[48 + mr];
        float mean = ts * (1.0f / 256.0f);
        float var = tq * (1.0f / 256.0f) - mean * mean;
        float rinv = rsqrtf(var + 1e-5f);
        int m = bm + mr;
        #pragma unroll
        for (int nj = 0; nj < 4; nj++) {
            int nn = wn + nj * 16 + n16;
            float o = (y[r][nj] - mean) * rinv * g[nn] + beta[nn];
            outf[(long)m * 256 + nn] = o;
            Axq[mr * 264 + nn] = (__bf16)(o + qpos_t[(long)m * 256 + nn]);
        }
    }
    __syncthreads();
    // soaw projection: 16 x 96, K=256, waves 0..2 handle 32 cols each
    if (wave < 3) {
        v4f sacc[2] = {};
        #pragma unroll
        for (int k0 = 0; k0 < 256; k0 += 32) {
            v8bf af = *(v8bf*)&Axq[n16 * 264 + k0 + quad * 8];
            #pragma unroll
            for (int t = 0; t < 2; t++) {
                int col = wave * 32 + t * 16 + n16;
                v8bf bw = *(const v8bf*)(Wsm + (long)col * 256 + k0 + quad * 8);
                sacc[t] = __builtin_amdgcn_mfma_f32_16x16x32_bf16(af, bw, sacc[t], 0, 0, 0);
            }
        }
        #pragma unroll
        for (int t = 0; t < 2; t++)
            #pragma unroll
            for (int r = 0; r < 4; r++) {
                int mm = bm + quad * 4 + r;
                int col = wave * 32 + t * 16 + n16;
                soawO[(long)mm * 96 + col] = sacc[t][r] + bsm[col];
            }
    }
}

// ============ msdeform bilinear sampling (4000 blocks, high TLP) ============
__global__ __launch_bounds__(256) void msds_kernel(
    const __bf16* __restrict__ vproj, const float* __restrict__ soaw,
    const float* __restrict__ refp, __bf16* __restrict__ out)
{
    int bq = blockIdx.x; int b = bq / NQ; int q = bq % NQ;
    int t = threadIdx.x; int h = t / HD; int d = t % HD;
    float rx = refp[(b * NQ + q) * 2 + 0];
    float ry = refp[(b * NQ + q) * 2 + 1];
    const float* rowp = soaw + (long)(b * NQ + q) * 96;
    const float* offp = rowp + h * 8;
    const float* awp  = rowp + 64 + h * 4;
    float a0 = awp[0], a1 = awp[1], a2 = awp[2], a3 = awp[3];
    float m = fmaxf(fmaxf(a0, a1), fmaxf(a2, a3));
    float e0 = __expf(a0 - m), e1 = __expf(a1 - m), e2 = __expf(a2 - m), e3 = __expf(a3 - m);
    float invs = 1.0f / (e0 + e1 + e2 + e3);
    float acc = 0.f;
    #pragma unroll
    for (int p = 0; p < PN; p++) {
        float ew = (p == 0 ? e0 : p == 1 ? e1 : p == 2 ? e2 : e3) * invs;
        float xim = rx * (float)WBEV + offp[p * 2 + 0] - 0.5f;
        float yim = ry * (float)HBEV + offp[p * 2 + 1] - 0.5f;
        float x0f = floorf(xim), y0f = floorf(yim);
        float lx = xim - x0f, ly = yim - y0f;
        int x0 = (int)x0f, y0 = (int)y0f;
        float gsum = 0.f;
        #pragma unroll
        for (int dy = 0; dy < 2; dy++) {
            #pragma unroll
            for (int dx = 0; dx < 2; dx++) {
                int xi = x0 + dx, yi = y0 + dy;
                float w = (dx ? lx : 1.f - lx) * (dy ? ly : 1.f - ly);
                bool ok = (xi >= 0 && xi < WBEV && yi >= 0 && yi < HBEV);
                int xc = min(max(xi, 0), WBEV - 1);
                int yc = min(max(yi, 0), HBEV - 1);
                int idx = yc * WBEV + xc;
                float gv = (float)vproj[((long)(idx * BS + b)) * CDIM + h * HD + d];
                gsum += (ok ? w : 0.f) * gv;
            }
        }
        acc += ew * gsum;
    }
    out[(b * NQ + q) * CDIM + h * HD + d] = (__bf16)acc;
}

// ============ op-proj (K=256) + residual + LN2 -> fp32 + bf16 ============
__global__ __launch_bounds__(256) void gln2_kernel(
    const __bf16* __restrict__ A, const __bf16* __restrict__ W,
    const float* __restrict__ bias, const float* __restrict__ res,
    const float* __restrict__ g, const float* __restrict__ beta,
    float* __restrict__ outf, __bf16* __restrict__ outb)
{
    __shared__ __align__(16) char smem[35328];
    __bf16* As = (__bf16*)smem;             // [16][64]
    __bf16* Bs = (__bf16*)(smem + 2048);    // [256][64]
    float* redS = (float*)(smem + 34816);
    float* redQ = redS + 64;
    int tid = threadIdx.x;
    int bm = blockIdx.x * 16;
    int wave = tid >> 6, lane = tid & 63, quad = lane >> 4, n16 = lane & 15;
    int wn = wave * 64;
    v4f acc[4] = {};

    for (int k0 = 0; k0 < 256; k0 += 64) {
        __syncthreads();
        if (tid < 128) {
            int e = tid;
            int r = e >> 3, c = (e & 7) ^ (r & 7);
            gload_lds16(A + (long)(bm + r) * 256 + k0 + c * 8, As + e * 8);
        }
        #pragma unroll
        for (int i = 0; i < 8; i++) {
            int e = i * 256 + tid;
            int r = e >> 3, c = (e & 7) ^ (r & 7);
            gload_lds16(W + (long)r * 256 + k0 + c * 8, Bs + e * 8);
        }
        __syncthreads();
        #pragma unroll
        for (int s = 0; s < 2; s++) {
            v8bf af = *(v8bf*)&As[n16 * 64 + (((quad + s * 4) ^ (n16 & 7))) * 8];
            #pragma unroll
            for (int nj = 0; nj < 4; nj++) {
                int row = wn + nj * 16 + n16;
                v8bf bfr = *(v8bf*)&Bs[row * 64 + (((quad + s * 4) ^ (row & 7))) * 8];
                acc[nj] = __builtin_amdgcn_mfma_f32_16x16x32_bf16(af, bfr, acc[nj], 0, 0, 0);
            }
        }
    }

    float y[4][4], s1[4] = {}, s2[4] = {};
    #pragma unroll
    for (int r = 0; r < 4; r++) {
        int m = bm + quad * 4 + r;
        #pragma unroll
        for (int nj = 0; nj < 4; nj++) {
            int nn = wn + nj * 16 + n16;
            float v = acc[nj][r] + bias[nn] + res[(long)m * 256 + nn];
            y[r][nj] = v;
            s1[r] += v; s2[r] += v * v;
        }
    }
    #pragma unroll
    for (int r = 0; r < 4; r++) {
        #pragma unroll
        for (int off = 1; off < 16; off <<= 1) {
            s1[r] += __shfl_xor(s1[r], off, 16);
            s2[r] += __shfl_xor(s2[r], off, 16);
        }
    }
    if (n16 == 0) {
        #pragma unroll
        for (int r = 0; r < 4; r++) {
            redS[wave * 16 + quad * 4 + r] = s1[r];
            redQ[wave * 16 + quad * 4 + r] = s2[r];
        }
    }
    __syncthreads();
    #pragma unroll
    for (int r = 0; r < 4; r++) {
        int mr = quad * 4 + r;
        float ts = redS[mr] + redS[16 + mr] + redS[32 + mr] + redS[48 + mr];
        float tq = redQ[mr] + redQ[16 + mr] + redQ[32 + mr] + redQ[48 + mr];
        float mean = ts * (1.0f / 256.0f);
        float var = tq * (1.0f / 256.0f) - mean * mean;
        float rinv = rsqrtf(var + 1e-5f);
        int m = bm + mr;
        #pragma unroll
        for (int nj = 0; nj < 4; nj++) {
            int nn = wn + nj * 16 + n16;
            float o = (y[r][nj] - mean) * rinv * g[nn] + beta[nn];
            outf[(long)m * 256 + nn] = o;
            outb[(long)m * 256 + nn] = (__bf16)o;
        }
    }
}

// ============ plain MFMA bf16 GEMM (FFN1), BK=64 ============
template<int TBM, int TBN>
__global__ __launch_bounds__(256) void mgemm_kernel(
    const __bf16* __restrict__ A, const __bf16* __restrict__ W,
    const float* __restrict__ bias, __bf16* __restrict__ Yb,
    int M, int N, int K, int relu, int nx)
{
    constexpr int SZ = TBM * 128 + TBN * 128;
    __shared__ __align__(16) char smem[SZ];
    constexpr int WMF = TBM / 32;
    constexpr int WNF = TBN / 32;
    __bf16* As = (__bf16*)smem;                 // [TBM][64]
    __bf16* Bs = (__bf16*)(smem + TBM * 128);   // [TBN][64]
    int bm = (blockIdx.x / nx) * TBM, bn = (blockIdx.x % nx) * TBN;
    int tid = threadIdx.x;
    int wave = tid >> 6, lane = tid & 63, quad = lane >> 4, n16 = lane & 15;
    int wm = (wave & 1) * (TBM / 2), wn = (wave >> 1) * (TBN / 2);
    v4f acc[WMF][WNF] = {};

    for (int k0 = 0; k0 < K; k0 += 64) {
        __syncthreads();
        #pragma unroll
        for (int i = 0; i < TBM * 8 / 256; i++) {
            int e = i * 256 + tid;
            int r = e >> 3, c = (e & 7) ^ (r & 7);
            int row = bm + r; if (row > M - 1) row = M - 1;
            gload_lds16(A + (long)row * K + k0 + c * 8, As + e * 8);
        }
        #pragma unroll
        for (int i = 0; i < TBN * 8 / 256; i++) {
            int e = i * 256 + tid;
            int r = e >> 3, c = (e & 7) ^ (r & 7);
            gload_lds16(W + (long)(bn + r) * K + k0 + c * 8, Bs + e * 8);
        }
        __syncthreads();
        #pragma unroll
        for (int s = 0; s < 2; s++) {
            v8bf af[WMF], bfr[WNF];
            #pragma unroll
            for (int mi = 0; mi < WMF; mi++) {
                int row = wm + mi * 16 + n16;
                af[mi] = *(v8bf*)&As[row * 64 + (((quad + s * 4) ^ (row & 7))) * 8];
            }
            #pragma unroll
            for (int nj = 0; nj < WNF; nj++) {
                int row = wn + nj * 16 + n16;
                bfr[nj] = *(v8bf*)&Bs[row * 64 + (((quad + s * 4) ^ (row & 7))) * 8];
            }
            #pragma unroll
            for (int mi = 0; mi < WMF; mi++)
                #pragma unroll
                for (int nj = 0; nj < WNF; nj++)
                    acc[mi][nj] = __builtin_amdgcn_mfma_f32_16x16x32_bf16(af[mi], bfr[nj], acc[mi][nj], 0, 0, 0);
        }
    }

    #pragma unroll
    for (int mi = 0; mi < WMF; mi++) {
        #pragma unroll
        for (int r = 0; r < 4; r++) {
            int m = bm + wm + mi * 16 + quad * 4 + r;
            if (m >= M) continue;
            #pragma unroll
            for (int nj = 0; nj < WNF; nj++) {
                int nn = bn + wn + nj * 16 + n16;
                if (nn >= N) continue;
                float v = acc[mi][nj][r] + bias[nn];
                if (relu) v = fmaxf(v, 0.f);
                Yb[(long)m * N + nn] = (__bf16)v;
            }
        }
    }
}

// ============ FFN2 (K=512) + residual + LN3 + transpose-out ============
__global__ __launch_bounds__(256) void gln3_kernel(
    const __bf16* __restrict__ A, const __bf16* __restrict__ W,
    const float* __restrict__ bias, const float* __restrict__ res,
    const float* __restrict__ g, const float* __restrict__ beta,
    float* __restrict__ outf)
{
    __shared__ __align__(16) char smem[35328];
    __bf16* As = (__bf16*)smem;             // [16][64]
    __bf16* Bs = (__bf16*)(smem + 2048);    // [256][64]
    float* redS = (float*)(smem + 34816);
    float* redQ = redS + 64;
    int tid = threadIdx.x;
    int bm = blockIdx.x * 16;
    int wave = tid >> 6, lane = tid & 63, quad = lane >> 4, n16 = lane & 15;
    int wn = wave * 64;
    v4f acc[4] = {};

    for (int k0 = 0; k0 < 512; k0 += 64) {
        __syncthreads();
        if (tid < 128) {
            int e = tid;
            int r = e >> 3, c = (e & 7) ^ (r & 7);
            gload_lds16(A + (long)(bm + r) * 512 + k0 + c * 8, As + e * 8);
        }
        #pragma unroll
        for (int i = 0; i < 8; i++) {
            int e = i * 256 + tid;
            int r = e >> 3, c = (e & 7) ^ (r & 7);
            gload_lds16(W + (long)r * 512 + k0 + c * 8, Bs + e * 8);
        }
        __syncthreads();
        #pragma unroll
        for (int s = 0; s < 2; s++) {
            v8bf af = *(v8bf*)&As[n16 * 64 + (((quad + s * 4) ^ (n16 & 7))) * 8];
            #pragma unroll
            for (int nj = 0; nj < 4; nj++) {
                int row = wn + nj * 16 + n16;
                v8bf bfr = *(v8bf*)&Bs[row * 64 + (((quad + s * 4) ^ (row & 7))) * 8];
                acc[nj] = __builtin_amdgcn_mfma_f32_16x16x32_bf16(af, bfr, acc[nj], 0, 0, 0);
            }
        }
    }

    float y[4][4], s1[4] = {}, s2[4] = {};
    #pragma unroll
    for (int r = 0; r < 4; r++) {
        int m = bm + quad * 4 + r;
        #pragma unroll
        for (int nj = 0; nj < 4; nj++) {
            int nn = wn + nj * 16 + n16;
            float v = acc[nj][r] + bias[nn] + res[(long)m * 256 + nn];
            y[r][nj] = v;
            s1[r] += v; s2[r] += v * v;
        }
    }
    #pragma unroll
    for (int r = 0; r < 4; r++) {
        #pragma unroll
        for (int off = 1; off < 16; off <<= 1) {
            s1[r] += __shfl_xor(s1[r], off, 16);
            s2[r] += __shfl_xor(s2[r], off, 16);
        }
    }
    if (n16 == 0) {
        #pragma unroll
        for (int r = 0; r < 4; r++) {
            redS[wave * 16 + quad * 4 + r] = s1[r];
            redQ[wave * 16 + quad * 4 + r] = s2[r];
        }
    }
    __syncthreads();
    #pragma unroll
    for (int r = 0; r < 4; r++) {
        int mr = quad * 4 + r;
        float ts = redS[mr] + redS[16 + mr] + redS[32 + mr] + redS[48 + mr];
        float tq = redQ[mr] + redQ[16 + mr] + redQ[32 + mr] + redQ[48 + mr];
        float mean = ts * (1.0f / 256.0f);
        float var = tq * (1.0f / 256.0f) - mean * mean;
        float rinv = rsqrtf(var + 1e-5f);
        int m = bm + mr;
        int b = m / NQ, q = m - b * NQ;
        #pragma unroll
        for (int nj = 0; nj < 4; nj++) {
            int nn = wn + nj * 16 + n16;
            float o = (y[r][nj] - mean) * rinv * g[nn] + beta[nn];
            outf[(long)(q * BS + b) * 256 + nn] = o;
        }
    }
}

extern "C" void kernel_launch(void* const* d_in, const int* in_sizes, int n_in,
                              void* d_out, int out_size, void* d_ws, size_t ws_size,
                              hipStream_t stream) {
    const float* query = (const float*)d_in[0];
    const float* value = (const float*)d_in[1];
    const float* qpos  = (const float*)d_in[2];
    const float* refp  = (const float*)d_in[3];
    const float* in_w  = (const float*)d_in[6];
    const float* in_b  = (const float*)d_in[7];
    const float* mha_ow = (const float*)d_in[8];
    const float* mha_ob = (const float*)d_in[9];
    const float* so_w  = (const float*)d_in[10];
    const float* so_b  = (const float*)d_in[11];
    const float* aw_w  = (const float*)d_in[12];
    const float* aw_b  = (const float*)d_in[13];
    const float* vp_w  = (const float*)d_in[14];
    const float* vp_b  = (const float*)d_in[15];
    const float* op_w  = (const float*)d_in[16];
    const float* op_b  = (const float*)d_in[17];
    const float* ffn_w1 = (const float*)d_in[18];
    const float* ffn_b1 = (const float*)d_in[19];
    const float* ffn_w2 = (const float*)d_in[20];
    const float* ffn_b2 = (const float*)d_in[21];
    const float* ln1_g = (const float*)d_in[22];
    const float* ln1_b = (const float*)d_in[23];
    const float* ln2_g = (const float*)d_in[24];
    const float* ln2_b = (const float*)d_in[25];
    const float* ln3_g = (const float*)d_in[26];
    const float* ln3_b = (const float*)d_in[27];
    float* out = (float*)d_out;

    const long NTOK = (long)BS * NQ * CDIM;   // 1,024,000

    float* x      = (float*)d_ws;
    float* qpos_t = x + NTOK;
    float* x1     = qpos_t + NTOK;
    float* x2     = x1 + NTOK;
    float* soaw   = x2 + NTOK;                       // 4000*96
    float* bsmall = soaw + (long)BS * NQ * 96;       // 128
    __bf16* x_bf   = (__bf16*)(bsmall + 128);
    __bf16* xq_bf  = x_bf + NTOK;
    __bf16* qk_bf  = xq_bf + NTOK;                   // 2*NTOK (q|k, stride 512)
    __bf16* vh_bf  = qk_bf + 2 * NTOK;
    __bf16* aA_bf  = vh_bf + NTOK;
    __bf16* x2_bf  = aA_bf + NTOK;
    __bf16* h1_bf  = x2_bf + NTOK;                   // 2*NTOK
    __bf16* vpj_bf = h1_bf + 2 * NTOK;               // 20,480,000
    __bf16* wb     = vpj_bf + (long)BS * NVAL * CDIM;
    __bf16* inw_b  = wb;
    __bf16* mow_b  = wb + 196608;
    __bf16* vpw_b  = wb + 262144;
    __bf16* opw_b  = wb + 327680;
    __bf16* fw1_b  = wb + 393216;
    __bf16* fw2_b  = wb + 524288;
    __bf16* wsmall = wb + 655360;                    // 128x256

    dim3 blk(256);

    prep_all_kernel<<<4673, blk, 0, stream>>>(
        query, qpos, in_w, mha_ow, vp_w, op_w, ffn_w1, ffn_w2,
        so_w, aw_w, so_b, aw_b,
        x, qpos_t, x_bf, xq_bf, wb, wsmall, bsmall);

    // q|k|v in-proj (756) + vgemm chunk 0 (417)
    qkvv_kernel<<<1173, blk, 0, stream>>>(xq_bf, x_bf, inw_b, in_b, qk_bf, vh_bf,
                                          value, vpw_b, vp_b, vpj_bf, 0);

    // flash attention TK=64 (512) + vgemm chunk 1 (417)
    fattnv_kernel<<<929, blk, 0, stream>>>(qk_bf, vh_bf, aA_bf,
                                           value, vpw_b, vp_b, vpj_bf, 417);

    // mha out-proj + res(x) + LN1 + fused soaw projection (250) + chunk 2 (416)
    gln1s_kernel<<<666, blk, 0, stream>>>(
        aA_bf, mow_b, mha_ob, x, ln1_g, ln1_b, qpos_t, wsmall, bsmall,
        x1, soaw, value, vpw_b, vp_b, vpj_bf, 834);

    // msdeform sampling (4000 blocks — TLP hides gather latency)
    msds_kernel<<<BS * NQ, blk, 0, stream>>>(vpj_bf, soaw, refp, aA_bf);

    // op-proj + residual(x1) + LN2 -> x2 fp32 + bf16
    gln2_kernel<<<250, blk, 0, stream>>>(
        aA_bf, opw_b, op_b, x1, ln2_g, ln2_b, x2, x2_bf);

    // FFN1 (relu)
    mgemm_kernel<64, 64><<<504, blk, 0, stream>>>(
        x2_bf, fw1_b, ffn_b1, h1_bf, BS * NQ, 512, 256, 1, 8);

    // FFN2 + residual(x2) + LN3 + transpose -> out
    gln3_kernel<<<250, blk, 0, stream>>>(
        h1_bf, fw2_b, ffn_b2, x2, ln3_g, ln3_b, out);
}

// Round 3
// 270.452 us; speedup vs baseline: 1.2778x; 1.0166x over previous
//
#include <hip/hip_runtime.h>
#include <hip/hip_bf16.h>
#include <cmath>

#define BS   4
#define NQ   1000
#define CDIM 256
#define NH   8
#define HD   32
#define NVAL 20000
#define FFND 512
#define PN   4
#define WBEV 100
#define HBEV 200
#define TK   64

typedef __bf16 v8bf __attribute__((ext_vector_type(8)));
typedef __bf16 v2bf __attribute__((ext_vector_type(2)));
typedef float  v4f  __attribute__((ext_vector_type(4)));

__device__ __forceinline__ void gload_lds16(const void* g, void* l) {
    __builtin_amdgcn_global_load_lds(
        (const __attribute__((address_space(1))) unsigned int*)g,
        (__attribute__((address_space(3))) unsigned int*)l, 16, 0, 0);
}

// ============ vgemm rider: value-proj, 64 rows x 256 cols per block =========
// value (fp32) is read exactly ONCE across all 1250 blocks.
__device__ __forceinline__ void vgemm64_block(
    int vb, const float* __restrict__ value, const __bf16* __restrict__ Wv,
    const float* __restrict__ bv, __bf16* __restrict__ vpj, char* smem)
{
    __bf16* As = (__bf16*)smem;             // [64][64]
    __bf16* Bs = (__bf16*)(smem + 8192);    // [256][64]
    int tid = threadIdx.x;
    int wave = tid >> 6, lane = tid & 63, quad = lane >> 4, n16 = lane & 15;
    int bm = vb * 64;
    int wm = (wave & 1) * 32, wn = (wave >> 1) * 128;
    v4f acc[2][8] = {};

    for (int k0 = 0; k0 < 256; k0 += 64) {
        float4 fa[2][2];
        #pragma unroll
        for (int i = 0; i < 2; i++) {
            int e = i * 256 + tid;
            int r = e >> 3, c = (e & 7) ^ (r & 7);
            const float* p = value + (long)(bm + r) * 256 + k0 + c * 8;
            fa[i][0] = *(const float4*)p;
            fa[i][1] = *(const float4*)(p + 4);
        }
        __syncthreads();
        #pragma unroll
        for (int i = 0; i < 2; i++) {
            int e = i * 256 + tid;
            v8bf v;
            v[0] = (__bf16)fa[i][0].x; v[1] = (__bf16)fa[i][0].y;
            v[2] = (__bf16)fa[i][0].z; v[3] = (__bf16)fa[i][0].w;
            v[4] = (__bf16)fa[i][1].x; v[5] = (__bf16)fa[i][1].y;
            v[6] = (__bf16)fa[i][1].z; v[7] = (__bf16)fa[i][1].w;
            *(v8bf*)(As + e * 8) = v;
        }
        #pragma unroll
        for (int i = 0; i < 8; i++) {
            int e = i * 256 + tid;
            int r = e >> 3, c = (e & 7) ^ (r & 7);
            gload_lds16(Wv + (long)r * 256 + k0 + c * 8, Bs + e * 8);
        }
        __syncthreads();
        #pragma unroll
        for (int s = 0; s < 2; s++) {
            v8bf af[2], bfr[8];
            #pragma unroll
            for (int mi = 0; mi < 2; mi++) {
                int row = wm + mi * 16 + n16;
                af[mi] = *(v8bf*)&As[row * 64 + (((quad + s * 4) ^ (row & 7))) * 8];
            }
            #pragma unroll
            for (int nj = 0; nj < 8; nj++) {
                int row = wn + nj * 16 + n16;
                bfr[nj] = *(v8bf*)&Bs[row * 64 + (((quad + s * 4) ^ (row & 7))) * 8];
            }
            #pragma unroll
            for (int mi = 0; mi < 2; mi++)
                #pragma unroll
                for (int nj = 0; nj < 8; nj++)
                    acc[mi][nj] = __builtin_amdgcn_mfma_f32_16x16x32_bf16(af[mi], bfr[nj], acc[mi][nj], 0, 0, 0);
        }
    }
    #pragma unroll
    for (int mi = 0; mi < 2; mi++) {
        #pragma unroll
        for (int r = 0; r < 4; r++) {
            int m = bm + wm + mi * 16 + quad * 4 + r;
            #pragma unroll
            for (int nj = 0; nj < 8; nj++) {
                int nn = wn + nj * 16 + n16;
                vpj[(long)m * 256 + nn] = (__bf16)(acc[mi][nj][r] + bv[nn]);
            }
        }
    }
}

// ============ prep_all: weight cast | prep | soaw pack ============
__global__ __launch_bounds__(256) void prep_all_kernel(
    const float* __restrict__ query, const float* __restrict__ qpos,
    const float* __restrict__ in_w, const float* __restrict__ mha_ow,
    const float* __restrict__ vp_w, const float* __restrict__ op_w,
    const float* __restrict__ ffn_w1, const float* __restrict__ ffn_w2,
    const float* __restrict__ so_w, const float* __restrict__ aw_w,
    const float* __restrict__ so_b, const float* __restrict__ aw_b,
    float* __restrict__ x, float* __restrict__ qpos_t,
    __bf16* __restrict__ x_bf, __bf16* __restrict__ xq_bf,
    __bf16* __restrict__ wb, __bf16* __restrict__ wsmall,
    float* __restrict__ bsmall)
{
    int blk = blockIdx.x, tid = threadIdx.x;
    if (blk < 640) {
        long e = ((long)blk * 256 + tid) * 4;
        const float* src; long off;
        if      (e < 196608) { src = in_w;   off = e; }
        else if (e < 262144) { src = mha_ow; off = e - 196608; }
        else if (e < 327680) { src = vp_w;   off = e - 262144; }
        else if (e < 393216) { src = op_w;   off = e - 327680; }
        else if (e < 524288) { src = ffn_w1; off = e - 393216; }
        else                 { src = ffn_w2; off = e - 524288; }
        float4 v = *(const float4*)(src + off);
        __bf16* d = wb + e;
        d[0] = (__bf16)v.x; d[1] = (__bf16)v.y; d[2] = (__bf16)v.z; d[3] = (__bf16)v.w;
    } else if (blk < 4640) {
        int qb = blk - 640;
        int q = qb / BS, b = qb % BS;
        float qv = query[(q * BS + b) * CDIM + tid];
        float pv = qpos [(q * BS + b) * CDIM + tid];
        int o = (b * NQ + q) * CDIM + tid;
        x[o] = qv; qpos_t[o] = pv;
        x_bf[o] = (__bf16)qv; xq_bf[o] = (__bf16)(qv + pv);
    } else if (blk < 4672) {
        long e = ((long)(blk - 4640) * 256 + tid) * 4;
        int row = (int)(e >> 8), col = (int)(e & 255);
        float4 v = {0.f, 0.f, 0.f, 0.f};
        if (row < 64)      v = *(const float4*)(so_w + row * 256 + col);
        else if (row < 96) v = *(const float4*)(aw_w + (row - 64) * 256 + col);
        __bf16* d = wsmall + e;
        d[0] = (__bf16)v.x; d[1] = (__bf16)v.y; d[2] = (__bf16)v.z; d[3] = (__bf16)v.w;
    } else {
        if (tid < 128) bsmall[tid] = tid < 64 ? so_b[tid] : (tid < 96 ? aw_b[tid - 64] : 0.f);
    }
}

// ============ fused q|k|v projection (756 blocks) + vgemm rider ============
__global__ __launch_bounds__(256) void qkvv_kernel(
    const __bf16* __restrict__ xq, const __bf16* __restrict__ xv,
    const __bf16* __restrict__ W, const float* __restrict__ bias,
    __bf16* __restrict__ qk, __bf16* __restrict__ vh,
    const float* __restrict__ value, const __bf16* __restrict__ Wv,
    const float* __restrict__ bv, __bf16* __restrict__ vpj, int voff)
{
    __shared__ __align__(16) char smem[40960];
    int tid = threadIdx.x;
    if ((int)blockIdx.x >= 756) {
        vgemm64_block(blockIdx.x - 756 + voff, value, Wv, bv, vpj, smem);
        return;
    }
    int blk = blockIdx.x;
    int bn = (blk % 12) * 64, bm = (blk / 12) * 64;
    __bf16* As = (__bf16*)smem;             // [64][64]
    __bf16* Bs = (__bf16*)(smem + 8192);    // [64][64]
    const __bf16* A = (bn < 512) ? xq : xv;
    int wave = tid >> 6, lane = tid & 63, quad = lane >> 4, n16 = lane & 15;
    int wm = (wave & 1) * 32, wn = (wave >> 1) * 32;
    v4f acc[2][2] = {};

    for (int k0 = 0; k0 < 256; k0 += 64) {
        __syncthreads();
        #pragma unroll
        for (int i = 0; i < 2; i++) {
            int e = i * 256 + tid;
            int r = e >> 3, c = (e & 7) ^ (r & 7);
            int row = bm + r; if (row > BS * NQ - 1) row = BS * NQ - 1;
            gload_lds16(A + (long)row * 256 + k0 + c * 8, As + e * 8);
        }
        #pragma unroll
        for (int i = 0; i < 2; i++) {
            int e = i * 256 + tid;
            int r = e >> 3, c = (e & 7) ^ (r & 7);
            gload_lds16(W + (long)(bn + r) * 256 + k0 + c * 8, Bs + e * 8);
        }
        __syncthreads();
        #pragma unroll
        for (int s = 0; s < 2; s++) {
            v8bf af[2], bfr[2];
            #pragma unroll
            for (int mi = 0; mi < 2; mi++) {
                int row = wm + mi * 16 + n16;
                af[mi] = *(v8bf*)&As[row * 64 + (((quad + s * 4) ^ (row & 7))) * 8];
            }
            #pragma unroll
            for (int nj = 0; nj < 2; nj++) {
                int row = wn + nj * 16 + n16;
                bfr[nj] = *(v8bf*)&Bs[row * 64 + (((quad + s * 4) ^ (row & 7))) * 8];
            }
            #pragma unroll
            for (int mi = 0; mi < 2; mi++)
                #pragma unroll
                for (int nj = 0; nj < 2; nj++)
                    acc[mi][nj] = __builtin_amdgcn_mfma_f32_16x16x32_bf16(af[mi], bfr[nj], acc[mi][nj], 0, 0, 0);
        }
    }

    #pragma unroll
    for (int mi = 0; mi < 2; mi++) {
        #pragma unroll
        for (int r = 0; r < 4; r++) {
            int m = bm + wm + mi * 16 + quad * 4 + r;
            if (m >= BS * NQ) continue;
            #pragma unroll
            for (int nj = 0; nj < 2; nj++) {
                int nn = bn + wn + nj * 16 + n16;
                float v = acc[mi][nj][r] + bias[nn];
                if (nn < 512) qk[(long)m * 512 + nn] = (__bf16)v;
                else          vh[(long)m * 256 + (nn - 512)] = (__bf16)v;
            }
        }
    }
}

// ============ flash attention, TK=64 (512 blocks) + vgemm rider ============
__global__ __launch_bounds__(256) void fattnv_kernel(
    const __bf16* __restrict__ qk, const __bf16* __restrict__ vh,
    __bf16* __restrict__ aout,
    const float* __restrict__ value, const __bf16* __restrict__ Wv,
    const float* __restrict__ bv, __bf16* __restrict__ vpj, int voff)
{
    __shared__ __align__(16) char smem[40960];
    int tid = threadIdx.x;
    if ((int)blockIdx.x >= 512) {
        vgemm64_block(blockIdx.x - 512 + voff, value, Wv, bv, vpj, smem);
        return;
    }
    int fb = blockIdx.x;
    int qt = fb & 15, h = (fb >> 4) & 7, b = fb >> 7;
    __bf16* Ks = (__bf16*)smem;             // [2][64][40]  = 10240 B
    __bf16* Vt = (__bf16*)(smem + 10240);   // [2][32][72]  =  9216 B
    __bf16* Pl = (__bf16*)(smem + 19456);   // [4][16][72]  =  9216 B
    int wave = tid >> 6, lane = tid & 63, quad = lane >> 4, n = lane & 15;
    int q0 = qt * 64 + wave * 16;
    const float scale = 0.17677669529663687f;
    const float M0 = 8.0f;

    int qrow = q0 + n; if (qrow > NQ - 1) qrow = NQ - 1;
    v8bf aq = *(const v8bf*)(qk + (long)(b * NQ + qrow) * 512 + h * HD + quad * 8);

    v4f o0 = {}, o1 = {};
    float lp[4] = {0.f, 0.f, 0.f, 0.f};

    int sv = tid >> 7;          // 0: stage K, 1: stage V
    int t2 = tid & 127;
    int key = t2 & 63;
    int d16 = (t2 >> 6) * 16;

    v8bf stg0, stg1;
    auto loadtile = [&](int k0) {
        int krow = k0 + key; if (krow > NQ - 1) krow = NQ - 1;
        const __bf16* p = sv ? (vh + (long)(b * NQ + krow) * CDIM + h * HD + d16)
                             : (qk + (long)(b * NQ + krow) * 512 + 256 + h * HD + d16);
        stg0 = *(const v8bf*)p;
        stg1 = *(const v8bf*)(p + 8);
    };

    loadtile(0);
    int pb = 0;
    for (int k0 = 0; k0 < NQ; k0 += TK) {
        if (sv == 0) {
            *(v8bf*)&Ks[(pb * 64 + key) * 40 + d16]     = stg0;
            *(v8bf*)&Ks[(pb * 64 + key) * 40 + d16 + 8] = stg1;
        } else {
            #pragma unroll
            for (int j = 0; j < 8; j++) {
                Vt[(pb * 32 + d16 + j) * 72 + key]            = stg0[j];
                Vt[(pb * 32 + d16 + 8 + j) * 72 + (key ^ 16)] = stg1[j];
            }
        }
        if (k0 + TK < NQ) loadtile(k0 + TK);
        __syncthreads();

        v8bf bk0 = *(v8bf*)&Ks[(pb * 64 +      n) * 40 + quad * 8];
        v8bf bk1 = *(v8bf*)&Ks[(pb * 64 + 16 + n) * 40 + quad * 8];
        v8bf bk2 = *(v8bf*)&Ks[(pb * 64 + 32 + n) * 40 + quad * 8];
        v8bf bk3 = *(v8bf*)&Ks[(pb * 64 + 48 + n) * 40 + quad * 8];
        v4f z = {};
        v4f S0 = __builtin_amdgcn_mfma_f32_16x16x32_bf16(aq, bk0, z, 0, 0, 0);
        v4f S1 = __builtin_amdgcn_mfma_f32_16x16x32_bf16(aq, bk1, z, 0, 0, 0);
        v4f S2 = __builtin_amdgcn_mfma_f32_16x16x32_bf16(aq, bk2, z, 0, 0, 0);
        v4f S3 = __builtin_amdgcn_mfma_f32_16x16x32_bf16(aq, bk3, z, 0, 0, 0);

        bool last = (k0 + TK > NQ);
        float p0[4], p1[4], p2[4], p3[4];
        #pragma unroll
        for (int r = 0; r < 4; r++) {
            p0[r] = __expf(fmaf(S0[r], scale, -M0));
            p1[r] = __expf(fmaf(S1[r], scale, -M0));
            p2[r] = __expf(fmaf(S2[r], scale, -M0));
            p3[r] = __expf(fmaf(S3[r], scale, -M0));
            if (last) {
                if (k0 + 32 + n >= NQ) p2[r] = 0.f;
                if (k0 + 48 + n >= NQ) p3[r] = 0.f;
            }
            lp[r] += p0[r] + p1[r] + p2[r] + p3[r];
        }
        #pragma unroll
        for (int r = 0; r < 4; r++) {
            __bf16* pp = &Pl[(wave * 16 + quad * 4 + r) * 72];
            pp[n]      = (__bf16)p0[r];
            pp[16 + n] = (__bf16)p1[r];
            pp[32 + n] = (__bf16)p2[r];
            pp[48 + n] = (__bf16)p3[r];
        }
        asm volatile("s_waitcnt lgkmcnt(0)" ::: "memory");
        v8bf ap0 = *(v8bf*)&Pl[(wave * 16 + n) * 72 + quad * 8];
        v8bf ap1 = *(v8bf*)&Pl[(wave * 16 + n) * 72 + 32 + quad * 8];
        int swz = ((n >> 3) & 1) << 4;
        int c0 = (quad * 8) ^ swz;
        int c1 = (32 + quad * 8) ^ swz;
        v8bf bv00 = *(v8bf*)&Vt[(pb * 32 +      n) * 72 + c0];
        v8bf bv01 = *(v8bf*)&Vt[(pb * 32 +      n) * 72 + c1];
        v8bf bv10 = *(v8bf*)&Vt[(pb * 32 + 16 + n) * 72 + c0];
        v8bf bv11 = *(v8bf*)&Vt[(pb * 32 + 16 + n) * 72 + c1];
        o0 = __builtin_amdgcn_mfma_f32_16x16x32_bf16(ap0, bv00, o0, 0, 0, 0);
        o0 = __builtin_amdgcn_mfma_f32_16x16x32_bf16(ap1, bv01, o0, 0, 0, 0);
        o1 = __builtin_amdgcn_mfma_f32_16x16x32_bf16(ap0, bv10, o1, 0, 0, 0);
        o1 = __builtin_amdgcn_mfma_f32_16x16x32_bf16(ap1, bv11, o1, 0, 0, 0);
        pb ^= 1;
    }

    #pragma unroll
    for (int r = 0; r < 4; r++) {
        float l = lp[r];
        #pragma unroll
        for (int off = 1; off < 16; off <<= 1) l += __shfl_xor(l, off, 16);
        int q = q0 + quad * 4 + r;
        if (q < NQ) {
            float invl = 1.0f / l;
            __bf16* op = aout + ((long)(b * NQ + q) * CDIM + h * HD);
            op[n]      = (__bf16)(o0[r] * invl);
            op[16 + n] = (__bf16)(o1[r] * invl);
        }
    }
}

// ==== mha out-proj + res + LN1 + (LN1out+qpos -> soaw projection), rider ====
__global__ __launch_bounds__(256) void gln1s_kernel(
    const __bf16* __restrict__ A, const __bf16* __restrict__ W,
    const float* __restrict__ bias, const float* __restrict__ res,
    const float* __restrict__ g, const float* __restrict__ beta,
    const float* __restrict__ qpos_t,
    const __bf16* __restrict__ Wsm, const float* __restrict__ bsm,
    float* __restrict__ outf, float* __restrict__ soawO,
    const float* __restrict__ value, const __bf16* __restrict__ Wv,
    const float* __restrict__ bv, __bf16* __restrict__ vpj, int voff)
{
    __shared__ __align__(16) char smem[43776];
    int tid = threadIdx.x;
    if ((int)blockIdx.x >= 250) {
        vgemm64_block(blockIdx.x - 250 + voff, value, Wv, bv, vpj, smem);
        return;
    }
    __bf16* As  = (__bf16*)smem;             // [16][64]
    __bf16* Bs  = (__bf16*)(smem + 2048);    // [256][64]
    __bf16* Axq = (__bf16*)(smem + 34816);   // [16][264]
    float* redS = (float*)(smem + 43264);    // [64]
    float* redQ = redS + 64;                 // [64]
    int bm = blockIdx.x * 16;
    int wave = tid >> 6, lane = tid & 63, quad = lane >> 4, n16 = lane & 15;
    int wn = wave * 64;
    v4f acc[4] = {};

    for (int k0 = 0; k0 < 256; k0 += 64) {
        __syncthreads();
        if (tid < 128) {
            int e = tid;
            int r = e >> 3, c = (e & 7) ^ (r & 7);
            gload_lds16(A + (long)(bm + r) * 256 + k0 + c * 8, As + e * 8);
        }
        #pragma unroll
        for (int i = 0; i < 8; i++) {
            int e = i * 256 + tid;
            int r = e >> 3, c = (e & 7) ^ (r & 7);
            gload_lds16(W + (long)r * 256 + k0 + c * 8, Bs + e * 8);
        }
        __syncthreads();
        #pragma unroll
        for (int s = 0; s < 2; s++) {
            v8bf af = *(v8bf*)&As[n16 * 64 + (((quad + s * 4) ^ (n16 & 7))) * 8];
            #pragma unroll
            for (int nj = 0; nj < 4; nj++) {
                int row = wn + nj * 16 + n16;
                v8bf bfr = *(v8bf*)&Bs[row * 64 + (((quad + s * 4) ^ (row & 7))) * 8];
                acc[nj] = __builtin_amdgcn_mfma_f32_16x16x32_bf16(af, bfr, acc[nj], 0, 0, 0);
            }
        }
    }

    float y[4][4], s1[4] = {}, s2[4] = {};
    #pragma unroll
    for (int r = 0; r < 4; r++) {
        int m = bm + quad * 4 + r;
        #pragma unroll
        for (int nj = 0; nj < 4; nj++) {
            int nn = wn + nj * 16 + n16;
            float v = acc[nj][r] + bias[nn] + res[(long)m * 256 + nn];
            y[r][nj] = v;
            s1[r] += v; s2[r] += v * v;
        }
    }
    #pragma unroll
    for (int r = 0; r < 4; r++) {
        #pragma unroll
        for (int off = 1; off < 16; off <<= 1) {
            s1[r] += __shfl_xor(s1[r], off, 16);
            s2[r] += __shfl_xor(s2[r], off, 16);
        }
    }
    if (n16 == 0) {
        #pragma unroll
        for (int r = 0; r < 4; r++) {
            redS[wave * 16 + quad * 4 + r] = s1[r];
            redQ[wave * 16 + quad * 4 + r] = s2[r];
        }
    }
    __syncthreads();
    #pragma unroll
    for (int r = 0; r < 4; r++) {
        int mr = quad * 4 + r;
        float ts = redS[mr] + redS[16 + mr] + redS[32 + mr] + redS[48 + mr];
        float tq = redQ[mr] + redQ[16 + mr] + redQ[32 + mr] + redQ[48 + mr];
        float mean = ts * (1.0f / 256.0f);
        float var = tq * (1.0f / 256.0f) - mean * mean;
        float rinv = rsqrtf(var + 1e-5f);
        int m = bm + mr;
        #pragma unroll
        for (int nj = 0; nj < 4; nj++) {
            int nn = wn + nj * 16 + n16;
            float o = (y[r][nj] - mean) * rinv * g[nn] + beta[nn];
            outf[(long)m * 256 + nn] = o;
            Axq[mr * 264 + nn] = (__bf16)(o + qpos_t[(long)m * 256 + nn]);
        }
    }
    __syncthreads();
    // soaw projection: 16 x 96, K=256, waves 0..2 handle 32 cols each
    if (wave < 3) {
        v4f sacc[2] = {};
        #pragma unroll
        for (int k0 = 0; k0 < 256; k0 += 32) {
            v8bf af = *(v8bf*)&Axq[n16 * 264 + k0 + quad * 8];
            #pragma unroll
            for (int t = 0; t < 2; t++) {
                int col = wave * 32 + t * 16 + n16;
                v8bf bw = *(const v8bf*)(Wsm + (long)col * 256 + k0 + quad * 8);
                sacc[t] = __builtin_amdgcn_mfma_f32_16x16x32_bf16(af, bw, sacc[t], 0, 0, 0);
            }
        }
        #pragma unroll
        for (int t = 0; t < 2; t++)
            #pragma unroll
            for (int r = 0; r < 4; r++) {
                int mm = bm + quad * 4 + r;
                int col = wave * 32 + t * 16 + n16;
                soawO[(long)mm * 96 + col] = sacc[t][r] + bsm[col];
            }
    }
}

// ====== msdeform bilinear sampling (2000 blocks, 2 queries/block, 4B loads) =
__global__ __launch_bounds__(256) void msds_kernel(
    const __bf16* __restrict__ vproj, const float* __restrict__ soaw,
    const float* __restrict__ refp, __bf16* __restrict__ out)
{
    int t = threadIdx.x;
    int bq = blockIdx.x * 2 + (t >> 7);
    int b = bq / NQ; int q = bq % NQ;
    int t2 = t & 127;
    int h = t2 >> 4;            // 0..7
    int d0 = (t2 & 15) * 2;     // 0,2,...,30
    float rx = refp[(b * NQ + q) * 2 + 0];
    float ry = refp[(b * NQ + q) * 2 + 1];
    const float* rowp = soaw + (long)(b * NQ + q) * 96;
    const float* offp = rowp + h * 8;
    const float* awp  = rowp + 64 + h * 4;
    float a0 = awp[0], a1 = awp[1], a2 = awp[2], a3 = awp[3];
    float m = fmaxf(fmaxf(a0, a1), fmaxf(a2, a3));
    float e0 = __expf(a0 - m), e1 = __expf(a1 - m), e2 = __expf(a2 - m), e3 = __expf(a3 - m);
    float invs = 1.0f / (e0 + e1 + e2 + e3);
    float accA = 0.f, accB = 0.f;
    #pragma unroll
    for (int p = 0; p < PN; p++) {
        float ew = (p == 0 ? e0 : p == 1 ? e1 : p == 2 ? e2 : e3) * invs;
        float xim = rx * (float)WBEV + offp[p * 2 + 0] - 0.5f;
        float yim = ry * (float)HBEV + offp[p * 2 + 1] - 0.5f;
        float x0f = floorf(xim), y0f = floorf(yim);
        float lx = xim - x0f, ly = yim - y0f;
        int x0 = (int)x0f, y0 = (int)y0f;
        float gA = 0.f, gB = 0.f;
        #pragma unroll
        for (int dy = 0; dy < 2; dy++) {
            #pragma unroll
            for (int dx = 0; dx < 2; dx++) {
                int xi = x0 + dx, yi = y0 + dy;
                float w = (dx ? lx : 1.f - lx) * (dy ? ly : 1.f - ly);
                bool ok = (xi >= 0 && xi < WBEV && yi >= 0 && yi < HBEV);
                int xc = min(max(xi, 0), WBEV - 1);
                int yc = min(max(yi, 0), HBEV - 1);
                int idx = yc * WBEV + xc;
                v2bf gv = *(const v2bf*)(vproj + ((long)(idx * BS + b)) * CDIM + h * HD + d0);
                float wk = (ok ? w : 0.f);
                gA += wk * (float)gv[0];
                gB += wk * (float)gv[1];
            }
        }
        accA += ew * gA;
        accB += ew * gB;
    }
    v2bf o2; o2[0] = (__bf16)accA; o2[1] = (__bf16)accB;
    *(v2bf*)(out + (long)(b * NQ + q) * CDIM + h * HD + d0) = o2;
}

// == fused tail: op-proj+res+LN2 -> FFN1(relu) -> FFN2+res+LN3 -> out (250) ==
__global__ __launch_bounds__(256) void gtail_kernel(
    const __bf16* __restrict__ A, const __bf16* __restrict__ Wop,
    const float* __restrict__ opb, const float* __restrict__ res,
    const float* __restrict__ g2, const float* __restrict__ b2ln,
    const __bf16* __restrict__ W1, const float* __restrict__ b1,
    const __bf16* __restrict__ W2, const float* __restrict__ bff2,
    const float* __restrict__ g3, const float* __restrict__ b3ln,
    float* __restrict__ outf)
{
    __shared__ __align__(16) char smem[59904];
    __bf16* As  = (__bf16*)smem;              // [16][64]   phase-A A staging
    __bf16* Bs  = (__bf16*)(smem + 2048);     // [256][64]  weight staging (all phases)
    __bf16* As2 = (__bf16*)(smem + 34816);    // [4][16][64] LN2-out tile (swizzled)
    __bf16* h1s = (__bf16*)(smem + 43008);    // [8][16][64] FFN1-out tile (swizzled)
    float* redS = (float*)(smem + 59392);     // [64]
    float* redQ = (float*)(smem + 59648);     // [64]
    int tid = threadIdx.x;
    int bm = blockIdx.x * 16;
    int wave = tid >> 6, lane = tid & 63, quad = lane >> 4, n16 = lane & 15;
    int wn = wave * 64;

    // ---------- Phase A: op-proj (K=256) + residual + LN2 ----------
    v4f acc[4] = {};
    for (int k0 = 0; k0 < 256; k0 += 64) {
        __syncthreads();
        if (tid < 128) {
            int e = tid;
            int r = e >> 3, c = (e & 7) ^ (r & 7);
            gload_lds16(A + (long)(bm + r) * 256 + k0 + c * 8, As + e * 8);
        }
        #pragma unroll
        for (int i = 0; i < 8; i++) {
            int e = i * 256 + tid;
            int r = e >> 3, c = (e & 7) ^ (r & 7);
            gload_lds16(Wop + (long)r * 256 + k0 + c * 8, Bs + e * 8);
        }
        __syncthreads();
        #pragma unroll
        for (int s = 0; s < 2; s++) {
            v8bf af = *(v8bf*)&As[n16 * 64 + (((quad + s * 4) ^ (n16 & 7))) * 8];
            #pragma unroll
            for (int nj = 0; nj < 4; nj++) {
                int row = wn + nj * 16 + n16;
                v8bf bfr = *(v8bf*)&Bs[row * 64 + (((quad + s * 4) ^ (row & 7))) * 8];
                acc[nj] = __builtin_amdgcn_mfma_f32_16x16x32_bf16(af, bfr, acc[nj], 0, 0, 0);
            }
        }
    }
    float yv[4][4], s1[4] = {}, s2[4] = {};
    #pragma unroll
    for (int r = 0; r < 4; r++) {
        int m = bm + quad * 4 + r;
        #pragma unroll
        for (int nj = 0; nj < 4; nj++) {
            int nn = wn + nj * 16 + n16;
            float v = acc[nj][r] + opb[nn] + res[(long)m * 256 + nn];
            yv[r][nj] = v;
            s1[r] += v; s2[r] += v * v;
        }
    }
    #pragma unroll
    for (int r = 0; r < 4; r++) {
        #pragma unroll
        for (int off = 1; off < 16; off <<= 1) {
            s1[r] += __shfl_xor(s1[r], off, 16);
            s2[r] += __shfl_xor(s2[r], off, 16);
        }
    }
    if (n16 == 0) {
        #pragma unroll
        for (int r = 0; r < 4; r++) {
            redS[wave * 16 + quad * 4 + r] = s1[r];
            redQ[wave * 16 + quad * 4 + r] = s2[r];
        }
    }
    __syncthreads();
    #pragma unroll
    for (int r = 0; r < 4; r++) {
        int mr = quad * 4 + r;
        float ts = redS[mr] + redS[16 + mr] + redS[32 + mr] + redS[48 + mr];
        float tq = redQ[mr] + redQ[16 + mr] + redQ[32 + mr] + redQ[48 + mr];
        float mean = ts * (1.0f / 256.0f);
        float var = tq * (1.0f / 256.0f) - mean * mean;
        float rinv = rsqrtf(var + 1e-5f);
        #pragma unroll
        for (int nj = 0; nj < 4; nj++) {
            int nn = wn + nj * 16 + n16;
            float o = (yv[r][nj] - mean) * rinv * g2[nn] + b2ln[nn];
            yv[r][nj] = o;   // keep x2 residual in registers
            int c = nn & 63;                 // wn stripped: kc == wave
            As2[wave * 1024 + mr * 64 + ((((c >> 3)) ^ (mr & 7)) << 3) + (c & 7)] = (__bf16)o;
        }
    }

    // ---------- Phase B: FFN1 (K=256, N=512 in two halves) + ReLU ----------
    #pragma unroll 1
    for (int H = 0; H < 2; H++) {
        v4f accB[4] = {};
        for (int k0 = 0; k0 < 256; k0 += 64) {
            __syncthreads();
            #pragma unroll
            for (int i = 0; i < 8; i++) {
                int e = i * 256 + tid;
                int r = e >> 3, c = (e & 7) ^ (r & 7);
                gload_lds16(W1 + (long)(H * 256 + r) * 256 + k0 + c * 8, Bs + e * 8);
            }
            __syncthreads();
            int kc = k0 >> 6;
            #pragma unroll
            for (int s = 0; s < 2; s++) {
                v8bf af = *(v8bf*)&As2[kc * 1024 + n16 * 64 + (((quad + s * 4) ^ (n16 & 7))) * 8];
                #pragma unroll
                for (int nj = 0; nj < 4; nj++) {
                    int row = wn + nj * 16 + n16;
                    v8bf bfr = *(v8bf*)&Bs[row * 64 + (((quad + s * 4) ^ (row & 7))) * 8];
                    accB[nj] = __builtin_amdgcn_mfma_f32_16x16x32_bf16(af, bfr, accB[nj], 0, 0, 0);
                }
            }
        }
        #pragma unroll
        for (int r = 0; r < 4; r++) {
            int mr = quad * 4 + r;
            #pragma unroll
            for (int nj = 0; nj < 4; nj++) {
                int col = H * 256 + wn + nj * 16 + n16;
                float v = accB[nj][r] + b1[col];
                v = fmaxf(v, 0.f);
                int kc = col >> 6, c = col & 63;
                h1s[kc * 1024 + mr * 64 + ((((c >> 3)) ^ (mr & 7)) << 3) + (c & 7)] = (__bf16)v;
            }
        }
    }

    // ---------- Phase C: FFN2 (K=512) + bias + x2 residual + LN3 ----------
    v4f acc3[4] = {};
    for (int k0 = 0; k0 < 512; k0 += 64) {
        __syncthreads();
        #pragma unroll
        for (int i = 0; i < 8; i++) {
            int e = i * 256 + tid;
            int r = e >> 3, c = (e & 7) ^ (r & 7);
            gload_lds16(W2 + (long)r * 512 + k0 + c * 8, Bs + e * 8);
        }
        __syncthreads();
        int kc = k0 >> 6;
        #pragma unroll
        for (int s = 0; s < 2; s++) {
            v8bf af = *(v8bf*)&h1s[kc * 1024 + n16 * 64 + (((quad + s * 4) ^ (n16 & 7))) * 8];
            #pragma unroll
            for (int nj = 0; nj < 4; nj++) {
                int row = wn + nj * 16 + n16;
                v8bf bfr = *(v8bf*)&Bs[row * 64 + (((quad + s * 4) ^ (row & 7))) * 8];
                acc3[nj] = __builtin_amdgcn_mfma_f32_16x16x32_bf16(af, bfr, acc3[nj], 0, 0, 0);
            }
        }
    }
    float y3[4][4], t1[4] = {}, t2[4] = {};
    #pragma unroll
    for (int r = 0; r < 4; r++) {
        #pragma unroll
        for (int nj = 0; nj < 4; nj++) {
            int nn = wn + nj * 16 + n16;
            float v = acc3[nj][r] + bff2[nn] + yv[r][nj];
            y3[r][nj] = v;
            t1[r] += v; t2[r] += v * v;
        }
    }
    #pragma unroll
    for (int r = 0; r < 4; r++) {
        #pragma unroll
        for (int off = 1; off < 16; off <<= 1) {
            t1[r] += __shfl_xor(t1[r], off, 16);
            t2[r] += __shfl_xor(t2[r], off, 16);
        }
    }
    __syncthreads();   // red arrays free for reuse
    if (n16 == 0) {
        #pragma unroll
        for (int r = 0; r < 4; r++) {
            redS[wave * 16 + quad * 4 + r] = t1[r];
            redQ[wave * 16 + quad * 4 + r] = t2[r];
        }
    }
    __syncthreads();
    #pragma unroll
    for (int r = 0; r < 4; r++) {
        int mr = quad * 4 + r;
        float ts = redS[mr] + redS[16 + mr] + redS[32 + mr] + redS[48 + mr];
        float tq = redQ[mr] + redQ[16 + mr] + redQ[32 + mr] + redQ[48 + mr];
        float mean = ts * (1.0f / 256.0f);
        float var = tq * (1.0f / 256.0f) - mean * mean;
        float rinv = rsqrtf(var + 1e-5f);
        int m = bm + mr;
        int b = m / NQ, q = m - b * NQ;
        #pragma unroll
        for (int nj = 0; nj < 4; nj++) {
            int nn = wn + nj * 16 + n16;
            float o = (y3[r][nj] - mean) * rinv * g3[nn] + b3ln[nn];
            outf[(long)(q * BS + b) * 256 + nn] = o;
        }
    }
}

extern "C" void kernel_launch(void* const* d_in, const int* in_sizes, int n_in,
                              void* d_out, int out_size, void* d_ws, size_t ws_size,
                              hipStream_t stream) {
    const float* query = (const float*)d_in[0];
    const float* value = (const float*)d_in[1];
    const float* qpos  = (const float*)d_in[2];
    const float* refp  = (const float*)d_in[3];
    const float* in_w  = (const float*)d_in[6];
    const float* in_b  = (const float*)d_in[7];
    const float* mha_ow = (const float*)d_in[8];
    const float* mha_ob = (const float*)d_in[9];
    const float* so_w  = (const float*)d_in[10];
    const float* so_b  = (const float*)d_in[11];
    const float* aw_w  = (const float*)d_in[12];
    const float* aw_b  = (const float*)d_in[13];
    const float* vp_w  = (const float*)d_in[14];
    const float* vp_b  = (const float*)d_in[15];
    const float* op_w  = (const float*)d_in[16];
    const float* op_b  = (const float*)d_in[17];
    const float* ffn_w1 = (const float*)d_in[18];
    const float* ffn_b1 = (const float*)d_in[19];
    const float* ffn_w2 = (const float*)d_in[20];
    const float* ffn_b2 = (const float*)d_in[21];
    const float* ln1_g = (const float*)d_in[22];
    const float* ln1_b = (const float*)d_in[23];
    const float* ln2_g = (const float*)d_in[24];
    const float* ln2_b = (const float*)d_in[25];
    const float* ln3_g = (const float*)d_in[26];
    const float* ln3_b = (const float*)d_in[27];
    float* out = (float*)d_out;

    const long NTOK = (long)BS * NQ * CDIM;   // 1,024,000

    float* x      = (float*)d_ws;
    float* qpos_t = x + NTOK;
    float* x1     = qpos_t + NTOK;
    float* x2     = x1 + NTOK;                       // (unused now, keeps layout)
    float* soaw   = x2 + NTOK;                       // 4000*96
    float* bsmall = soaw + (long)BS * NQ * 96;       // 128
    __bf16* x_bf   = (__bf16*)(bsmall + 128);
    __bf16* xq_bf  = x_bf + NTOK;
    __bf16* qk_bf  = xq_bf + NTOK;                   // 2*NTOK (q|k, stride 512)
    __bf16* vh_bf  = qk_bf + 2 * NTOK;
    __bf16* aA_bf  = vh_bf + NTOK;
    __bf16* x2_bf  = aA_bf + NTOK;                   // (unused now)
    __bf16* h1_bf  = x2_bf + NTOK;                   // (unused now)
    __bf16* vpj_bf = h1_bf + 2 * NTOK;               // 20,480,000
    __bf16* wb     = vpj_bf + (long)BS * NVAL * CDIM;
    __bf16* inw_b  = wb;
    __bf16* mow_b  = wb + 196608;
    __bf16* vpw_b  = wb + 262144;
    __bf16* opw_b  = wb + 327680;
    __bf16* fw1_b  = wb + 393216;
    __bf16* fw2_b  = wb + 524288;
    __bf16* wsmall = wb + 655360;                    // 128x256

    dim3 blk(256);

    prep_all_kernel<<<4673, blk, 0, stream>>>(
        query, qpos, in_w, mha_ow, vp_w, op_w, ffn_w1, ffn_w2,
        so_w, aw_w, so_b, aw_b,
        x, qpos_t, x_bf, xq_bf, wb, wsmall, bsmall);

    // q|k|v in-proj (756) + vgemm chunk 0 (417)
    qkvv_kernel<<<1173, blk, 0, stream>>>(xq_bf, x_bf, inw_b, in_b, qk_bf, vh_bf,
                                          value, vpw_b, vp_b, vpj_bf, 0);

    // flash attention TK=64 (512) + vgemm chunk 1 (417)
    fattnv_kernel<<<929, blk, 0, stream>>>(qk_bf, vh_bf, aA_bf,
                                           value, vpw_b, vp_b, vpj_bf, 417);

    // mha out-proj + res(x) + LN1 + fused soaw projection (250) + chunk 2 (416)
    gln1s_kernel<<<666, blk, 0, stream>>>(
        aA_bf, mow_b, mha_ob, x, ln1_g, ln1_b, qpos_t, wsmall, bsmall,
        x1, soaw, value, vpw_b, vp_b, vpj_bf, 834);

    // msdeform sampling (2000 blocks, 2 queries each, 4B gathers)
    msds_kernel<<<2000, blk, 0, stream>>>(vpj_bf, soaw, refp, aA_bf);

    // fused tail: op-proj+LN2 -> FFN1 -> FFN2+LN3 -> out
    gtail_kernel<<<250, blk, 0, stream>>>(
        aA_bf, opw_b, op_b, x1, ln2_g, ln2_b,
        fw1_b, ffn_b1, fw2_b, ffn_b2, ln3_g, ln3_b, out);
}

// Round 4
// 264.300 us; speedup vs baseline: 1.3076x; 1.0233x over previous
//
#include <hip/hip_runtime.h>
#include <hip/hip_bf16.h>
#include <cmath>

#define BS   4
#define NQ   1000
#define CDIM 256
#define NH   8
#define HD   32
#define NVAL 20000
#define FFND 512
#define PN   4
#define WBEV 100
#define HBEV 200
#define TK   64

typedef __bf16 v8bf __attribute__((ext_vector_type(8)));
typedef __bf16 v2bf __attribute__((ext_vector_type(2)));
typedef float  v4f  __attribute__((ext_vector_type(4)));

__device__ __forceinline__ void gload_lds16(const void* g, void* l) {
    __builtin_amdgcn_global_load_lds(
        (const __attribute__((address_space(1))) unsigned int*)g,
        (__attribute__((address_space(3))) unsigned int*)l, 16, 0, 0);
}

// ============ value-proj GEMM, dedicated launch: 1250 blocks, 64x256 =======
// value (fp32) read exactly once; uniform 4.9 blocks/CU packing.
__global__ __launch_bounds__(256) void vgemm_kernel(
    const float* __restrict__ value, const __bf16* __restrict__ Wv,
    const float* __restrict__ bv, __bf16* __restrict__ vpj)
{
    __shared__ __align__(16) char smem[40960];
    __bf16* As = (__bf16*)smem;             // [64][64]
    __bf16* Bs = (__bf16*)(smem + 8192);    // [256][64]
    int tid = threadIdx.x;
    int wave = tid >> 6, lane = tid & 63, quad = lane >> 4, n16 = lane & 15;
    int bm = blockIdx.x * 64;
    int wm = (wave & 1) * 32, wn = (wave >> 1) * 128;
    v4f acc[2][8] = {};

    for (int k0 = 0; k0 < 256; k0 += 64) {
        float4 fa[2][2];
        #pragma unroll
        for (int i = 0; i < 2; i++) {
            int e = i * 256 + tid;
            int r = e >> 3, c = (e & 7) ^ (r & 7);
            const float* p = value + (long)(bm + r) * 256 + k0 + c * 8;
            fa[i][0] = *(const float4*)p;
            fa[i][1] = *(const float4*)(p + 4);
        }
        __syncthreads();
        #pragma unroll
        for (int i = 0; i < 2; i++) {
            int e = i * 256 + tid;
            v8bf v;
            v[0] = (__bf16)fa[i][0].x; v[1] = (__bf16)fa[i][0].y;
            v[2] = (__bf16)fa[i][0].z; v[3] = (__bf16)fa[i][0].w;
            v[4] = (__bf16)fa[i][1].x; v[5] = (__bf16)fa[i][1].y;
            v[6] = (__bf16)fa[i][1].z; v[7] = (__bf16)fa[i][1].w;
            *(v8bf*)(As + e * 8) = v;
        }
        #pragma unroll
        for (int i = 0; i < 8; i++) {
            int e = i * 256 + tid;
            int r = e >> 3, c = (e & 7) ^ (r & 7);
            gload_lds16(Wv + (long)r * 256 + k0 + c * 8, Bs + e * 8);
        }
        __syncthreads();
        #pragma unroll
        for (int s = 0; s < 2; s++) {
            v8bf af[2], bfr[8];
            #pragma unroll
            for (int mi = 0; mi < 2; mi++) {
                int row = wm + mi * 16 + n16;
                af[mi] = *(v8bf*)&As[row * 64 + (((quad + s * 4) ^ (row & 7))) * 8];
            }
            #pragma unroll
            for (int nj = 0; nj < 8; nj++) {
                int row = wn + nj * 16 + n16;
                bfr[nj] = *(v8bf*)&Bs[row * 64 + (((quad + s * 4) ^ (row & 7))) * 8];
            }
            #pragma unroll
            for (int mi = 0; mi < 2; mi++)
                #pragma unroll
                for (int nj = 0; nj < 8; nj++)
                    acc[mi][nj] = __builtin_amdgcn_mfma_f32_16x16x32_bf16(af[mi], bfr[nj], acc[mi][nj], 0, 0, 0);
        }
    }
    #pragma unroll
    for (int mi = 0; mi < 2; mi++) {
        #pragma unroll
        for (int r = 0; r < 4; r++) {
            int m = bm + wm + mi * 16 + quad * 4 + r;
            #pragma unroll
            for (int nj = 0; nj < 8; nj++) {
                int nn = wn + nj * 16 + n16;
                vpj[(long)m * 256 + nn] = (__bf16)(acc[mi][nj][r] + bv[nn]);
            }
        }
    }
}

// ============ prep_all: weight cast | prep | soaw pack ============
__global__ __launch_bounds__(256) void prep_all_kernel(
    const float* __restrict__ query, const float* __restrict__ qpos,
    const float* __restrict__ in_w, const float* __restrict__ mha_ow,
    const float* __restrict__ vp_w, const float* __restrict__ op_w,
    const float* __restrict__ ffn_w1, const float* __restrict__ ffn_w2,
    const float* __restrict__ so_w, const float* __restrict__ aw_w,
    const float* __restrict__ so_b, const float* __restrict__ aw_b,
    float* __restrict__ x, float* __restrict__ qpos_t,
    __bf16* __restrict__ x_bf, __bf16* __restrict__ xq_bf,
    __bf16* __restrict__ wb, __bf16* __restrict__ wsmall,
    float* __restrict__ bsmall)
{
    int blk = blockIdx.x, tid = threadIdx.x;
    if (blk < 640) {
        long e = ((long)blk * 256 + tid) * 4;
        const float* src; long off;
        if      (e < 196608) { src = in_w;   off = e; }
        else if (e < 262144) { src = mha_ow; off = e - 196608; }
        else if (e < 327680) { src = vp_w;   off = e - 262144; }
        else if (e < 393216) { src = op_w;   off = e - 327680; }
        else if (e < 524288) { src = ffn_w1; off = e - 393216; }
        else                 { src = ffn_w2; off = e - 524288; }
        float4 v = *(const float4*)(src + off);
        __bf16* d = wb + e;
        d[0] = (__bf16)v.x; d[1] = (__bf16)v.y; d[2] = (__bf16)v.z; d[3] = (__bf16)v.w;
    } else if (blk < 4640) {
        int qb = blk - 640;
        int q = qb / BS, b = qb % BS;
        float qv = query[(q * BS + b) * CDIM + tid];
        float pv = qpos [(q * BS + b) * CDIM + tid];
        int o = (b * NQ + q) * CDIM + tid;
        x[o] = qv; qpos_t[o] = pv;
        x_bf[o] = (__bf16)qv; xq_bf[o] = (__bf16)(qv + pv);
    } else if (blk < 4672) {
        long e = ((long)(blk - 4640) * 256 + tid) * 4;
        int row = (int)(e >> 8), col = (int)(e & 255);
        float4 v = {0.f, 0.f, 0.f, 0.f};
        if (row < 64)      v = *(const float4*)(so_w + row * 256 + col);
        else if (row < 96) v = *(const float4*)(aw_w + (row - 64) * 256 + col);
        __bf16* d = wsmall + e;
        d[0] = (__bf16)v.x; d[1] = (__bf16)v.y; d[2] = (__bf16)v.z; d[3] = (__bf16)v.w;
    } else {
        if (tid < 128) bsmall[tid] = tid < 64 ? so_b[tid] : (tid < 96 ? aw_b[tid - 64] : 0.f);
    }
}

// ============ fused q|k|v projection (756 blocks, 16 KB LDS) ============
__global__ __launch_bounds__(256) void qkvv_kernel(
    const __bf16* __restrict__ xq, const __bf16* __restrict__ xv,
    const __bf16* __restrict__ W, const float* __restrict__ bias,
    __bf16* __restrict__ qk, __bf16* __restrict__ vh)
{
    __shared__ __align__(16) char smem[16384];
    int tid = threadIdx.x;
    int blk = blockIdx.x;
    int bn = (blk % 12) * 64, bm = (blk / 12) * 64;
    __bf16* As = (__bf16*)smem;             // [64][64]
    __bf16* Bs = (__bf16*)(smem + 8192);    // [64][64]
    const __bf16* A = (bn < 512) ? xq : xv;
    int wave = tid >> 6, lane = tid & 63, quad = lane >> 4, n16 = lane & 15;
    int wm = (wave & 1) * 32, wn = (wave >> 1) * 32;
    v4f acc[2][2] = {};

    for (int k0 = 0; k0 < 256; k0 += 64) {
        __syncthreads();
        #pragma unroll
        for (int i = 0; i < 2; i++) {
            int e = i * 256 + tid;
            int r = e >> 3, c = (e & 7) ^ (r & 7);
            int row = bm + r; if (row > BS * NQ - 1) row = BS * NQ - 1;
            gload_lds16(A + (long)row * 256 + k0 + c * 8, As + e * 8);
        }
        #pragma unroll
        for (int i = 0; i < 2; i++) {
            int e = i * 256 + tid;
            int r = e >> 3, c = (e & 7) ^ (r & 7);
            gload_lds16(W + (long)(bn + r) * 256 + k0 + c * 8, Bs + e * 8);
        }
        __syncthreads();
        #pragma unroll
        for (int s = 0; s < 2; s++) {
            v8bf af[2], bfr[2];
            #pragma unroll
            for (int mi = 0; mi < 2; mi++) {
                int row = wm + mi * 16 + n16;
                af[mi] = *(v8bf*)&As[row * 64 + (((quad + s * 4) ^ (row & 7))) * 8];
            }
            #pragma unroll
            for (int nj = 0; nj < 2; nj++) {
                int row = wn + nj * 16 + n16;
                bfr[nj] = *(v8bf*)&Bs[row * 64 + (((quad + s * 4) ^ (row & 7))) * 8];
            }
            #pragma unroll
            for (int mi = 0; mi < 2; mi++)
                #pragma unroll
                for (int nj = 0; nj < 2; nj++)
                    acc[mi][nj] = __builtin_amdgcn_mfma_f32_16x16x32_bf16(af[mi], bfr[nj], acc[mi][nj], 0, 0, 0);
        }
    }

    #pragma unroll
    for (int mi = 0; mi < 2; mi++) {
        #pragma unroll
        for (int r = 0; r < 4; r++) {
            int m = bm + wm + mi * 16 + quad * 4 + r;
            if (m >= BS * NQ) continue;
            #pragma unroll
            for (int nj = 0; nj < 2; nj++) {
                int nn = bn + wn + nj * 16 + n16;
                float v = acc[mi][nj][r] + bias[nn];
                if (nn < 512) qk[(long)m * 512 + nn] = (__bf16)v;
                else          vh[(long)m * 256 + (nn - 512)] = (__bf16)v;
            }
        }
    }
}

// ============ flash attention, TK=64 (512 blocks, 28 KB LDS) ============
__global__ __launch_bounds__(256) void fattnv_kernel(
    const __bf16* __restrict__ qk, const __bf16* __restrict__ vh,
    __bf16* __restrict__ aout)
{
    __shared__ __align__(16) char smem[28672];
    int tid = threadIdx.x;
    int fb = blockIdx.x;
    int qt = fb & 15, h = (fb >> 4) & 7, b = fb >> 7;
    __bf16* Ks = (__bf16*)smem;             // [2][64][40]  = 10240 B
    __bf16* Vt = (__bf16*)(smem + 10240);   // [2][32][72]  =  9216 B
    __bf16* Pl = (__bf16*)(smem + 19456);   // [4][16][72]  =  9216 B
    int wave = tid >> 6, lane = tid & 63, quad = lane >> 4, n = lane & 15;
    int q0 = qt * 64 + wave * 16;
    const float scale = 0.17677669529663687f;
    const float M0 = 8.0f;

    int qrow = q0 + n; if (qrow > NQ - 1) qrow = NQ - 1;
    v8bf aq = *(const v8bf*)(qk + (long)(b * NQ + qrow) * 512 + h * HD + quad * 8);

    v4f o0 = {}, o1 = {};
    float lp[4] = {0.f, 0.f, 0.f, 0.f};

    int sv = tid >> 7;          // 0: stage K, 1: stage V
    int t2 = tid & 127;
    int key = t2 & 63;
    int d16 = (t2 >> 6) * 16;

    v8bf stg0, stg1;
    auto loadtile = [&](int k0) {
        int krow = k0 + key; if (krow > NQ - 1) krow = NQ - 1;
        const __bf16* p = sv ? (vh + (long)(b * NQ + krow) * CDIM + h * HD + d16)
                             : (qk + (long)(b * NQ + krow) * 512 + 256 + h * HD + d16);
        stg0 = *(const v8bf*)p;
        stg1 = *(const v8bf*)(p + 8);
    };

    loadtile(0);
    int pb = 0;
    for (int k0 = 0; k0 < NQ; k0 += TK) {
        if (sv == 0) {
            *(v8bf*)&Ks[(pb * 64 + key) * 40 + d16]     = stg0;
            *(v8bf*)&Ks[(pb * 64 + key) * 40 + d16 + 8] = stg1;
        } else {
            #pragma unroll
            for (int j = 0; j < 8; j++) {
                Vt[(pb * 32 + d16 + j) * 72 + key]            = stg0[j];
                Vt[(pb * 32 + d16 + 8 + j) * 72 + (key ^ 16)] = stg1[j];
            }
        }
        if (k0 + TK < NQ) loadtile(k0 + TK);
        __syncthreads();

        v8bf bk0 = *(v8bf*)&Ks[(pb * 64 +      n) * 40 + quad * 8];
        v8bf bk1 = *(v8bf*)&Ks[(pb * 64 + 16 + n) * 40 + quad * 8];
        v8bf bk2 = *(v8bf*)&Ks[(pb * 64 + 32 + n) * 40 + quad * 8];
        v8bf bk3 = *(v8bf*)&Ks[(pb * 64 + 48 + n) * 40 + quad * 8];
        v4f z = {};
        v4f S0 = __builtin_amdgcn_mfma_f32_16x16x32_bf16(aq, bk0, z, 0, 0, 0);
        v4f S1 = __builtin_amdgcn_mfma_f32_16x16x32_bf16(aq, bk1, z, 0, 0, 0);
        v4f S2 = __builtin_amdgcn_mfma_f32_16x16x32_bf16(aq, bk2, z, 0, 0, 0);
        v4f S3 = __builtin_amdgcn_mfma_f32_16x16x32_bf16(aq, bk3, z, 0, 0, 0);

        bool last = (k0 + TK > NQ);
        float p0[4], p1[4], p2[4], p3[4];
        #pragma unroll
        for (int r = 0; r < 4; r++) {
            p0[r] = __expf(fmaf(S0[r], scale, -M0));
            p1[r] = __expf(fmaf(S1[r], scale, -M0));
            p2[r] = __expf(fmaf(S2[r], scale, -M0));
            p3[r] = __expf(fmaf(S3[r], scale, -M0));
            if (last) {
                if (k0 + 32 + n >= NQ) p2[r] = 0.f;
                if (k0 + 48 + n >= NQ) p3[r] = 0.f;
            }
            lp[r] += p0[r] + p1[r] + p2[r] + p3[r];
        }
        #pragma unroll
        for (int r = 0; r < 4; r++) {
            __bf16* pp = &Pl[(wave * 16 + quad * 4 + r) * 72];
            pp[n]      = (__bf16)p0[r];
            pp[16 + n] = (__bf16)p1[r];
            pp[32 + n] = (__bf16)p2[r];
            pp[48 + n] = (__bf16)p3[r];
        }
        asm volatile("s_waitcnt lgkmcnt(0)" ::: "memory");
        v8bf ap0 = *(v8bf*)&Pl[(wave * 16 + n) * 72 + quad * 8];
        v8bf ap1 = *(v8bf*)&Pl[(wave * 16 + n) * 72 + 32 + quad * 8];
        int swz = ((n >> 3) & 1) << 4;
        int c0 = (quad * 8) ^ swz;
        int c1 = (32 + quad * 8) ^ swz;
        v8bf bv00 = *(v8bf*)&Vt[(pb * 32 +      n) * 72 + c0];
        v8bf bv01 = *(v8bf*)&Vt[(pb * 32 +      n) * 72 + c1];
        v8bf bv10 = *(v8bf*)&Vt[(pb * 32 + 16 + n) * 72 + c0];
        v8bf bv11 = *(v8bf*)&Vt[(pb * 32 + 16 + n) * 72 + c1];
        o0 = __builtin_amdgcn_mfma_f32_16x16x32_bf16(ap0, bv00, o0, 0, 0, 0);
        o0 = __builtin_amdgcn_mfma_f32_16x16x32_bf16(ap1, bv01, o0, 0, 0, 0);
        o1 = __builtin_amdgcn_mfma_f32_16x16x32_bf16(ap0, bv10, o1, 0, 0, 0);
        o1 = __builtin_amdgcn_mfma_f32_16x16x32_bf16(ap1, bv11, o1, 0, 0, 0);
        pb ^= 1;
    }

    #pragma unroll
    for (int r = 0; r < 4; r++) {
        float l = lp[r];
        #pragma unroll
        for (int off = 1; off < 16; off <<= 1) l += __shfl_xor(l, off, 16);
        int q = q0 + quad * 4 + r;
        if (q < NQ) {
            float invl = 1.0f / l;
            __bf16* op = aout + ((long)(b * NQ + q) * CDIM + h * HD);
            op[n]      = (__bf16)(o0[r] * invl);
            op[16 + n] = (__bf16)(o1[r] * invl);
        }
    }
}

// ==== mha out-proj + res + LN1 + (LN1out+qpos -> soaw projection) ====
__global__ __launch_bounds__(256) void gln1s_kernel(
    const __bf16* __restrict__ A, const __bf16* __restrict__ W,
    const float* __restrict__ bias, const float* __restrict__ res,
    const float* __restrict__ g, const float* __restrict__ beta,
    const float* __restrict__ qpos_t,
    const __bf16* __restrict__ Wsm, const float* __restrict__ bsm,
    float* __restrict__ outf, float* __restrict__ soawO)
{
    __shared__ __align__(16) char smem[43776];
    int tid = threadIdx.x;
    __bf16* As  = (__bf16*)smem;             // [16][64]
    __bf16* Bs  = (__bf16*)(smem + 2048);    // [256][64]
    __bf16* Axq = (__bf16*)(smem + 34816);   // [16][264]
    float* redS = (float*)(smem + 43264);    // [64]
    float* redQ = redS + 64;                 // [64]
    int bm = blockIdx.x * 16;
    int wave = tid >> 6, lane = tid & 63, quad = lane >> 4, n16 = lane & 15;
    int wn = wave * 64;
    v4f acc[4] = {};

    for (int k0 = 0; k0 < 256; k0 += 64) {
        __syncthreads();
        if (tid < 128) {
            int e = tid;
            int r = e >> 3, c = (e & 7) ^ (r & 7);
            gload_lds16(A + (long)(bm + r) * 256 + k0 + c * 8, As + e * 8);
        }
        #pragma unroll
        for (int i = 0; i < 8; i++) {
            int e = i * 256 + tid;
            int r = e >> 3, c = (e & 7) ^ (r & 7);
            gload_lds16(W + (long)r * 256 + k0 + c * 8, Bs + e * 8);
        }
        __syncthreads();
        #pragma unroll
        for (int s = 0; s < 2; s++) {
            v8bf af = *(v8bf*)&As[n16 * 64 + (((quad + s * 4) ^ (n16 & 7))) * 8];
            #pragma unroll
            for (int nj = 0; nj < 4; nj++) {
                int row = wn + nj * 16 + n16;
                v8bf bfr = *(v8bf*)&Bs[row * 64 + (((quad + s * 4) ^ (row & 7))) * 8];
                acc[nj] = __builtin_amdgcn_mfma_f32_16x16x32_bf16(af, bfr, acc[nj], 0, 0, 0);
            }
        }
    }

    float y[4][4], s1[4] = {}, s2[4] = {};
    #pragma unroll
    for (int r = 0; r < 4; r++) {
        int m = bm + quad * 4 + r;
        #pragma unroll
        for (int nj = 0; nj < 4; nj++) {
            int nn = wn + nj * 16 + n16;
            float v = acc[nj][r] + bias[nn] + res[(long)m * 256 + nn];
            y[r][nj] = v;
            s1[r] += v; s2[r] += v * v;
        }
    }
    #pragma unroll
    for (int r = 0; r < 4; r++) {
        #pragma unroll
        for (int off = 1; off < 16; off <<= 1) {
            s1[r] += __shfl_xor(s1[r], off, 16);
            s2[r] += __shfl_xor(s2[r], off, 16);
        }
    }
    if (n16 == 0) {
        #pragma unroll
        for (int r = 0; r < 4; r++) {
            redS[wave * 16 + quad * 4 + r] = s1[r];
            redQ[wave * 16 + quad * 4 + r] = s2[r];
        }
    }
    __syncthreads();
    #pragma unroll
    for (int r = 0; r < 4; r++) {
        int mr = quad * 4 + r;
        float ts = redS[mr] + redS[16 + mr] + redS[32 + mr] + redS[48 + mr];
        float tq = redQ[mr] + redQ[16 + mr] + redQ[32 + mr] + redQ[48 + mr];
        float mean = ts * (1.0f / 256.0f);
        float var = tq * (1.0f / 256.0f) - mean * mean;
        float rinv = rsqrtf(var + 1e-5f);
        int m = bm + mr;
        #pragma unroll
        for (int nj = 0; nj < 4; nj++) {
            int nn = wn + nj * 16 + n16;
            float o = (y[r][nj] - mean) * rinv * g[nn] + beta[nn];
            outf[(long)m * 256 + nn] = o;
            Axq[mr * 264 + nn] = (__bf16)(o + qpos_t[(long)m * 256 + nn]);
        }
    }
    __syncthreads();
    // soaw projection: 16 x 96, K=256, waves 0..2 handle 32 cols each
    if (wave < 3) {
        v4f sacc[2] = {};
        #pragma unroll
        for (int k0 = 0; k0 < 256; k0 += 32) {
            v8bf af = *(v8bf*)&Axq[n16 * 264 + k0 + quad * 8];
            #pragma unroll
            for (int t = 0; t < 2; t++) {
                int col = wave * 32 + t * 16 + n16;
                v8bf bw = *(const v8bf*)(Wsm + (long)col * 256 + k0 + quad * 8);
                sacc[t] = __builtin_amdgcn_mfma_f32_16x16x32_bf16(af, bw, sacc[t], 0, 0, 0);
            }
        }
        #pragma unroll
        for (int t = 0; t < 2; t++)
            #pragma unroll
            for (int r = 0; r < 4; r++) {
                int mm = bm + quad * 4 + r;
                int col = wave * 32 + t * 16 + n16;
                soawO[(long)mm * 96 + col] = sacc[t][r] + bsm[col];
            }
    }
}

// ====== msdeform bilinear sampling (2000 blocks, 2 queries/block) ======
__global__ __launch_bounds__(256) void msds_kernel(
    const __bf16* __restrict__ vproj, const float* __restrict__ soaw,
    const float* __restrict__ refp, __bf16* __restrict__ out)
{
    int t = threadIdx.x;
    int bq = blockIdx.x * 2 + (t >> 7);
    int b = bq / NQ; int q = bq % NQ;
    int t2 = t & 127;
    int h = t2 >> 4;            // 0..7
    int d0 = (t2 & 15) * 2;     // 0,2,...,30
    float rx = refp[(b * NQ + q) * 2 + 0];
    float ry = refp[(b * NQ + q) * 2 + 1];
    const float* rowp = soaw + (long)(b * NQ + q) * 96;
    const float* offp = rowp + h * 8;
    const float* awp  = rowp + 64 + h * 4;
    float a0 = awp[0], a1 = awp[1], a2 = awp[2], a3 = awp[3];
    float m = fmaxf(fmaxf(a0, a1), fmaxf(a2, a3));
    float e0 = __expf(a0 - m), e1 = __expf(a1 - m), e2 = __expf(a2 - m), e3 = __expf(a3 - m);
    float invs = 1.0f / (e0 + e1 + e2 + e3);
    float accA = 0.f, accB = 0.f;
    #pragma unroll
    for (int p = 0; p < PN; p++) {
        float ew = (p == 0 ? e0 : p == 1 ? e1 : p == 2 ? e2 : e3) * invs;
        float xim = rx * (float)WBEV + offp[p * 2 + 0] - 0.5f;
        float yim = ry * (float)HBEV + offp[p * 2 + 1] - 0.5f;
        float x0f = floorf(xim), y0f = floorf(yim);
        float lx = xim - x0f, ly = yim - y0f;
        int x0 = (int)x0f, y0 = (int)y0f;
        float gA = 0.f, gB = 0.f;
        #pragma unroll
        for (int dy = 0; dy < 2; dy++) {
            #pragma unroll
            for (int dx = 0; dx < 2; dx++) {
                int xi = x0 + dx, yi = y0 + dy;
                float w = (dx ? lx : 1.f - lx) * (dy ? ly : 1.f - ly);
                bool ok = (xi >= 0 && xi < WBEV && yi >= 0 && yi < HBEV);
                int xc = min(max(xi, 0), WBEV - 1);
                int yc = min(max(yi, 0), HBEV - 1);
                int idx = yc * WBEV + xc;
                v2bf gv = *(const v2bf*)(vproj + ((long)(idx * BS + b)) * CDIM + h * HD + d0);
                float wk = (ok ? w : 0.f);
                gA += wk * (float)gv[0];
                gB += wk * (float)gv[1];
            }
        }
        accA += ew * gA;
        accB += ew * gB;
    }
    v2bf o2; o2[0] = (__bf16)accA; o2[1] = (__bf16)accB;
    *(v2bf*)(out + (long)(b * NQ + q) * CDIM + h * HD + d0) = o2;
}

// == fused tail @512 threads (8 waves x 32 cols): op-proj+LN2 -> FFN1 ->
//    FFN2+res+LN3 -> transpose-out.  250 blocks, ~60 KB LDS. ==
__global__ __launch_bounds__(512) void gtail_kernel(
    const __bf16* __restrict__ A, const __bf16* __restrict__ Wop,
    const float* __restrict__ opb, const float* __restrict__ res,
    const float* __restrict__ g2, const float* __restrict__ b2ln,
    const __bf16* __restrict__ W1, const float* __restrict__ b1,
    const __bf16* __restrict__ W2, const float* __restrict__ bff2,
    const float* __restrict__ g3, const float* __restrict__ b3ln,
    float* __restrict__ outf)
{
    __shared__ __align__(16) char smem[60416];
    __bf16* As  = (__bf16*)smem;              // [16][64]    phase-A A staging
    __bf16* Bs  = (__bf16*)(smem + 2048);     // [256][64]   weight staging
    __bf16* As2 = (__bf16*)(smem + 34816);    // [4][16][64] LN2-out (swizzled)
    __bf16* h1s = (__bf16*)(smem + 43008);    // [8][16][64] FFN1-out (swizzled)
    float* redS = (float*)(smem + 59392);     // [128]
    float* redQ = (float*)(smem + 59904);     // [128]
    int tid = threadIdx.x;
    int bm = blockIdx.x * 16;
    int wave = tid >> 6, lane = tid & 63, quad = lane >> 4, n16 = lane & 15;
    int wn = wave * 32;
    int mr_ = quad * 4;   // row base for this lane's 4 rows

    // ---------- Phase A: op-proj (K=256) + residual + LN2 ----------
    v4f acc[2] = {};
    for (int k0 = 0; k0 < 256; k0 += 64) {
        __syncthreads();
        if (tid < 128) {
            int e = tid;
            int r = e >> 3, c = (e & 7) ^ (r & 7);
            gload_lds16(A + (long)(bm + r) * 256 + k0 + c * 8, As + e * 8);
        }
        #pragma unroll
        for (int i = 0; i < 4; i++) {
            int e = i * 512 + tid;
            int r = e >> 3, c = (e & 7) ^ (r & 7);
            gload_lds16(Wop + (long)r * 256 + k0 + c * 8, Bs + e * 8);
        }
        __syncthreads();
        #pragma unroll
        for (int s = 0; s < 2; s++) {
            v8bf af = *(v8bf*)&As[n16 * 64 + (((quad + s * 4) ^ (n16 & 7))) * 8];
            #pragma unroll
            for (int nj = 0; nj < 2; nj++) {
                int row = wn + nj * 16 + n16;
                v8bf bfr = *(v8bf*)&Bs[row * 64 + (((quad + s * 4) ^ (row & 7))) * 8];
                acc[nj] = __builtin_amdgcn_mfma_f32_16x16x32_bf16(af, bfr, acc[nj], 0, 0, 0);
            }
        }
    }
    float yv[4][2], s1[4] = {}, s2[4] = {};
    #pragma unroll
    for (int r = 0; r < 4; r++) {
        int m = bm + mr_ + r;
        #pragma unroll
        for (int nj = 0; nj < 2; nj++) {
            int nn = wn + nj * 16 + n16;
            float v = acc[nj][r] + opb[nn] + res[(long)m * 256 + nn];
            yv[r][nj] = v;
            s1[r] += v; s2[r] += v * v;
        }
    }
    #pragma unroll
    for (int r = 0; r < 4; r++) {
        #pragma unroll
        for (int off = 1; off < 16; off <<= 1) {
            s1[r] += __shfl_xor(s1[r], off, 16);
            s2[r] += __shfl_xor(s2[r], off, 16);
        }
    }
    if (n16 == 0) {
        #pragma unroll
        for (int r = 0; r < 4; r++) {
            redS[wave * 16 + mr_ + r] = s1[r];
            redQ[wave * 16 + mr_ + r] = s2[r];
        }
    }
    __syncthreads();
    #pragma unroll
    for (int r = 0; r < 4; r++) {
        int mr = mr_ + r;
        float ts = 0.f, tq = 0.f;
        #pragma unroll
        for (int j = 0; j < 8; j++) { ts += redS[j * 16 + mr]; tq += redQ[j * 16 + mr]; }
        float mean = ts * (1.0f / 256.0f);
        float var = tq * (1.0f / 256.0f) - mean * mean;
        float rinv = rsqrtf(var + 1e-5f);
        #pragma unroll
        for (int nj = 0; nj < 2; nj++) {
            int nn = wn + nj * 16 + n16;
            float o = (yv[r][nj] - mean) * rinv * g2[nn] + b2ln[nn];
            yv[r][nj] = o;   // keep x2 residual in registers
            int kc = nn >> 6, c6 = nn & 63;
            As2[kc * 1024 + mr * 64 + (((c6 >> 3) ^ (mr & 7)) << 3) + (c6 & 7)] = (__bf16)o;
        }
    }

    // ---------- Phase B: FFN1 (K=256, N=512 in two halves) + ReLU ----------
    #pragma unroll 1
    for (int H = 0; H < 2; H++) {
        v4f accB[2] = {};
        for (int k0 = 0; k0 < 256; k0 += 64) {
            __syncthreads();
            #pragma unroll
            for (int i = 0; i < 4; i++) {
                int e = i * 512 + tid;
                int r = e >> 3, c = (e & 7) ^ (r & 7);
                gload_lds16(W1 + (long)(H * 256 + r) * 256 + k0 + c * 8, Bs + e * 8);
            }
            __syncthreads();
            int kc = k0 >> 6;
            #pragma unroll
            for (int s = 0; s < 2; s++) {
                v8bf af = *(v8bf*)&As2[kc * 1024 + n16 * 64 + (((quad + s * 4) ^ (n16 & 7))) * 8];
                #pragma unroll
                for (int nj = 0; nj < 2; nj++) {
                    int row = wn + nj * 16 + n16;
                    v8bf bfr = *(v8bf*)&Bs[row * 64 + (((quad + s * 4) ^ (row & 7))) * 8];
                    accB[nj] = __builtin_amdgcn_mfma_f32_16x16x32_bf16(af, bfr, accB[nj], 0, 0, 0);
                }
            }
        }
        #pragma unroll
        for (int r = 0; r < 4; r++) {
            int mr = mr_ + r;
            #pragma unroll
            for (int nj = 0; nj < 2; nj++) {
                int col = H * 256 + wn + nj * 16 + n16;
                float v = accB[nj][r] + b1[col];
                v = fmaxf(v, 0.f);
                int kc = col >> 6, c6 = col & 63;
                h1s[kc * 1024 + mr * 64 + (((c6 >> 3) ^ (mr & 7)) << 3) + (c6 & 7)] = (__bf16)v;
            }
        }
    }

    // ---------- Phase C: FFN2 (K=512) + bias + x2 residual + LN3 ----------
    v4f acc3[2] = {};
    for (int k0 = 0; k0 < 512; k0 += 64) {
        __syncthreads();
        #pragma unroll
        for (int i = 0; i < 4; i++) {
            int e = i * 512 + tid;
            int r = e >> 3, c = (e & 7) ^ (r & 7);
            gload_lds16(W2 + (long)r * 512 + k0 + c * 8, Bs + e * 8);
        }
        __syncthreads();
        int kc = k0 >> 6;
        #pragma unroll
        for (int s = 0; s < 2; s++) {
            v8bf af = *(v8bf*)&h1s[kc * 1024 + n16 * 64 + (((quad + s * 4) ^ (n16 & 7))) * 8];
            #pragma unroll
            for (int nj = 0; nj < 2; nj++) {
                int row = wn + nj * 16 + n16;
                v8bf bfr = *(v8bf*)&Bs[row * 64 + (((quad + s * 4) ^ (row & 7))) * 8];
                acc3[nj] = __builtin_amdgcn_mfma_f32_16x16x32_bf16(af, bfr, acc3[nj], 0, 0, 0);
            }
        }
    }
    float y3[4][2], t1[4] = {}, t2[4] = {};
    #pragma unroll
    for (int r = 0; r < 4; r++) {
        #pragma unroll
        for (int nj = 0; nj < 2; nj++) {
            int nn = wn + nj * 16 + n16;
            float v = acc3[nj][r] + bff2[nn] + yv[r][nj];
            y3[r][nj] = v;
            t1[r] += v; t2[r] += v * v;
        }
    }
    #pragma unroll
    for (int r = 0; r < 4; r++) {
        #pragma unroll
        for (int off = 1; off < 16; off <<= 1) {
            t1[r] += __shfl_xor(t1[r], off, 16);
            t2[r] += __shfl_xor(t2[r], off, 16);
        }
    }
    __syncthreads();   // red arrays free for reuse
    if (n16 == 0) {
        #pragma unroll
        for (int r = 0; r < 4; r++) {
            redS[wave * 16 + mr_ + r] = t1[r];
            redQ[wave * 16 + mr_ + r] = t2[r];
        }
    }
    __syncthreads();
    #pragma unroll
    for (int r = 0; r < 4; r++) {
        int mr = mr_ + r;
        float ts = 0.f, tq = 0.f;
        #pragma unroll
        for (int j = 0; j < 8; j++) { ts += redS[j * 16 + mr]; tq += redQ[j * 16 + mr]; }
        float mean = ts * (1.0f / 256.0f);
        float var = tq * (1.0f / 256.0f) - mean * mean;
        float rinv = rsqrtf(var + 1e-5f);
        int m = bm + mr;
        int b = m / NQ, q = m - b * NQ;
        #pragma unroll
        for (int nj = 0; nj < 2; nj++) {
            int nn = wn + nj * 16 + n16;
            float o = (y3[r][nj] - mean) * rinv * g3[nn] + b3ln[nn];
            outf[(long)(q * BS + b) * 256 + nn] = o;
        }
    }
}

extern "C" void kernel_launch(void* const* d_in, const int* in_sizes, int n_in,
                              void* d_out, int out_size, void* d_ws, size_t ws_size,
                              hipStream_t stream) {
    const float* query = (const float*)d_in[0];
    const float* value = (const float*)d_in[1];
    const float* qpos  = (const float*)d_in[2];
    const float* refp  = (const float*)d_in[3];
    const float* in_w  = (const float*)d_in[6];
    const float* in_b  = (const float*)d_in[7];
    const float* mha_ow = (const float*)d_in[8];
    const float* mha_ob = (const float*)d_in[9];
    const float* so_w  = (const float*)d_in[10];
    const float* so_b  = (const float*)d_in[11];
    const float* aw_w  = (const float*)d_in[12];
    const float* aw_b  = (const float*)d_in[13];
    const float* vp_w  = (const float*)d_in[14];
    const float* vp_b  = (const float*)d_in[15];
    const float* op_w  = (const float*)d_in[16];
    const float* op_b  = (const float*)d_in[17];
    const float* ffn_w1 = (const float*)d_in[18];
    const float* ffn_b1 = (const float*)d_in[19];
    const float* ffn_w2 = (const float*)d_in[20];
    const float* ffn_b2 = (const float*)d_in[21];
    const float* ln1_g = (const float*)d_in[22];
    const float* ln1_b = (const float*)d_in[23];
    const float* ln2_g = (const float*)d_in[24];
    const float* ln2_b = (const float*)d_in[25];
    const float* ln3_g = (const float*)d_in[26];
    const float* ln3_b = (const float*)d_in[27];
    float* out = (float*)d_out;

    const long NTOK = (long)BS * NQ * CDIM;   // 1,024,000

    float* x      = (float*)d_ws;
    float* qpos_t = x + NTOK;
    float* x1     = qpos_t + NTOK;
    float* x2     = x1 + NTOK;                       // (unused, keeps layout)
    float* soaw   = x2 + NTOK;                       // 4000*96
    float* bsmall = soaw + (long)BS * NQ * 96;       // 128
    __bf16* x_bf   = (__bf16*)(bsmall + 128);
    __bf16* xq_bf  = x_bf + NTOK;
    __bf16* qk_bf  = xq_bf + NTOK;                   // 2*NTOK (q|k, stride 512)
    __bf16* vh_bf  = qk_bf + 2 * NTOK;
    __bf16* aA_bf  = vh_bf + NTOK;
    __bf16* x2_bf  = aA_bf + NTOK;                   // (unused)
    __bf16* h1_bf  = x2_bf + NTOK;                   // (unused)
    __bf16* vpj_bf = h1_bf + 2 * NTOK;               // 20,480,000
    __bf16* wb     = vpj_bf + (long)BS * NVAL * CDIM;
    __bf16* inw_b  = wb;
    __bf16* mow_b  = wb + 196608;
    __bf16* vpw_b  = wb + 262144;
    __bf16* opw_b  = wb + 327680;
    __bf16* fw1_b  = wb + 393216;
    __bf16* fw2_b  = wb + 524288;
    __bf16* wsmall = wb + 655360;                    // 128x256

    dim3 blk(256);

    prep_all_kernel<<<4673, blk, 0, stream>>>(
        query, qpos, in_w, mha_ow, vp_w, op_w, ffn_w1, ffn_w2,
        so_w, aw_w, so_b, aw_b,
        x, qpos_t, x_bf, xq_bf, wb, wsmall, bsmall);

    // q|k|v in-proj (756, 16 KB LDS)
    qkvv_kernel<<<756, blk, 0, stream>>>(xq_bf, x_bf, inw_b, in_b, qk_bf, vh_bf);

    // value-proj GEMM, dedicated launch (1250 blocks, ~4.9/CU)
    vgemm_kernel<<<1250, blk, 0, stream>>>(value, vpw_b, vp_b, vpj_bf);

    // flash attention TK=64 (512, 28 KB LDS)
    fattnv_kernel<<<512, blk, 0, stream>>>(qk_bf, vh_bf, aA_bf);

    // mha out-proj + res(x) + LN1 + fused soaw projection (250)
    gln1s_kernel<<<250, blk, 0, stream>>>(
        aA_bf, mow_b, mha_ob, x, ln1_g, ln1_b, qpos_t, wsmall, bsmall,
        x1, soaw);

    // msdeform sampling (2000 blocks, 2 queries each, 4B gathers)
    msds_kernel<<<2000, blk, 0, stream>>>(vpj_bf, soaw, refp, aA_bf);

    // fused tail @512 threads: op-proj+LN2 -> FFN1 -> FFN2+LN3 -> out
    gtail_kernel<<<250, dim3(512), 0, stream>>>(
        aA_bf, opw_b, op_b, x1, ln2_g, ln2_b,
        fw1_b, ffn_b1, fw2_b, ffn_b2, ln3_g, ln3_b, out);
}

// Round 5
// 261.052 us; speedup vs baseline: 1.3238x; 1.0124x over previous
//
#include <hip/hip_runtime.h>
#include <hip/hip_bf16.h>
#include <cmath>

#define BS   4
#define NQ   1000
#define CDIM 256
#define NH   8
#define HD   32
#define NVAL 20000
#define FFND 512
#define PN   4
#define WBEV 100
#define HBEV 200
#define TK   64

typedef __bf16 v8bf __attribute__((ext_vector_type(8)));
typedef __bf16 v2bf __attribute__((ext_vector_type(2)));
typedef float  v4f  __attribute__((ext_vector_type(4)));

__device__ __forceinline__ void gload_lds16(const void* g, void* l) {
    __builtin_amdgcn_global_load_lds(
        (const __attribute__((address_space(1))) unsigned int*)g,
        (__attribute__((address_space(3))) unsigned int*)l, 16, 0, 0);
}

// ============ value-proj block: 64 rows x 256 cols; value read once ========
__device__ __forceinline__ void vgemm64_block(
    int vb, const float* __restrict__ value, const __bf16* __restrict__ Wv,
    const float* __restrict__ bv, __bf16* __restrict__ vpj, char* smem)
{
    __bf16* As = (__bf16*)smem;             // [64][64]
    __bf16* Bs = (__bf16*)(smem + 8192);    // [256][64]
    int tid = threadIdx.x;
    int wave = tid >> 6, lane = tid & 63, quad = lane >> 4, n16 = lane & 15;
    int bm = vb * 64;
    int wm = (wave & 1) * 32, wn = (wave >> 1) * 128;
    v4f acc[2][8] = {};

    for (int k0 = 0; k0 < 256; k0 += 64) {
        float4 fa[2][2];
        #pragma unroll
        for (int i = 0; i < 2; i++) {
            int e = i * 256 + tid;
            int r = e >> 3, c = (e & 7) ^ (r & 7);
            const float* p = value + (long)(bm + r) * 256 + k0 + c * 8;
            fa[i][0] = *(const float4*)p;
            fa[i][1] = *(const float4*)(p + 4);
        }
        __syncthreads();
        #pragma unroll
        for (int i = 0; i < 2; i++) {
            int e = i * 256 + tid;
            v8bf v;
            v[0] = (__bf16)fa[i][0].x; v[1] = (__bf16)fa[i][0].y;
            v[2] = (__bf16)fa[i][0].z; v[3] = (__bf16)fa[i][0].w;
            v[4] = (__bf16)fa[i][1].x; v[5] = (__bf16)fa[i][1].y;
            v[6] = (__bf16)fa[i][1].z; v[7] = (__bf16)fa[i][1].w;
            *(v8bf*)(As + e * 8) = v;
        }
        #pragma unroll
        for (int i = 0; i < 8; i++) {
            int e = i * 256 + tid;
            int r = e >> 3, c = (e & 7) ^ (r & 7);
            gload_lds16(Wv + (long)r * 256 + k0 + c * 8, Bs + e * 8);
        }
        __syncthreads();
        #pragma unroll
        for (int s = 0; s < 2; s++) {
            v8bf af[2], bfr[8];
            #pragma unroll
            for (int mi = 0; mi < 2; mi++) {
                int row = wm + mi * 16 + n16;
                af[mi] = *(v8bf*)&As[row * 64 + (((quad + s * 4) ^ (row & 7))) * 8];
            }
            #pragma unroll
            for (int nj = 0; nj < 8; nj++) {
                int row = wn + nj * 16 + n16;
                bfr[nj] = *(v8bf*)&Bs[row * 64 + (((quad + s * 4) ^ (row & 7))) * 8];
            }
            #pragma unroll
            for (int mi = 0; mi < 2; mi++)
                #pragma unroll
                for (int nj = 0; nj < 8; nj++)
                    acc[mi][nj] = __builtin_amdgcn_mfma_f32_16x16x32_bf16(af[mi], bfr[nj], acc[mi][nj], 0, 0, 0);
        }
    }
    #pragma unroll
    for (int mi = 0; mi < 2; mi++) {
        #pragma unroll
        for (int r = 0; r < 4; r++) {
            int m = bm + wm + mi * 16 + quad * 4 + r;
            #pragma unroll
            for (int nj = 0; nj < 8; nj++) {
                int nn = wn + nj * 16 + n16;
                vpj[(long)m * 256 + nn] = (__bf16)(acc[mi][nj][r] + bv[nn]);
            }
        }
    }
}

// ============ prep_all: weight cast | prep | soaw pack ============
__global__ __launch_bounds__(256) void prep_all_kernel(
    const float* __restrict__ query, const float* __restrict__ qpos,
    const float* __restrict__ in_w, const float* __restrict__ mha_ow,
    const float* __restrict__ vp_w, const float* __restrict__ op_w,
    const float* __restrict__ ffn_w1, const float* __restrict__ ffn_w2,
    const float* __restrict__ so_w, const float* __restrict__ aw_w,
    const float* __restrict__ so_b, const float* __restrict__ aw_b,
    float* __restrict__ x, float* __restrict__ qpos_t,
    __bf16* __restrict__ x_bf, __bf16* __restrict__ xq_bf,
    __bf16* __restrict__ wb, __bf16* __restrict__ wsmall,
    float* __restrict__ bsmall)
{
    int blk = blockIdx.x, tid = threadIdx.x;
    if (blk < 640) {
        long e = ((long)blk * 256 + tid) * 4;
        const float* src; long off;
        if      (e < 196608) { src = in_w;   off = e; }
        else if (e < 262144) { src = mha_ow; off = e - 196608; }
        else if (e < 327680) { src = vp_w;   off = e - 262144; }
        else if (e < 393216) { src = op_w;   off = e - 327680; }
        else if (e < 524288) { src = ffn_w1; off = e - 393216; }
        else                 { src = ffn_w2; off = e - 524288; }
        float4 v = *(const float4*)(src + off);
        __bf16* d = wb + e;
        d[0] = (__bf16)v.x; d[1] = (__bf16)v.y; d[2] = (__bf16)v.z; d[3] = (__bf16)v.w;
    } else if (blk < 4640) {
        int qb = blk - 640;
        int q = qb / BS, b = qb % BS;
        float qv = query[(q * BS + b) * CDIM + tid];
        float pv = qpos [(q * BS + b) * CDIM + tid];
        int o = (b * NQ + q) * CDIM + tid;
        x[o] = qv; qpos_t[o] = pv;
        x_bf[o] = (__bf16)qv; xq_bf[o] = (__bf16)(qv + pv);
    } else if (blk < 4672) {
        long e = ((long)(blk - 4640) * 256 + tid) * 4;
        int row = (int)(e >> 8), col = (int)(e & 255);
        float4 v = {0.f, 0.f, 0.f, 0.f};
        if (row < 64)      v = *(const float4*)(so_w + row * 256 + col);
        else if (row < 96) v = *(const float4*)(aw_w + (row - 64) * 256 + col);
        __bf16* d = wsmall + e;
        d[0] = (__bf16)v.x; d[1] = (__bf16)v.y; d[2] = (__bf16)v.z; d[3] = (__bf16)v.w;
    } else {
        if (tid < 128) bsmall[tid] = tid < 64 ? so_b[tid] : (tid < 96 ? aw_b[tid - 64] : 0.f);
    }
}

// ====== fused q|k|v projection (756) + value-proj rider (1250) = 2006 ======
// qkvv at 756 blocks is <=3 blocks/CU regardless, so the 40 KB rider LDS
// costs no occupancy; riders backfill CUs as qkvv blocks drain.
__global__ __launch_bounds__(256) void qkvv_kernel(
    const __bf16* __restrict__ xq, const __bf16* __restrict__ xv,
    const __bf16* __restrict__ W, const float* __restrict__ bias,
    __bf16* __restrict__ qk, __bf16* __restrict__ vh,
    const float* __restrict__ value, const __bf16* __restrict__ Wv,
    const float* __restrict__ bv, __bf16* __restrict__ vpj)
{
    __shared__ __align__(16) char smem[40960];
    int tid = threadIdx.x;
    if ((int)blockIdx.x >= 756) {
        vgemm64_block(blockIdx.x - 756, value, Wv, bv, vpj, smem);
        return;
    }
    int blk = blockIdx.x;
    int bn = (blk % 12) * 64, bm = (blk / 12) * 64;
    __bf16* As = (__bf16*)smem;             // [64][64]
    __bf16* Bs = (__bf16*)(smem + 8192);    // [64][64]
    const __bf16* A = (bn < 512) ? xq : xv;
    int wave = tid >> 6, lane = tid & 63, quad = lane >> 4, n16 = lane & 15;
    int wm = (wave & 1) * 32, wn = (wave >> 1) * 32;
    v4f acc[2][2] = {};

    for (int k0 = 0; k0 < 256; k0 += 64) {
        __syncthreads();
        #pragma unroll
        for (int i = 0; i < 2; i++) {
            int e = i * 256 + tid;
            int r = e >> 3, c = (e & 7) ^ (r & 7);
            int row = bm + r; if (row > BS * NQ - 1) row = BS * NQ - 1;
            gload_lds16(A + (long)row * 256 + k0 + c * 8, As + e * 8);
        }
        #pragma unroll
        for (int i = 0; i < 2; i++) {
            int e = i * 256 + tid;
            int r = e >> 3, c = (e & 7) ^ (r & 7);
            gload_lds16(W + (long)(bn + r) * 256 + k0 + c * 8, Bs + e * 8);
        }
        __syncthreads();
        #pragma unroll
        for (int s = 0; s < 2; s++) {
            v8bf af[2], bfr[2];
            #pragma unroll
            for (int mi = 0; mi < 2; mi++) {
                int row = wm + mi * 16 + n16;
                af[mi] = *(v8bf*)&As[row * 64 + (((quad + s * 4) ^ (row & 7))) * 8];
            }
            #pragma unroll
            for (int nj = 0; nj < 2; nj++) {
                int row = wn + nj * 16 + n16;
                bfr[nj] = *(v8bf*)&Bs[row * 64 + (((quad + s * 4) ^ (row & 7))) * 8];
            }
            #pragma unroll
            for (int mi = 0; mi < 2; mi++)
                #pragma unroll
                for (int nj = 0; nj < 2; nj++)
                    acc[mi][nj] = __builtin_amdgcn_mfma_f32_16x16x32_bf16(af[mi], bfr[nj], acc[mi][nj], 0, 0, 0);
        }
    }

    #pragma unroll
    for (int mi = 0; mi < 2; mi++) {
        #pragma unroll
        for (int r = 0; r < 4; r++) {
            int m = bm + wm + mi * 16 + quad * 4 + r;
            if (m >= BS * NQ) continue;
            #pragma unroll
            for (int nj = 0; nj < 2; nj++) {
                int nn = bn + wn + nj * 16 + n16;
                float v = acc[mi][nj][r] + bias[nn];
                if (nn < 512) qk[(long)m * 512 + nn] = (__bf16)v;
                else          vh[(long)m * 256 + (nn - 512)] = (__bf16)v;
            }
        }
    }
}

// ====== flash attention, split-K 2-way (1024 blocks); fp32 partials ======
// Fixed-M0 softmax => partials combine exactly: o = (o0+o1)/(l0+l1).
__global__ __launch_bounds__(256) void fattns_kernel(
    const __bf16* __restrict__ qk, const __bf16* __restrict__ vh,
    float* __restrict__ op0, float* __restrict__ op1, float* __restrict__ lpart)
{
    __shared__ __align__(16) char smem[28672];
    int tid = threadIdx.x;
    int fb = blockIdx.x;
    int split = fb >> 9;
    int f2 = fb & 511;
    int qt = f2 & 15, h = (f2 >> 4) & 7, b = f2 >> 7;
    __bf16* Ks = (__bf16*)smem;             // [2][64][40]  = 10240 B
    __bf16* Vt = (__bf16*)(smem + 10240);   // [2][32][72]  =  9216 B
    __bf16* Pl = (__bf16*)(smem + 19456);   // [4][16][72]  =  9216 B
    int wave = tid >> 6, lane = tid & 63, quad = lane >> 4, n = lane & 15;
    int q0 = qt * 64 + wave * 16;
    const float scale = 0.17677669529663687f;
    const float M0 = 8.0f;

    int qrow = q0 + n; if (qrow > NQ - 1) qrow = NQ - 1;
    v8bf aq = *(const v8bf*)(qk + (long)(b * NQ + qrow) * 512 + h * HD + quad * 8);

    v4f o0 = {}, o1 = {};
    float lp[4] = {0.f, 0.f, 0.f, 0.f};

    int sv = tid >> 7;          // 0: stage K, 1: stage V
    int t2 = tid & 127;
    int key = t2 & 63;
    int d16 = (t2 >> 6) * 16;

    v8bf stg0, stg1;
    auto loadtile = [&](int k0) {
        int krow = k0 + key; if (krow > NQ - 1) krow = NQ - 1;
        const __bf16* p = sv ? (vh + (long)(b * NQ + krow) * CDIM + h * HD + d16)
                             : (qk + (long)(b * NQ + krow) * 512 + 256 + h * HD + d16);
        stg0 = *(const v8bf*)p;
        stg1 = *(const v8bf*)(p + 8);
    };

    int kstart = split * 512;
    int kend = split ? NQ : 512;
    loadtile(kstart);
    int pb = 0;
    for (int k0 = kstart; k0 < kend; k0 += TK) {
        if (sv == 0) {
            *(v8bf*)&Ks[(pb * 64 + key) * 40 + d16]     = stg0;
            *(v8bf*)&Ks[(pb * 64 + key) * 40 + d16 + 8] = stg1;
        } else {
            #pragma unroll
            for (int j = 0; j < 8; j++) {
                Vt[(pb * 32 + d16 + j) * 72 + key]            = stg0[j];
                Vt[(pb * 32 + d16 + 8 + j) * 72 + (key ^ 16)] = stg1[j];
            }
        }
        if (k0 + TK < kend) loadtile(k0 + TK);
        __syncthreads();

        v8bf bk0 = *(v8bf*)&Ks[(pb * 64 +      n) * 40 + quad * 8];
        v8bf bk1 = *(v8bf*)&Ks[(pb * 64 + 16 + n) * 40 + quad * 8];
        v8bf bk2 = *(v8bf*)&Ks[(pb * 64 + 32 + n) * 40 + quad * 8];
        v8bf bk3 = *(v8bf*)&Ks[(pb * 64 + 48 + n) * 40 + quad * 8];
        v4f z = {};
        v4f S0 = __builtin_amdgcn_mfma_f32_16x16x32_bf16(aq, bk0, z, 0, 0, 0);
        v4f S1 = __builtin_amdgcn_mfma_f32_16x16x32_bf16(aq, bk1, z, 0, 0, 0);
        v4f S2 = __builtin_amdgcn_mfma_f32_16x16x32_bf16(aq, bk2, z, 0, 0, 0);
        v4f S3 = __builtin_amdgcn_mfma_f32_16x16x32_bf16(aq, bk3, z, 0, 0, 0);

        bool last = (k0 + TK > NQ);
        float p0[4], p1[4], p2[4], p3[4];
        #pragma unroll
        for (int r = 0; r < 4; r++) {
            p0[r] = __expf(fmaf(S0[r], scale, -M0));
            p1[r] = __expf(fmaf(S1[r], scale, -M0));
            p2[r] = __expf(fmaf(S2[r], scale, -M0));
            p3[r] = __expf(fmaf(S3[r], scale, -M0));
            if (last) {
                if (k0 + 32 + n >= NQ) p2[r] = 0.f;
                if (k0 + 48 + n >= NQ) p3[r] = 0.f;
            }
            lp[r] += p0[r] + p1[r] + p2[r] + p3[r];
        }
        #pragma unroll
        for (int r = 0; r < 4; r++) {
            __bf16* pp = &Pl[(wave * 16 + quad * 4 + r) * 72];
            pp[n]      = (__bf16)p0[r];
            pp[16 + n] = (__bf16)p1[r];
            pp[32 + n] = (__bf16)p2[r];
            pp[48 + n] = (__bf16)p3[r];
        }
        asm volatile("s_waitcnt lgkmcnt(0)" ::: "memory");
        v8bf ap0 = *(v8bf*)&Pl[(wave * 16 + n) * 72 + quad * 8];
        v8bf ap1 = *(v8bf*)&Pl[(wave * 16 + n) * 72 + 32 + quad * 8];
        int swz = ((n >> 3) & 1) << 4;
        int c0 = (quad * 8) ^ swz;
        int c1 = (32 + quad * 8) ^ swz;
        v8bf bv00 = *(v8bf*)&Vt[(pb * 32 +      n) * 72 + c0];
        v8bf bv01 = *(v8bf*)&Vt[(pb * 32 +      n) * 72 + c1];
        v8bf bv10 = *(v8bf*)&Vt[(pb * 32 + 16 + n) * 72 + c0];
        v8bf bv11 = *(v8bf*)&Vt[(pb * 32 + 16 + n) * 72 + c1];
        o0 = __builtin_amdgcn_mfma_f32_16x16x32_bf16(ap0, bv00, o0, 0, 0, 0);
        o0 = __builtin_amdgcn_mfma_f32_16x16x32_bf16(ap1, bv01, o0, 0, 0, 0);
        o1 = __builtin_amdgcn_mfma_f32_16x16x32_bf16(ap0, bv10, o1, 0, 0, 0);
        o1 = __builtin_amdgcn_mfma_f32_16x16x32_bf16(ap1, bv11, o1, 0, 0, 0);
        pb ^= 1;
    }

    float* oP = split ? op1 : op0;
    #pragma unroll
    for (int r = 0; r < 4; r++) {
        float l = lp[r];
        #pragma unroll
        for (int off = 1; off < 16; off <<= 1) l += __shfl_xor(l, off, 16);
        int q = q0 + quad * 4 + r;
        if (q < NQ) {
            float* opp = oP + (long)(b * NQ + q) * 256 + h * HD;
            opp[n]      = o0[r];
            opp[16 + n] = o1[r];
            if (n == 0) lpart[split * 32000 + (b * NQ + q) * 8 + h] = l;
        }
    }
}

// ==== split-combine + mha out-proj + res + LN1 + soaw projection (250) ====
__global__ __launch_bounds__(256) void gln1s_kernel(
    const float* __restrict__ op0, const float* __restrict__ op1,
    const float* __restrict__ lpart,
    const __bf16* __restrict__ W,
    const float* __restrict__ bias, const float* __restrict__ res,
    const float* __restrict__ g, const float* __restrict__ beta,
    const float* __restrict__ qpos_t,
    const __bf16* __restrict__ Wsm, const float* __restrict__ bsm,
    float* __restrict__ outf, float* __restrict__ soawO)
{
    __shared__ __align__(16) char smem[43776];
    int tid = threadIdx.x;
    __bf16* As  = (__bf16*)smem;             // [16][64]
    __bf16* Bs  = (__bf16*)(smem + 2048);    // [256][64]
    __bf16* Axq = (__bf16*)(smem + 34816);   // [16][264]
    float* redS = (float*)(smem + 43264);    // [64]
    float* redQ = redS + 64;                 // [64]
    int bm = blockIdx.x * 16;
    int wave = tid >> 6, lane = tid & 63, quad = lane >> 4, n16 = lane & 15;
    int wn = wave * 64;
    v4f acc[4] = {};

    for (int k0 = 0; k0 < 256; k0 += 64) {
        __syncthreads();
        if (tid < 128) {
            // combine split-K attention partials -> normalized bf16 A tile
            int e = tid;
            int r = e >> 3, c8 = (e & 7) ^ (r & 7);
            int m = bm + r;
            int col = k0 + c8 * 8;
            int hh = col >> 5;
            float invl = 1.0f / (lpart[m * 8 + hh] + lpart[32000 + m * 8 + hh]);
            const float* p0 = op0 + (long)m * 256 + col;
            const float* p1 = op1 + (long)m * 256 + col;
            float4 a0 = *(const float4*)p0;
            float4 a1 = *(const float4*)(p0 + 4);
            float4 b0 = *(const float4*)p1;
            float4 b1 = *(const float4*)(p1 + 4);
            v8bf v;
            v[0] = (__bf16)((a0.x + b0.x) * invl);
            v[1] = (__bf16)((a0.y + b0.y) * invl);
            v[2] = (__bf16)((a0.z + b0.z) * invl);
            v[3] = (__bf16)((a0.w + b0.w) * invl);
            v[4] = (__bf16)((a1.x + b1.x) * invl);
            v[5] = (__bf16)((a1.y + b1.y) * invl);
            v[6] = (__bf16)((a1.z + b1.z) * invl);
            v[7] = (__bf16)((a1.w + b1.w) * invl);
            *(v8bf*)(As + e * 8) = v;
        }
        #pragma unroll
        for (int i = 0; i < 8; i++) {
            int e = i * 256 + tid;
            int r = e >> 3, c = (e & 7) ^ (r & 7);
            gload_lds16(W + (long)r * 256 + k0 + c * 8, Bs + e * 8);
        }
        __syncthreads();
        #pragma unroll
        for (int s = 0; s < 2; s++) {
            v8bf af = *(v8bf*)&As[n16 * 64 + (((quad + s * 4) ^ (n16 & 7))) * 8];
            #pragma unroll
            for (int nj = 0; nj < 4; nj++) {
                int row = wn + nj * 16 + n16;
                v8bf bfr = *(v8bf*)&Bs[row * 64 + (((quad + s * 4) ^ (row & 7))) * 8];
                acc[nj] = __builtin_amdgcn_mfma_f32_16x16x32_bf16(af, bfr, acc[nj], 0, 0, 0);
            }
        }
    }

    float y[4][4], s1[4] = {}, s2[4] = {};
    #pragma unroll
    for (int r = 0; r < 4; r++) {
        int m = bm + quad * 4 + r;
        #pragma unroll
        for (int nj = 0; nj < 4; nj++) {
            int nn = wn + nj * 16 + n16;
            float v = acc[nj][r] + bias[nn] + res[(long)m * 256 + nn];
            y[r][nj] = v;
            s1[r] += v; s2[r] += v * v;
        }
    }
    #pragma unroll
    for (int r = 0; r < 4; r++) {
        #pragma unroll
        for (int off = 1; off < 16; off <<= 1) {
            s1[r] += __shfl_xor(s1[r], off, 16);
            s2[r] += __shfl_xor(s2[r], off, 16);
        }
    }
    if (n16 == 0) {
        #pragma unroll
        for (int r = 0; r < 4; r++) {
            redS[wave * 16 + quad * 4 + r] = s1[r];
            redQ[wave * 16 + quad * 4 + r] = s2[r];
        }
    }
    __syncthreads();
    #pragma unroll
    for (int r = 0; r < 4; r++) {
        int mr = quad * 4 + r;
        float ts = redS[mr] + redS[16 + mr] + redS[32 + mr] + redS[48 + mr];
        float tq = redQ[mr] + redQ[16 + mr] + redQ[32 + mr] + redQ[48 + mr];
        float mean = ts * (1.0f / 256.0f);
        float var = tq * (1.0f / 256.0f) - mean * mean;
        float rinv = rsqrtf(var + 1e-5f);
        int m = bm + mr;
        #pragma unroll
        for (int nj = 0; nj < 4; nj++) {
            int nn = wn + nj * 16 + n16;
            float o = (y[r][nj] - mean) * rinv * g[nn] + beta[nn];
            outf[(long)m * 256 + nn] = o;
            Axq[mr * 264 + nn] = (__bf16)(o + qpos_t[(long)m * 256 + nn]);
        }
    }
    __syncthreads();
    // soaw projection: 16 x 96, K=256, waves 0..2 handle 32 cols each
    if (wave < 3) {
        v4f sacc[2] = {};
        #pragma unroll
        for (int k0 = 0; k0 < 256; k0 += 32) {
            v8bf af = *(v8bf*)&Axq[n16 * 264 + k0 + quad * 8];
            #pragma unroll
            for (int t = 0; t < 2; t++) {
                int col = wave * 32 + t * 16 + n16;
                v8bf bw = *(const v8bf*)(Wsm + (long)col * 256 + k0 + quad * 8);
                sacc[t] = __builtin_amdgcn_mfma_f32_16x16x32_bf16(af, bw, sacc[t], 0, 0, 0);
            }
        }
        #pragma unroll
        for (int t = 0; t < 2; t++)
            #pragma unroll
            for (int r = 0; r < 4; r++) {
                int mm = bm + quad * 4 + r;
                int col = wave * 32 + t * 16 + n16;
                soawO[(long)mm * 96 + col] = sacc[t][r] + bsm[col];
            }
    }
}

// ====== msdeform bilinear sampling (2000 blocks, 2 queries/block) ======
__global__ __launch_bounds__(256) void msds_kernel(
    const __bf16* __restrict__ vproj, const float* __restrict__ soaw,
    const float* __restrict__ refp, __bf16* __restrict__ out)
{
    int t = threadIdx.x;
    int bq = blockIdx.x * 2 + (t >> 7);
    int b = bq / NQ; int q = bq % NQ;
    int t2 = t & 127;
    int h = t2 >> 4;            // 0..7
    int d0 = (t2 & 15) * 2;     // 0,2,...,30
    float rx = refp[(b * NQ + q) * 2 + 0];
    float ry = refp[(b * NQ + q) * 2 + 1];
    const float* rowp = soaw + (long)(b * NQ + q) * 96;
    const float* offp = rowp + h * 8;
    const float* awp  = rowp + 64 + h * 4;
    float a0 = awp[0], a1 = awp[1], a2 = awp[2], a3 = awp[3];
    float m = fmaxf(fmaxf(a0, a1), fmaxf(a2, a3));
    float e0 = __expf(a0 - m), e1 = __expf(a1 - m), e2 = __expf(a2 - m), e3 = __expf(a3 - m);
    float invs = 1.0f / (e0 + e1 + e2 + e3);
    float accA = 0.f, accB = 0.f;
    #pragma unroll
    for (int p = 0; p < PN; p++) {
        float ew = (p == 0 ? e0 : p == 1 ? e1 : p == 2 ? e2 : e3) * invs;
        float xim = rx * (float)WBEV + offp[p * 2 + 0] - 0.5f;
        float yim = ry * (float)HBEV + offp[p * 2 + 1] - 0.5f;
        float x0f = floorf(xim), y0f = floorf(yim);
        float lx = xim - x0f, ly = yim - y0f;
        int x0 = (int)x0f, y0 = (int)y0f;
        float gA = 0.f, gB = 0.f;
        #pragma unroll
        for (int dy = 0; dy < 2; dy++) {
            #pragma unroll
            for (int dx = 0; dx < 2; dx++) {
                int xi = x0 + dx, yi = y0 + dy;
                float w = (dx ? lx : 1.f - lx) * (dy ? ly : 1.f - ly);
                bool ok = (xi >= 0 && xi < WBEV && yi >= 0 && yi < HBEV);
                int xc = min(max(xi, 0), WBEV - 1);
                int yc = min(max(yi, 0), HBEV - 1);
                int idx = yc * WBEV + xc;
                v2bf gv = *(const v2bf*)(vproj + ((long)(idx * BS + b)) * CDIM + h * HD + d0);
                float wk = (ok ? w : 0.f);
                gA += wk * (float)gv[0];
                gB += wk * (float)gv[1];
            }
        }
        accA += ew * gA;
        accB += ew * gB;
    }
    v2bf o2; o2[0] = (__bf16)accA; o2[1] = (__bf16)accB;
    *(v2bf*)(out + (long)(b * NQ + q) * CDIM + h * HD + d0) = o2;
}

// == fused tail @512 threads (8 waves x 32 cols): op-proj+LN2 -> FFN1 ->
//    FFN2+res+LN3 -> transpose-out.  250 blocks, ~60 KB LDS. ==
__global__ __launch_bounds__(512) void gtail_kernel(
    const __bf16* __restrict__ A, const __bf16* __restrict__ Wop,
    const float* __restrict__ opb, const float* __restrict__ res,
    const float* __restrict__ g2, const float* __restrict__ b2ln,
    const __bf16* __restrict__ W1, const float* __restrict__ b1,
    const __bf16* __restrict__ W2, const float* __restrict__ bff2,
    const float* __restrict__ g3, const float* __restrict__ b3ln,
    float* __restrict__ outf)
{
    __shared__ __align__(16) char smem[60416];
    __bf16* As  = (__bf16*)smem;              // [16][64]    phase-A A staging
    __bf16* Bs  = (__bf16*)(smem + 2048);     // [256][64]   weight staging
    __bf16* As2 = (__bf16*)(smem + 34816);    // [4][16][64] LN2-out (swizzled)
    __bf16* h1s = (__bf16*)(smem + 43008);    // [8][16][64] FFN1-out (swizzled)
    float* redS = (float*)(smem + 59392);     // [128]
    float* redQ = (float*)(smem + 59904);     // [128]
    int tid = threadIdx.x;
    int bm = blockIdx.x * 16;
    int wave = tid >> 6, lane = tid & 63, quad = lane >> 4, n16 = lane & 15;
    int wn = wave * 32;
    int mr_ = quad * 4;   // row base for this lane's 4 rows

    // ---------- Phase A: op-proj (K=256) + residual + LN2 ----------
    v4f acc[2] = {};
    for (int k0 = 0; k0 < 256; k0 += 64) {
        __syncthreads();
        if (tid < 128) {
            int e = tid;
            int r = e >> 3, c = (e & 7) ^ (r & 7);
            gload_lds16(A + (long)(bm + r) * 256 + k0 + c * 8, As + e * 8);
        }
        #pragma unroll
        for (int i = 0; i < 4; i++) {
            int e = i * 512 + tid;
            int r = e >> 3, c = (e & 7) ^ (r & 7);
            gload_lds16(Wop + (long)r * 256 + k0 + c * 8, Bs + e * 8);
        }
        __syncthreads();
        #pragma unroll
        for (int s = 0; s < 2; s++) {
            v8bf af = *(v8bf*)&As[n16 * 64 + (((quad + s * 4) ^ (n16 & 7))) * 8];
            #pragma unroll
            for (int nj = 0; nj < 2; nj++) {
                int row = wn + nj * 16 + n16;
                v8bf bfr = *(v8bf*)&Bs[row * 64 + (((quad + s * 4) ^ (row & 7))) * 8];
                acc[nj] = __builtin_amdgcn_mfma_f32_16x16x32_bf16(af, bfr, acc[nj], 0, 0, 0);
            }
        }
    }
    float yv[4][2], s1[4] = {}, s2[4] = {};
    #pragma unroll
    for (int r = 0; r < 4; r++) {
        int m = bm + mr_ + r;
        #pragma unroll
        for (int nj = 0; nj < 2; nj++) {
            int nn = wn + nj * 16 + n16;
            float v = acc[nj][r] + opb[nn] + res[(long)m * 256 + nn];
            yv[r][nj] = v;
            s1[r] += v; s2[r] += v * v;
        }
    }
    #pragma unroll
    for (int r = 0; r < 4; r++) {
        #pragma unroll
        for (int off = 1; off < 16; off <<= 1) {
            s1[r] += __shfl_xor(s1[r], off, 16);
            s2[r] += __shfl_xor(s2[r], off, 16);
        }
    }
    if (n16 == 0) {
        #pragma unroll
        for (int r = 0; r < 4; r++) {
            redS[wave * 16 + mr_ + r] = s1[r];
            redQ[wave * 16 + mr_ + r] = s2[r];
        }
    }
    __syncthreads();
    #pragma unroll
    for (int r = 0; r < 4; r++) {
        int mr = mr_ + r;
        float ts = 0.f, tq = 0.f;
        #pragma unroll
        for (int j = 0; j < 8; j++) { ts += redS[j * 16 + mr]; tq += redQ[j * 16 + mr]; }
        float mean = ts * (1.0f / 256.0f);
        float var = tq * (1.0f / 256.0f) - mean * mean;
        float rinv = rsqrtf(var + 1e-5f);
        #pragma unroll
        for (int nj = 0; nj < 2; nj++) {
            int nn = wn + nj * 16 + n16;
            float o = (yv[r][nj] - mean) * rinv * g2[nn] + b2ln[nn];
            yv[r][nj] = o;   // keep x2 residual in registers
            int kc = nn >> 6, c6 = nn & 63;
            As2[kc * 1024 + mr * 64 + (((c6 >> 3) ^ (mr & 7)) << 3) + (c6 & 7)] = (__bf16)o;
        }
    }

    // ---------- Phase B: FFN1 (K=256, N=512 in two halves) + ReLU ----------
    #pragma unroll 1
    for (int H = 0; H < 2; H++) {
        v4f accB[2] = {};
        for (int k0 = 0; k0 < 256; k0 += 64) {
            __syncthreads();
            #pragma unroll
            for (int i = 0; i < 4; i++) {
                int e = i * 512 + tid;
                int r = e >> 3, c = (e & 7) ^ (r & 7);
                gload_lds16(W1 + (long)(H * 256 + r) * 256 + k0 + c * 8, Bs + e * 8);
            }
            __syncthreads();
            int kc = k0 >> 6;
            #pragma unroll
            for (int s = 0; s < 2; s++) {
                v8bf af = *(v8bf*)&As2[kc * 1024 + n16 * 64 + (((quad + s * 4) ^ (n16 & 7))) * 8];
                #pragma unroll
                for (int nj = 0; nj < 2; nj++) {
                    int row = wn + nj * 16 + n16;
                    v8bf bfr = *(v8bf*)&Bs[row * 64 + (((quad + s * 4) ^ (row & 7))) * 8];
                    accB[nj] = __builtin_amdgcn_mfma_f32_16x16x32_bf16(af, bfr, accB[nj], 0, 0, 0);
                }
            }
        }
        #pragma unroll
        for (int r = 0; r < 4; r++) {
            int mr = mr_ + r;
            #pragma unroll
            for (int nj = 0; nj < 2; nj++) {
                int col = H * 256 + wn + nj * 16 + n16;
                float v = accB[nj][r] + b1[col];
                v = fmaxf(v, 0.f);
                int kc = col >> 6, c6 = col & 63;
                h1s[kc * 1024 + mr * 64 + (((c6 >> 3) ^ (mr & 7)) << 3) + (c6 & 7)] = (__bf16)v;
            }
        }
    }

    // ---------- Phase C: FFN2 (K=512) + bias + x2 residual + LN3 ----------
    v4f acc3[2] = {};
    for (int k0 = 0; k0 < 512; k0 += 64) {
        __syncthreads();
        #pragma unroll
        for (int i = 0; i < 4; i++) {
            int e = i * 512 + tid;
            int r = e >> 3, c = (e & 7) ^ (r & 7);
            gload_lds16(W2 + (long)r * 512 + k0 + c * 8, Bs + e * 8);
        }
        __syncthreads();
        int kc = k0 >> 6;
        #pragma unroll
        for (int s = 0; s < 2; s++) {
            v8bf af = *(v8bf*)&h1s[kc * 1024 + n16 * 64 + (((quad + s * 4) ^ (n16 & 7))) * 8];
            #pragma unroll
            for (int nj = 0; nj < 2; nj++) {
                int row = wn + nj * 16 + n16;
                v8bf bfr = *(v8bf*)&Bs[row * 64 + (((quad + s * 4) ^ (row & 7))) * 8];
                acc3[nj] = __builtin_amdgcn_mfma_f32_16x16x32_bf16(af, bfr, acc3[nj], 0, 0, 0);
            }
        }
    }
    float y3[4][2], t1[4] = {}, t2[4] = {};
    #pragma unroll
    for (int r = 0; r < 4; r++) {
        #pragma unroll
        for (int nj = 0; nj < 2; nj++) {
            int nn = wn + nj * 16 + n16;
            float v = acc3[nj][r] + bff2[nn] + yv[r][nj];
            y3[r][nj] = v;
            t1[r] += v; t2[r] += v * v;
        }
    }
    #pragma unroll
    for (int r = 0; r < 4; r++) {
        #pragma unroll
        for (int off = 1; off < 16; off <<= 1) {
            t1[r] += __shfl_xor(t1[r], off, 16);
            t2[r] += __shfl_xor(t2[r], off, 16);
        }
    }
    __syncthreads();   // red arrays free for reuse
    if (n16 == 0) {
        #pragma unroll
        for (int r = 0; r < 4; r++) {
            redS[wave * 16 + mr_ + r] = t1[r];
            redQ[wave * 16 + mr_ + r] = t2[r];
        }
    }
    __syncthreads();
    #pragma unroll
    for (int r = 0; r < 4; r++) {
        int mr = mr_ + r;
        float ts = 0.f, tq = 0.f;
        #pragma unroll
        for (int j = 0; j < 8; j++) { ts += redS[j * 16 + mr]; tq += redQ[j * 16 + mr]; }
        float mean = ts * (1.0f / 256.0f);
        float var = tq * (1.0f / 256.0f) - mean * mean;
        float rinv = rsqrtf(var + 1e-5f);
        int m = bm + mr;
        int b = m / NQ, q = m - b * NQ;
        #pragma unroll
        for (int nj = 0; nj < 2; nj++) {
            int nn = wn + nj * 16 + n16;
            float o = (y3[r][nj] - mean) * rinv * g3[nn] + b3ln[nn];
            outf[(long)(q * BS + b) * 256 + nn] = o;
        }
    }
}

extern "C" void kernel_launch(void* const* d_in, const int* in_sizes, int n_in,
                              void* d_out, int out_size, void* d_ws, size_t ws_size,
                              hipStream_t stream) {
    const float* query = (const float*)d_in[0];
    const float* value = (const float*)d_in[1];
    const float* qpos  = (const float*)d_in[2];
    const float* refp  = (const float*)d_in[3];
    const float* in_w  = (const float*)d_in[6];
    const float* in_b  = (const float*)d_in[7];
    const float* mha_ow = (const float*)d_in[8];
    const float* mha_ob = (const float*)d_in[9];
    const float* so_w  = (const float*)d_in[10];
    const float* so_b  = (const float*)d_in[11];
    const float* aw_w  = (const float*)d_in[12];
    const float* aw_b  = (const float*)d_in[13];
    const float* vp_w  = (const float*)d_in[14];
    const float* vp_b  = (const float*)d_in[15];
    const float* op_w  = (const float*)d_in[16];
    const float* op_b  = (const float*)d_in[17];
    const float* ffn_w1 = (const float*)d_in[18];
    const float* ffn_b1 = (const float*)d_in[19];
    const float* ffn_w2 = (const float*)d_in[20];
    const float* ffn_b2 = (const float*)d_in[21];
    const float* ln1_g = (const float*)d_in[22];
    const float* ln1_b = (const float*)d_in[23];
    const float* ln2_g = (const float*)d_in[24];
    const float* ln2_b = (const float*)d_in[25];
    const float* ln3_g = (const float*)d_in[26];
    const float* ln3_b = (const float*)d_in[27];
    float* out = (float*)d_out;

    const long NTOK = (long)BS * NQ * CDIM;   // 1,024,000

    float* x      = (float*)d_ws;
    float* qpos_t = x + NTOK;
    float* x1     = qpos_t + NTOK;
    float* x2     = x1 + NTOK;                       // reused: attn o-partial 0
    float* soaw   = x2 + NTOK;                       // 4000*96
    float* bsmall = soaw + (long)BS * NQ * 96;       // 128
    __bf16* x_bf   = (__bf16*)(bsmall + 128);
    __bf16* xq_bf  = x_bf + NTOK;
    __bf16* qk_bf  = xq_bf + NTOK;                   // 2*NTOK (q|k, stride 512)
    __bf16* vh_bf  = qk_bf + 2 * NTOK;
    __bf16* aA_bf  = vh_bf + NTOK;
    __bf16* x2_bf  = aA_bf + NTOK;                   // reused: l-partials
    __bf16* h1_bf  = x2_bf + NTOK;                   // reused: attn o-partial 1
    __bf16* vpj_bf = h1_bf + 2 * NTOK;               // 20,480,000
    __bf16* wb     = vpj_bf + (long)BS * NVAL * CDIM;
    __bf16* inw_b  = wb;
    __bf16* mow_b  = wb + 196608;
    __bf16* vpw_b  = wb + 262144;
    __bf16* opw_b  = wb + 327680;
    __bf16* fw1_b  = wb + 393216;
    __bf16* fw2_b  = wb + 524288;
    __bf16* wsmall = wb + 655360;                    // 128x256

    float* opart0 = x2;                 // NTOK floats
    float* opart1 = (float*)h1_bf;      // 2*NTOK bf16 = NTOK floats
    float* lpart  = (float*)x2_bf;      // 2*32000 floats (fits NTOK bf16 region)

    dim3 blk(256);

    prep_all_kernel<<<4673, blk, 0, stream>>>(
        query, qpos, in_w, mha_ow, vp_w, op_w, ffn_w1, ffn_w2,
        so_w, aw_w, so_b, aw_b,
        x, qpos_t, x_bf, xq_bf, wb, wsmall, bsmall);

    // q|k|v in-proj (756) + value-proj rider (1250) overlapped
    qkvv_kernel<<<2006, blk, 0, stream>>>(xq_bf, x_bf, inw_b, in_b, qk_bf, vh_bf,
                                          value, vpw_b, vp_b, vpj_bf);

    // flash attention, split-K 2-way (1024 blocks, 4/CU)
    fattns_kernel<<<1024, blk, 0, stream>>>(qk_bf, vh_bf, opart0, opart1, lpart);

    // combine + mha out-proj + res(x) + LN1 + fused soaw projection (250)
    gln1s_kernel<<<250, blk, 0, stream>>>(
        opart0, opart1, lpart, mow_b, mha_ob, x, ln1_g, ln1_b, qpos_t,
        wsmall, bsmall, x1, soaw);

    // msdeform sampling (2000 blocks, 2 queries each, 4B gathers)
    msds_kernel<<<2000, blk, 0, stream>>>(vpj_bf, soaw, refp, aA_bf);

    // fused tail @512 threads: op-proj+LN2 -> FFN1 -> FFN2+LN3 -> out
    gtail_kernel<<<250, dim3(512), 0, stream>>>(
        aA_bf, opw_b, op_b, x1, ln2_g, ln2_b,
        fw1_b, ffn_b1, fw2_b, ffn_b2, ln3_g, ln3_b, out);
}